// Round 5
// baseline (2029.864 us; speedup 1.0000x reference)
//
#include <hip/hip_runtime.h>
#include <hip/hip_bf16.h>
#include <math.h>

#define D_MODEL 256
#define NUM_SLOTS 128
#define RANK 32
#define N_STEPS 6
#define VOCAB 32000
#define SEQ 512
#define BATCH 8
#define NTOK (BATCH*SEQ)
#define LN_EPS 1e-5f
#define SM_SCALE 0.0625f
#define IGROUPS 8
#define IPG (NUM_SLOTS/IGROUPS)

typedef __attribute__((ext_vector_type(8))) short bf16x8;
typedef __attribute__((ext_vector_type(8))) _Float16 f16x8;
typedef __attribute__((ext_vector_type(4))) float f32x4;

__device__ inline unsigned short f2bf(float x) {
    unsigned u = __float_as_uint(x);
    unsigned r = u + 0x7fff + ((u >> 16) & 1);
    return (unsigned short)(r >> 16);
}
__device__ inline float bf2f(unsigned short h) {
    return __uint_as_float(((unsigned)h) << 16);
}
__device__ inline unsigned pk2(float a, float b) {
    auto v = __builtin_amdgcn_cvt_pkrtz(a, b);
    union { decltype(v) x; unsigned u; } c;
    c.x = v;
    return c.u;
}

// X[b,l,:] = token_emb[ids[b,l],:] + pos_emb[l,:]
__global__ __launch_bounds__(256) void k_embed(const int* __restrict__ ids,
        const float* __restrict__ tok, const float* __restrict__ pos,
        float* __restrict__ X) {
    int bl = blockIdx.x;
    int d  = threadIdx.x;
    int l  = bl % SEQ;
    int id = ids[bl];
    X[(size_t)bl*D_MODEL + d] = tok[(size_t)id*D_MODEL + d] + pos[l*D_MODEL + d];
}

// C[m,n] = sum_k A[m,k]*B[n,k]   (both row-major, K contiguous)  64x64 tile
__global__ __launch_bounds__(256) void k_gemm_nt(const float* __restrict__ A,
        const float* __restrict__ B, float* __restrict__ C, int M, int N, int K) {
    __shared__ float As[32][64];
    __shared__ float Bs[32][64];
    int bm = blockIdx.x * 64, bn = blockIdx.y * 64;
    int t = threadIdx.x;
    int tm = (t & 15) * 4, tn = (t >> 4) * 4;
    float acc[4][4] = {};
    for (int k0 = 0; k0 < K; k0 += 32) {
        #pragma unroll
        for (int r = 0; r < 8; ++r) {
            int idx = r*256 + t;
            int m = idx >> 5, k = idx & 31;
            As[k][m] = A[(size_t)(bm+m)*K + k0 + k];
        }
        #pragma unroll
        for (int r = 0; r < 8; ++r) {
            int idx = r*256 + t;
            int n = idx >> 5, k = idx & 31;
            Bs[k][n] = B[(size_t)(bn+n)*K + k0 + k];
        }
        __syncthreads();
        #pragma unroll
        for (int k = 0; k < 32; ++k) {
            float4 a4 = *(const float4*)&As[k][tm];
            float4 b4 = *(const float4*)&Bs[k][tn];
            float a[4] = {a4.x,a4.y,a4.z,a4.w};
            float b[4] = {b4.x,b4.y,b4.z,b4.w};
            #pragma unroll
            for (int i = 0; i < 4; ++i)
                #pragma unroll
                for (int jj = 0; jj < 4; ++jj)
                    acc[i][jj] += a[i]*b[jj];
        }
        __syncthreads();
    }
    #pragma unroll
    for (int i = 0; i < 4; ++i) {
        float4 v = make_float4(acc[i][0],acc[i][1],acc[i][2],acc[i][3]);
        *(float4*)&C[(size_t)(bm+tm+i)*N + bn+tn] = v;
    }
}

// split fp32 -> bf16 hi + bf16 lo
__global__ __launch_bounds__(256) void k_split(const float* __restrict__ in,
        unsigned short* __restrict__ hi, unsigned short* __restrict__ lo, int n4) {
    int i = blockIdx.x*256 + threadIdx.x;
    if (i >= n4) return;
    float4 v = ((const float4*)in)[i];
    float f[4] = {v.x, v.y, v.z, v.w};
    ushort4 h, lw;
    unsigned short* hp = &h.x; unsigned short* lp = &lw.x;
    #pragma unroll
    for (int j = 0; j < 4; ++j) {
        unsigned short hb = f2bf(f[j]);
        hp[j] = hb;
        lp[j] = f2bf(f[j] - bf2f(hb));
    }
    ((ushort4*)hi)[i] = h;
    ((ushort4*)lo)[i] = lw;
}

// logits GEMM: 3-pass split-bf16 MFMA
__global__ __launch_bounds__(256) void k_logits(
        const unsigned short* __restrict__ Ahg, const unsigned short* __restrict__ Alg,
        const unsigned short* __restrict__ Bhg, const unsigned short* __restrict__ Blg,
        float* __restrict__ C) {
    __shared__ short lds[4*128*64];
    short* Ah = lds;
    short* Al = lds + 8192;
    short* Bh = lds + 16384;
    short* Bl = lds + 24576;
    int bm = blockIdx.x * 128, bn = blockIdx.y * 128;
    int t = threadIdx.x;
    int w = t >> 6, l = t & 63;
    int wr = w >> 1, wc = w & 1;
    int lr = l & 15, lk = l >> 4;
    f32x4 acc[4][4];
    #pragma unroll
    for (int mi = 0; mi < 4; ++mi)
        #pragma unroll
        for (int ni = 0; ni < 4; ++ni)
            acc[mi][ni] = (f32x4){0.f,0.f,0.f,0.f};

    for (int kc = 0; kc < 4; ++kc) {
        #pragma unroll
        for (int i = 0; i < 4; ++i) {
            int v = t + i*256;
            int row = v >> 3, cv = v & 7;
            int so = row*64 + ((cv ^ (row & 7)) << 3);
            size_t ga = (size_t)(bm+row)*256 + kc*64 + cv*8;
            size_t gb = (size_t)(bn+row)*256 + kc*64 + cv*8;
            *(bf16x8*)&Ah[so] = *(const bf16x8*)&Ahg[ga];
            *(bf16x8*)&Al[so] = *(const bf16x8*)&Alg[ga];
            *(bf16x8*)&Bh[so] = *(const bf16x8*)&Bhg[gb];
            *(bf16x8*)&Bl[so] = *(const bf16x8*)&Blg[gb];
        }
        __syncthreads();
        #pragma unroll
        for (int s = 0; s < 2; ++s) {
            bf16x8 ah[4], al[4], bh[4], bl[4];
            #pragma unroll
            for (int mi = 0; mi < 4; ++mi) {
                int row = wr*64 + mi*16 + lr;
                int off = row*64 + ((((s<<2)+lk) ^ (row&7)) << 3);
                ah[mi] = *(bf16x8*)&Ah[off];
                al[mi] = *(bf16x8*)&Al[off];
            }
            #pragma unroll
            for (int ni = 0; ni < 4; ++ni) {
                int row = wc*64 + ni*16 + lr;
                int off = row*64 + ((((s<<2)+lk) ^ (row&7)) << 3);
                bh[ni] = *(bf16x8*)&Bh[off];
                bl[ni] = *(bf16x8*)&Bl[off];
            }
            #pragma unroll
            for (int mi = 0; mi < 4; ++mi)
                #pragma unroll
                for (int ni = 0; ni < 4; ++ni) {
                    acc[mi][ni] = __builtin_amdgcn_mfma_f32_16x16x32_bf16(ah[mi], bh[ni], acc[mi][ni], 0, 0, 0);
                    acc[mi][ni] = __builtin_amdgcn_mfma_f32_16x16x32_bf16(ah[mi], bl[ni], acc[mi][ni], 0, 0, 0);
                    acc[mi][ni] = __builtin_amdgcn_mfma_f32_16x16x32_bf16(al[mi], bh[ni], acc[mi][ni], 0, 0, 0);
                }
        }
        __syncthreads();
    }
    #pragma unroll
    for (int mi = 0; mi < 4; ++mi)
        #pragma unroll
        for (int ni = 0; ni < 4; ++ni) {
            int col = bn + wc*64 + ni*16 + lr;
            #pragma unroll
            for (int r = 0; r < 4; ++r) {
                int row = bm + wr*64 + mi*16 + lk*4 + r;
                C[(size_t)row*VOCAB + col] = acc[mi][ni][r];
            }
        }
}

__global__ __launch_bounds__(128) void k_softmax_mask(float* __restrict__ A,
        const int* __restrict__ mask) {
    int row = blockIdx.x;
    int s = threadIdx.x;
    __shared__ float red[128];
    float v = A[(size_t)row*NUM_SLOTS + s] * SM_SCALE;
    red[s] = v; __syncthreads();
    for (int o = 64; o > 0; o >>= 1) { if (s < o) red[s] = fmaxf(red[s], red[s+o]); __syncthreads(); }
    float mx = red[0]; __syncthreads();
    float e = expf(v - mx);
    red[s] = e; __syncthreads();
    for (int o = 64; o > 0; o >>= 1) { if (s < o) red[s] += red[s+o]; __syncthreads(); }
    float sum = red[0];
    float m = (float)mask[row];
    A[(size_t)row*NUM_SLOTS + s] = e / sum * m;
}

__global__ __launch_bounds__(128) void k_colsum(const float* __restrict__ A,
        float* __restrict__ cs) {
    int b = blockIdx.x; int s = threadIdx.x;
    const float* Ab = A + (size_t)b*SEQ*NUM_SLOTS + s;
    float acc = 0.f;
    for (int l = 0; l < SEQ; ++l) acc += Ab[(size_t)l*NUM_SLOTS];
    cs[b*NUM_SLOTS + s] = acc + 1e-8f;
}

__global__ __launch_bounds__(256) void k_ir(const float* __restrict__ A,
        const float* __restrict__ V, const float* __restrict__ H,
        const float* __restrict__ cs, float* __restrict__ Hs) {
    int bs = blockIdx.x; int b = bs >> 7; int s = bs & 127;
    int d = threadIdx.x;
    float inv = 1.0f / cs[bs];
    const float* Ab = A + (size_t)b*SEQ*NUM_SLOTS + s;
    const float* Vb = V + (size_t)b*SEQ*D_MODEL + d;
    float acc = 0.f;
    for (int l = 0; l < SEQ; ++l) acc += Ab[(size_t)l*NUM_SLOTS] * Vb[(size_t)l*D_MODEL];
    Hs[(size_t)bs*D_MODEL + d] = H[s*D_MODEL + d] + acc * inv;
}

// ---- one-time fp32->fp16 weight conversion into MFMA fragment order ----
// WF layout per pair p=(j*128+i): [0:8192) ushorts = Ws frags (A-op of pass1),
// chunk ((ks*2+mt)*64+l): e -> Ws[i,j][d=ks*32+(l>>4)*8+e][r=mt*16+(l&15)]
// [8192:16384) = Wt frags (B-op of pass2),
// chunk (nt*64+l): e -> Wt[i,j][r=(l>>4)*8+e][d=nt*16+(l&15)]
// Split into two streaming kernels (17 KB LDS each -> high occupancy).

// Ws half: blockIdx.z = hf handles d in [hf*128, hf*128+128)
__global__ __launch_bounds__(256) void k_convert_s(const float* __restrict__ Ws,
        unsigned short* __restrict__ WF) {
    int i = blockIdx.x, j = blockIdx.y, hf = blockIdx.z;
    int t = threadIdx.x;
    __shared__ float lds[128*33];
    size_t sBase = ((size_t)i*128 + j)*8192;
    size_t pOut = ((size_t)j*128 + i)*16384;
    const float4* s4 = (const float4*)(Ws + sBase) + hf*1024;
    #pragma unroll
    for (int p = 0; p < 4; ++p) {
        int f4 = p*256 + t;
        float4 v = s4[f4];
        *(float4*)&lds[(f4 >> 3)*33 + 4*(f4 & 7)] = v;
    }
    __syncthreads();
    bool diag = (i == j);
    #pragma unroll
    for (int q = 0; q < 2; ++q) {
        int cl = q*256 + t;
        int ksl = cl >> 7, mt = (cl >> 6) & 1, l = cl & 63;
        int g = l >> 4, c = l & 15;
        union { f16x8 v; } o;
        #pragma unroll
        for (int e = 0; e < 8; ++e) {
            float f = diag ? 0.f : lds[(ksl*32 + g*8 + e)*33 + mt*16 + c];
            o.v[e] = (_Float16)f;
        }
        *(f16x8*)(WF + pOut + (size_t)hf*4096 + (size_t)cl*8) = o.v;
    }
}

// Wt half: blockIdx.z = hf handles d in [hf*128, hf*128+128)
__global__ __launch_bounds__(256) void k_convert_t(const float* __restrict__ Wt,
        unsigned short* __restrict__ WF) {
    int i = blockIdx.x, j = blockIdx.y, hf = blockIdx.z;
    int t = threadIdx.x;
    __shared__ float lds[32*133];
    size_t sBase = ((size_t)i*128 + j)*8192;
    size_t pOut = ((size_t)j*128 + i)*16384;
    const float4* s4 = (const float4*)(Wt + sBase);
    #pragma unroll
    for (int p = 0; p < 4; ++p) {
        int idx = p*256 + t;
        int r = idx >> 5, c4 = idx & 31;
        float4 v = s4[r*64 + hf*32 + c4];
        *(float4*)&lds[r*133 + c4*4] = v;
    }
    __syncthreads();
    #pragma unroll
    for (int q = 0; q < 2; ++q) {
        int cl = q*256 + t;
        int ntl = cl >> 6, l = cl & 63;
        int g = l >> 4, c = l & 15;
        union { f16x8 v; } o;
        #pragma unroll
        for (int e = 0; e < 8; ++e)
            o.v[e] = (_Float16)lds[(g*8 + e)*133 + ntl*16 + c];
        *(f16x8*)(WF + pOut + 8192 + (size_t)hf*4096 + (size_t)cl*8) = o.v;
    }
}

// ---- register-direct MFMA slot-pair kernel: block (j, g) accumulates 16 i's ----
// No LDS, no barriers: fragments load straight from WF (lane-contiguous 16B),
// the compiler software-pipelines the ii loop with counted vmcnt.
__global__ __launch_bounds__(256) void k_pairs_mfma(const float* __restrict__ h,
        const unsigned short* __restrict__ WF, float* __restrict__ part) {
    int j = blockIdx.x, g = blockIdx.y;
    int t = threadIdx.x, w = t >> 6, l = t & 63;
    int lg = l >> 4, c = l & 15;
    const unsigned short* pbase = WF + ((size_t)j*128 + g*16)*16384;
    f32x4 acc[4];
    #pragma unroll
    for (int nt = 0; nt < 4; ++nt) acc[nt] = (f32x4){0.f,0.f,0.f,0.f};

    for (int ii = 0; ii < 16; ++ii) {
        const unsigned short* bp = pbase + (size_t)ii*16384;
        // Ws A-frags (full, all waves identical -> L2 dedupes)
        f16x8 a0[8], a1[8];
        #pragma unroll
        for (int ks = 0; ks < 8; ++ks) {
            a0[ks] = *(const f16x8*)(bp + (ks*2+0)*512 + l*8);
            a1[ks] = *(const f16x8*)(bp + (ks*2+1)*512 + l*8);
        }
        // Wt B-frags (wave w owns d-tiles w*4..w*4+3)
        f16x8 bq[4];
        #pragma unroll
        for (int nt = 0; nt < 4; ++nt)
            bq[nt] = *(const f16x8*)(bp + 8192 + (size_t)((w*4+nt)*64 + l)*8);
        // h B-frags (direct from global, fp32->fp16, zero pad rows b>=8)
        f16x8 hb[8];
        if (c < 8) {
            const float* hrow = h + ((size_t)c*NUM_SLOTS + (g*16+ii))*D_MODEL + lg*8;
            #pragma unroll
            for (int ks = 0; ks < 8; ++ks) {
                float4 v0 = *(const float4*)(hrow + ks*32);
                float4 v1 = *(const float4*)(hrow + ks*32 + 4);
                float f[8] = {v0.x,v0.y,v0.z,v0.w,v1.x,v1.y,v1.z,v1.w};
                #pragma unroll
                for (int e = 0; e < 8; ++e) hb[ks][e] = (_Float16)f[e];
            }
        } else {
            #pragma unroll
            for (int ks = 0; ks < 8; ++ks)
                #pragma unroll
                for (int e = 0; e < 8; ++e) hb[ks][e] = (_Float16)0.f;
        }
        // pass1: interT[r=0..31][b] = sum_d WsT[r][d] h[b][d]
        f32x4 d1[2];
        d1[0] = (f32x4){0.f,0.f,0.f,0.f};
        d1[1] = (f32x4){0.f,0.f,0.f,0.f};
        #pragma unroll
        for (int ks = 0; ks < 8; ++ks) {
            d1[0] = __builtin_amdgcn_mfma_f32_16x16x32_f16(a0[ks], hb[ks], d1[0], 0, 0, 0);
            d1[1] = __builtin_amdgcn_mfma_f32_16x16x32_f16(a1[ks], hb[ks], d1[1], 0, 0, 0);
        }
        // pack interT to fp16 pairs, shuffle into pass2 A-frag
        unsigned q0 = pk2(d1[0][0], d1[0][1]);
        unsigned q1 = pk2(d1[0][2], d1[0][3]);
        unsigned s0 = pk2(d1[1][0], d1[1][1]);
        unsigned s1 = pk2(d1[1][2], d1[1][3]);
        int srcLo = 32*(lg & 1) + c;
        int srcHi = srcLo + 16;
        unsigned a0s = (unsigned)__shfl((int)q0, srcLo, 64);
        unsigned a1s = (unsigned)__shfl((int)q1, srcLo, 64);
        unsigned a2s = (unsigned)__shfl((int)q0, srcHi, 64);
        unsigned a3s = (unsigned)__shfl((int)q1, srcHi, 64);
        unsigned b0s = (unsigned)__shfl((int)s0, srcLo, 64);
        unsigned b1s = (unsigned)__shfl((int)s1, srcLo, 64);
        unsigned b2s = (unsigned)__shfl((int)s0, srcHi, 64);
        unsigned b3s = (unsigned)__shfl((int)s1, srcHi, 64);
        bool himt = ((lg >> 1) & 1);
        union { unsigned u[4]; f16x8 v; } A2u;
        A2u.u[0] = himt ? b0s : a0s;
        A2u.u[1] = himt ? b1s : a1s;
        A2u.u[2] = himt ? b2s : a2s;
        A2u.u[3] = himt ? b3s : a3s;
        // pass2: out[b][d] += sum_r inter[b][r] Wt[r][d]
        #pragma unroll
        for (int nt = 0; nt < 4; ++nt)
            acc[nt] = __builtin_amdgcn_mfma_f32_16x16x32_f16(A2u.v, bq[nt], acc[nt], 0, 0, 0);
    }
    // store: lanes lg<2 hold rows b = lg*4+reg (0..7)
    if (lg < 2) {
        #pragma unroll
        for (int nt = 0; nt < 4; ++nt) {
            int d = (w*4 + nt)*16 + c;
            #pragma unroll
            for (int r = 0; r < 4; ++r) {
                int b = lg*4 + r;
                part[(((size_t)g*BATCH + b)*NUM_SLOTS + j)*D_MODEL + d] = acc[nt][r];
            }
        }
    }
}

// fallback fp32 pairs kernel (used when ws too small for WF)
__global__ __launch_bounds__(256) void k_pairs(const float* __restrict__ h,
        const float* __restrict__ Ws, const float* __restrict__ Wt,
        float* __restrict__ part) {
    int j = blockIdx.x;
    int g = blockIdx.y;
    int t = threadIdx.x;
    __shared__ float sh_h[BATCH][D_MODEL];
    __shared__ float sh_inter[BATCH][RANK];
    float acc[BATCH];
    #pragma unroll
    for (int b = 0; b < BATCH; ++b) acc[b] = 0.f;
    int tb = t >> 5, tr = t & 31;
    for (int ii = 0; ii < IPG; ++ii) {
        int i = g*IPG + ii;
        if (i == j) continue;
        #pragma unroll
        for (int b = 0; b < BATCH; ++b)
            sh_h[b][t] = h[((size_t)b*NUM_SLOTS + i)*D_MODEL + t];
        __syncthreads();
        const float* ws = Ws + ((size_t)i*NUM_SLOTS + j)*(D_MODEL*RANK);
        float accA = 0.f;
        #pragma unroll 8
        for (int d = 0; d < D_MODEL; ++d)
            accA += sh_h[tb][d] * ws[(size_t)d*RANK + tr];
        sh_inter[tb][tr] = accA;
        __syncthreads();
        const float* wt = Wt + ((size_t)i*NUM_SLOTS + j)*(RANK*D_MODEL);
        #pragma unroll 8
        for (int r = 0; r < RANK; ++r) {
            float w = wt[(size_t)r*D_MODEL + t];
            #pragma unroll
            for (int b = 0; b < BATCH; ++b) acc[b] += sh_inter[b][r] * w;
        }
        __syncthreads();
    }
    #pragma unroll
    for (int b = 0; b < BATCH; ++b)
        part[(((size_t)g*BATCH + b)*NUM_SLOTS + j)*D_MODEL + t] = acc[b];
}

__global__ __launch_bounds__(256) void k_ln(float* __restrict__ h,
        const float* __restrict__ part, const float* __restrict__ gma,
        const float* __restrict__ bta) {
    int bj = blockIdx.x;
    int t = threadIdx.x;
    int b = bj >> 7, j = bj & 127;
    __shared__ float red[256];
    float v = 0.f;
    #pragma unroll
    for (int g = 0; g < IGROUPS; ++g)
        v += part[(((size_t)g*BATCH + b)*NUM_SLOTS + j)*D_MODEL + t];
    float x = h[(size_t)bj*D_MODEL + t] + fmaxf(v, 0.f);
    red[t] = x; __syncthreads();
    for (int o = 128; o > 0; o >>= 1) { if (t < o) red[t] += red[t+o]; __syncthreads(); }
    float mu = red[0] * (1.0f/D_MODEL); __syncthreads();
    float dx = x - mu;
    red[t] = dx*dx; __syncthreads();
    for (int o = 128; o > 0; o >>= 1) { if (t < o) red[t] += red[t+o]; __syncthreads(); }
    float var = red[0] * (1.0f/D_MODEL);
    h[(size_t)bj*D_MODEL + t] = dx * rsqrtf(var + LN_EPS) * gma[t] + bta[t];
}

__global__ __launch_bounds__(128) void k_attn2(const float* __restrict__ Q,
        const float* __restrict__ Kf, float* __restrict__ A2) {
    int bl = blockIdx.x; int b = bl / SEQ;
    int s = threadIdx.x;
    __shared__ float q[D_MODEL];
    __shared__ float red[128];
    q[s]       = Q[(size_t)bl*D_MODEL + s];
    q[s + 128] = Q[(size_t)bl*D_MODEL + s + 128];
    __syncthreads();
    const float* kf = Kf + ((size_t)b*NUM_SLOTS + s)*D_MODEL;
    float acc = 0.f;
    #pragma unroll 8
    for (int d = 0; d < D_MODEL; ++d) acc += q[d]*kf[d];
    acc *= SM_SCALE;
    red[s] = acc; __syncthreads();
    for (int o = 64; o > 0; o >>= 1) { if (s < o) red[s] = fmaxf(red[s], red[s+o]); __syncthreads(); }
    float mx = red[0]; __syncthreads();
    float e = expf(acc - mx);
    red[s] = e; __syncthreads();
    for (int o = 64; o > 0; o >>= 1) { if (s < o) red[s] += red[s+o]; __syncthreads(); }
    A2[(size_t)bl*NUM_SLOTS + s] = e / red[0];
}

__global__ __launch_bounds__(256) void k_y(const float* __restrict__ A2,
        const float* __restrict__ Vf, float* __restrict__ Y) {
    int bl = blockIdx.x; int b = bl / SEQ;
    int d = threadIdx.x;
    const float* a = A2 + (size_t)bl*NUM_SLOTS;
    const float* v = Vf + (size_t)b*NUM_SLOTS*D_MODEL + d;
    float acc = 0.f;
    #pragma unroll 4
    for (int s = 0; s < NUM_SLOTS; ++s) acc += a[s]*v[(size_t)s*D_MODEL];
    Y[(size_t)bl*D_MODEL + d] = acc;
}

extern "C" void kernel_launch(void* const* d_in, const int* in_sizes, int n_in,
                              void* d_out, int out_size, void* d_ws, size_t ws_size,
                              hipStream_t stream) {
    const int*   ids    = (const int*)d_in[0];
    const int*   amask  = (const int*)d_in[1];
    const float* tok    = (const float*)d_in[2];
    const float* pos    = (const float*)d_in[3];
    const float* Hin    = (const float*)d_in[4];
    const float* Ws     = (const float*)d_in[5];
    const float* Wt     = (const float*)d_in[6];
    const float* Wq_in  = (const float*)d_in[7];
    const float* Wk_sl  = (const float*)d_in[8];
    const float* Wv_in  = (const float*)d_in[9];
    const float* Wq_out = (const float*)d_in[10];
    const float* Wk_fin = (const float*)d_in[11];
    const float* Wv_fin = (const float*)d_in[12];
    const float* Wop    = (const float*)d_in[13];
    const float* lnsc   = (const float*)d_in[14];
    const float* lnbs   = (const float*)d_in[15];
    float* out = (float*)d_out;

    const size_t WF_USH = (size_t)16384 * 16384;     // 512 MiB of ushorts
    const size_t F32_FLOATS = 18449408ULL;           // fp32 scratch region
    const bool useF16 = ws_size >= WF_USH*2 + F32_FLOATS*4 + 256;

    unsigned short* WF = (unsigned short*)d_ws;
    float* ws = useF16 ? (float*)(WF + WF_USH) : (float*)d_ws;

    float* X    = ws;
    float* Qin  = X    + (size_t)NTOK*D_MODEL;
    float* Vin  = Qin  + (size_t)NTOK*D_MODEL;
    float* Ksl  = Vin  + (size_t)NTOK*D_MODEL;
    float* Asc  = Ksl  + (size_t)NUM_SLOTS*D_MODEL;
    float* cs   = Asc  + (size_t)NTOK*NUM_SLOTS;
    float* Hst  = cs   + (size_t)BATCH*NUM_SLOTS;
    float* part = Hst  + (size_t)BATCH*NUM_SLOTS*D_MODEL;
    float* Qout = part + (size_t)IGROUPS*BATCH*NUM_SLOTS*D_MODEL;
    float* Kf   = Qout + (size_t)NTOK*D_MODEL;
    float* Vf   = Kf   + (size_t)BATCH*NUM_SLOTS*D_MODEL;
    float* A2   = Vf   + (size_t)BATCH*NUM_SLOTS*D_MODEL;
    float* Yb   = A2   + (size_t)NTOK*NUM_SLOTS;
    unsigned short* Yh = (unsigned short*)(Yb + (size_t)NTOK*D_MODEL);
    unsigned short* Yl = Yh + (size_t)NTOK*D_MODEL;
    unsigned short* Wh = Yl + (size_t)NTOK*D_MODEL;
    unsigned short* Wl = Wh + (size_t)VOCAB*D_MODEL;

    // one-time weight conversions (independent of the rest)
    if (useF16) {
        k_convert_s<<<dim3(128, 128, 2), 256, 0, stream>>>(Ws, WF);
        k_convert_t<<<dim3(128, 128, 2), 256, 0, stream>>>(Wt, WF);
    }
    k_split<<<(VOCAB*D_MODEL/4 + 255)/256, 256, 0, stream>>>(Wop, Wh, Wl, VOCAB*D_MODEL/4);

    // embeddings
    k_embed<<<NTOK, 256, 0, stream>>>(ids, tok, pos, X);
    // compress projections
    k_gemm_nt<<<dim3(NTOK/64, 4), 256, 0, stream>>>(X, Wq_in, Qin, NTOK, D_MODEL, D_MODEL);
    k_gemm_nt<<<dim3(2, 4),       256, 0, stream>>>(Hin, Wk_sl, Ksl, NUM_SLOTS, D_MODEL, D_MODEL);
    k_gemm_nt<<<dim3(NTOK/64, 4), 256, 0, stream>>>(X, Wv_in, Vin, NTOK, D_MODEL, D_MODEL);
    // scores + softmax + mask
    k_gemm_nt<<<dim3(NTOK/64, 2), 256, 0, stream>>>(Qin, Ksl, Asc, NTOK, NUM_SLOTS, D_MODEL);
    k_softmax_mask<<<NTOK, 128, 0, stream>>>(Asc, amask);
    // column-normalize + aggregate into slots
    k_colsum<<<BATCH, 128, 0, stream>>>(Asc, cs);
    k_ir<<<BATCH*NUM_SLOTS, 256, 0, stream>>>(Asc, Vin, Hin, cs, Hst);
    // bilinear slot-interaction steps
    for (int st = 0; st < N_STEPS; ++st) {
        if (useF16)
            k_pairs_mfma<<<dim3(NUM_SLOTS, IGROUPS), 256, 0, stream>>>(Hst, WF, part);
        else
            k_pairs<<<dim3(NUM_SLOTS, IGROUPS), 256, 0, stream>>>(Hst, Ws, Wt, part);
        k_ln<<<BATCH*NUM_SLOTS, 256, 0, stream>>>(Hst, part, lnsc + st*D_MODEL, lnbs + st*D_MODEL);
    }
    // expand projections
    k_gemm_nt<<<dim3(NTOK/64, 4), 256, 0, stream>>>(X, Wq_out, Qout, NTOK, D_MODEL, D_MODEL);
    k_gemm_nt<<<dim3(BATCH*NUM_SLOTS/64, 4), 256, 0, stream>>>(Hst, Wk_fin, Kf, BATCH*NUM_SLOTS, D_MODEL, D_MODEL);
    k_gemm_nt<<<dim3(BATCH*NUM_SLOTS/64, 4), 256, 0, stream>>>(Hst, Wv_fin, Vf, BATCH*NUM_SLOTS, D_MODEL, D_MODEL);
    // expand attention
    k_attn2<<<NTOK, 128, 0, stream>>>(Qout, Kf, A2);
    k_y<<<NTOK, 256, 0, stream>>>(A2, Vf, Yb);
    // logits
    k_split<<<(NTOK*D_MODEL/4 + 255)/256, 256, 0, stream>>>(Yb, Yh, Yl, NTOK*D_MODEL/4);
    k_logits<<<dim3(NTOK/128, VOCAB/128), 256, 0, stream>>>(Yh, Yl, Wh, Wl, out);
}

// Round 6
// 1586.431 us; speedup vs baseline: 1.2795x; 1.2795x over previous
//
#include <hip/hip_runtime.h>
#include <hip/hip_bf16.h>
#include <math.h>

#define D_MODEL 256
#define NUM_SLOTS 128
#define RANK 32
#define N_STEPS 6
#define VOCAB 32000
#define SEQ 512
#define BATCH 8
#define NTOK (BATCH*SEQ)
#define LN_EPS 1e-5f
#define SM_SCALE 0.0625f
#define IGROUPS 8
#define IPG (NUM_SLOTS/IGROUPS)

typedef __attribute__((ext_vector_type(8))) short bf16x8;
typedef __attribute__((ext_vector_type(8))) _Float16 f16x8;
typedef __attribute__((ext_vector_type(4))) float f32x4;

#define GLD_LDS16(g, l) __builtin_amdgcn_global_load_lds( \
    (const __attribute__((address_space(1))) unsigned int*)(g), \
    (__attribute__((address_space(3))) unsigned int*)(l), 16, 0, 0)

__device__ inline unsigned short f2bf(float x) {
    unsigned u = __float_as_uint(x);
    unsigned r = u + 0x7fff + ((u >> 16) & 1);
    return (unsigned short)(r >> 16);
}
__device__ inline float bf2f(unsigned short h) {
    return __uint_as_float(((unsigned)h) << 16);
}
__device__ inline unsigned pk2(float a, float b) {
    auto v = __builtin_amdgcn_cvt_pkrtz(a, b);
    union { decltype(v) x; unsigned u; } c;
    c.x = v;
    return c.u;
}
__device__ inline unsigned short f2h(float x) {
    union { _Float16 h; unsigned short u; } c;
    c.h = (_Float16)x;
    return c.u;
}

// X[b,l,:] = token_emb[ids[b,l],:] + pos_emb[l,:]
__global__ __launch_bounds__(256) void k_embed(const int* __restrict__ ids,
        const float* __restrict__ tok, const float* __restrict__ pos,
        float* __restrict__ X) {
    int bl = blockIdx.x;
    int d  = threadIdx.x;
    int l  = bl % SEQ;
    int id = ids[bl];
    X[(size_t)bl*D_MODEL + d] = tok[(size_t)id*D_MODEL + d] + pos[l*D_MODEL + d];
}

// C[m,n] = sum_k A[m,k]*B[n,k]   (both row-major, K contiguous)  64x64 tile
__global__ __launch_bounds__(256) void k_gemm_nt(const float* __restrict__ A,
        const float* __restrict__ B, float* __restrict__ C, int M, int N, int K) {
    __shared__ float As[32][64];
    __shared__ float Bs[32][64];
    int bm = blockIdx.x * 64, bn = blockIdx.y * 64;
    int t = threadIdx.x;
    int tm = (t & 15) * 4, tn = (t >> 4) * 4;
    float acc[4][4] = {};
    for (int k0 = 0; k0 < K; k0 += 32) {
        #pragma unroll
        for (int r = 0; r < 8; ++r) {
            int idx = r*256 + t;
            int m = idx >> 5, k = idx & 31;
            As[k][m] = A[(size_t)(bm+m)*K + k0 + k];
        }
        #pragma unroll
        for (int r = 0; r < 8; ++r) {
            int idx = r*256 + t;
            int n = idx >> 5, k = idx & 31;
            Bs[k][n] = B[(size_t)(bn+n)*K + k0 + k];
        }
        __syncthreads();
        #pragma unroll
        for (int k = 0; k < 32; ++k) {
            float4 a4 = *(const float4*)&As[k][tm];
            float4 b4 = *(const float4*)&Bs[k][tn];
            float a[4] = {a4.x,a4.y,a4.z,a4.w};
            float b[4] = {b4.x,b4.y,b4.z,b4.w};
            #pragma unroll
            for (int i = 0; i < 4; ++i)
                #pragma unroll
                for (int jj = 0; jj < 4; ++jj)
                    acc[i][jj] += a[i]*b[jj];
        }
        __syncthreads();
    }
    #pragma unroll
    for (int i = 0; i < 4; ++i) {
        float4 v = make_float4(acc[i][0],acc[i][1],acc[i][2],acc[i][3]);
        *(float4*)&C[(size_t)(bm+tm+i)*N + bn+tn] = v;
    }
}

// split fp32 -> bf16 hi + bf16 lo
__global__ __launch_bounds__(256) void k_split(const float* __restrict__ in,
        unsigned short* __restrict__ hi, unsigned short* __restrict__ lo, int n4) {
    int i = blockIdx.x*256 + threadIdx.x;
    if (i >= n4) return;
    float4 v = ((const float4*)in)[i];
    float f[4] = {v.x, v.y, v.z, v.w};
    ushort4 h, lw;
    unsigned short* hp = &h.x; unsigned short* lp = &lw.x;
    #pragma unroll
    for (int j = 0; j < 4; ++j) {
        unsigned short hb = f2bf(f[j]);
        hp[j] = hb;
        lp[j] = f2bf(f[j] - bf2f(hb));
    }
    ((ushort4*)hi)[i] = h;
    ((ushort4*)lo)[i] = lw;
}

// logits GEMM: 3-pass split-bf16 MFMA
__global__ __launch_bounds__(256) void k_logits(
        const unsigned short* __restrict__ Ahg, const unsigned short* __restrict__ Alg,
        const unsigned short* __restrict__ Bhg, const unsigned short* __restrict__ Blg,
        float* __restrict__ C) {
    __shared__ short lds[4*128*64];
    short* Ah = lds;
    short* Al = lds + 8192;
    short* Bh = lds + 16384;
    short* Bl = lds + 24576;
    int bm = blockIdx.x * 128, bn = blockIdx.y * 128;
    int t = threadIdx.x;
    int w = t >> 6, l = t & 63;
    int wr = w >> 1, wc = w & 1;
    int lr = l & 15, lk = l >> 4;
    f32x4 acc[4][4];
    #pragma unroll
    for (int mi = 0; mi < 4; ++mi)
        #pragma unroll
        for (int ni = 0; ni < 4; ++ni)
            acc[mi][ni] = (f32x4){0.f,0.f,0.f,0.f};

    for (int kc = 0; kc < 4; ++kc) {
        #pragma unroll
        for (int i = 0; i < 4; ++i) {
            int v = t + i*256;
            int row = v >> 3, cv = v & 7;
            int so = row*64 + ((cv ^ (row & 7)) << 3);
            size_t ga = (size_t)(bm+row)*256 + kc*64 + cv*8;
            size_t gb = (size_t)(bn+row)*256 + kc*64 + cv*8;
            *(bf16x8*)&Ah[so] = *(const bf16x8*)&Ahg[ga];
            *(bf16x8*)&Al[so] = *(const bf16x8*)&Alg[ga];
            *(bf16x8*)&Bh[so] = *(const bf16x8*)&Bhg[gb];
            *(bf16x8*)&Bl[so] = *(const bf16x8*)&Blg[gb];
        }
        __syncthreads();
        #pragma unroll
        for (int s = 0; s < 2; ++s) {
            bf16x8 ah[4], al[4], bh[4], bl[4];
            #pragma unroll
            for (int mi = 0; mi < 4; ++mi) {
                int row = wr*64 + mi*16 + lr;
                int off = row*64 + ((((s<<2)+lk) ^ (row&7)) << 3);
                ah[mi] = *(bf16x8*)&Ah[off];
                al[mi] = *(bf16x8*)&Al[off];
            }
            #pragma unroll
            for (int ni = 0; ni < 4; ++ni) {
                int row = wc*64 + ni*16 + lr;
                int off = row*64 + ((((s<<2)+lk) ^ (row&7)) << 3);
                bh[ni] = *(bf16x8*)&Bh[off];
                bl[ni] = *(bf16x8*)&Bl[off];
            }
            #pragma unroll
            for (int mi = 0; mi < 4; ++mi)
                #pragma unroll
                for (int ni = 0; ni < 4; ++ni) {
                    acc[mi][ni] = __builtin_amdgcn_mfma_f32_16x16x32_bf16(ah[mi], bh[ni], acc[mi][ni], 0, 0, 0);
                    acc[mi][ni] = __builtin_amdgcn_mfma_f32_16x16x32_bf16(ah[mi], bl[ni], acc[mi][ni], 0, 0, 0);
                    acc[mi][ni] = __builtin_amdgcn_mfma_f32_16x16x32_bf16(al[mi], bh[ni], acc[mi][ni], 0, 0, 0);
                }
        }
        __syncthreads();
    }
    #pragma unroll
    for (int mi = 0; mi < 4; ++mi)
        #pragma unroll
        for (int ni = 0; ni < 4; ++ni) {
            int col = bn + wc*64 + ni*16 + lr;
            #pragma unroll
            for (int r = 0; r < 4; ++r) {
                int row = bm + wr*64 + mi*16 + lk*4 + r;
                C[(size_t)row*VOCAB + col] = acc[mi][ni][r];
            }
        }
}

__global__ __launch_bounds__(128) void k_softmax_mask(float* __restrict__ A,
        const int* __restrict__ mask) {
    int row = blockIdx.x;
    int s = threadIdx.x;
    __shared__ float red[128];
    float v = A[(size_t)row*NUM_SLOTS + s] * SM_SCALE;
    red[s] = v; __syncthreads();
    for (int o = 64; o > 0; o >>= 1) { if (s < o) red[s] = fmaxf(red[s], red[s+o]); __syncthreads(); }
    float mx = red[0]; __syncthreads();
    float e = expf(v - mx);
    red[s] = e; __syncthreads();
    for (int o = 64; o > 0; o >>= 1) { if (s < o) red[s] += red[s+o]; __syncthreads(); }
    float sum = red[0];
    float m = (float)mask[row];
    A[(size_t)row*NUM_SLOTS + s] = e / sum * m;
}

__global__ __launch_bounds__(128) void k_colsum(const float* __restrict__ A,
        float* __restrict__ cs) {
    int b = blockIdx.x; int s = threadIdx.x;
    const float* Ab = A + (size_t)b*SEQ*NUM_SLOTS + s;
    float acc = 0.f;
    for (int l = 0; l < SEQ; ++l) acc += Ab[(size_t)l*NUM_SLOTS];
    cs[b*NUM_SLOTS + s] = acc + 1e-8f;
}

// H_state = H + IR; writes fp32 and fp16 copies
__global__ __launch_bounds__(256) void k_ir(const float* __restrict__ A,
        const float* __restrict__ V, const float* __restrict__ H,
        const float* __restrict__ cs, float* __restrict__ Hs,
        unsigned short* __restrict__ Hs16) {
    int bs = blockIdx.x; int b = bs >> 7; int s = bs & 127;
    int d = threadIdx.x;
    float inv = 1.0f / cs[bs];
    const float* Ab = A + (size_t)b*SEQ*NUM_SLOTS + s;
    const float* Vb = V + (size_t)b*SEQ*D_MODEL + d;
    float acc = 0.f;
    for (int l = 0; l < SEQ; ++l) acc += Ab[(size_t)l*NUM_SLOTS] * Vb[(size_t)l*D_MODEL];
    float v = H[s*D_MODEL + d] + acc * inv;
    Hs[(size_t)bs*D_MODEL + d] = v;
    Hs16[(size_t)bs*D_MODEL + d] = f2h(v);
}

// ---- one-time fp32->fp16 weight conversion into MFMA fragment order ----
// WF layout per pair p=(j*128+i): [0:8192) ushorts = Ws frags (A-op of pass1),
// chunk ((ks*2+mt)*64+l): e -> Ws[i,j][d=ks*32+(l>>4)*8+e][r=mt*16+(l&15)]
// [8192:16384) = Wt frags (B-op of pass2),
// chunk (nt*64+l): e -> Wt[i,j][r=(l>>4)*8+e][d=nt*16+(l&15)]

// Ws half: blockIdx.z = hf handles d in [hf*128, hf*128+128)
__global__ __launch_bounds__(256) void k_convert_s(const float* __restrict__ Ws,
        unsigned short* __restrict__ WF) {
    int i = blockIdx.x, j = blockIdx.y, hf = blockIdx.z;
    int t = threadIdx.x;
    __shared__ float lds[128*33];
    size_t sBase = ((size_t)i*128 + j)*8192;
    size_t pOut = ((size_t)j*128 + i)*16384;
    const float4* s4 = (const float4*)(Ws + sBase) + hf*1024;
    #pragma unroll
    for (int p = 0; p < 4; ++p) {
        int f4 = p*256 + t;
        float4 v = s4[f4];
        *(float4*)&lds[(f4 >> 3)*33 + 4*(f4 & 7)] = v;
    }
    __syncthreads();
    bool diag = (i == j);
    #pragma unroll
    for (int q = 0; q < 2; ++q) {
        int cl = q*256 + t;
        int ksl = cl >> 7, mt = (cl >> 6) & 1, l = cl & 63;
        int g = l >> 4, c = l & 15;
        union { f16x8 v; } o;
        #pragma unroll
        for (int e = 0; e < 8; ++e) {
            float f = diag ? 0.f : lds[(ksl*32 + g*8 + e)*33 + mt*16 + c];
            o.v[e] = (_Float16)f;
        }
        *(f16x8*)(WF + pOut + (size_t)hf*4096 + (size_t)cl*8) = o.v;
    }
}

// Wt half: blockIdx.z = hf handles d in [hf*128, hf*128+128)
__global__ __launch_bounds__(256) void k_convert_t(const float* __restrict__ Wt,
        unsigned short* __restrict__ WF) {
    int i = blockIdx.x, j = blockIdx.y, hf = blockIdx.z;
    int t = threadIdx.x;
    __shared__ float lds[32*133];
    size_t sBase = ((size_t)i*128 + j)*8192;
    size_t pOut = ((size_t)j*128 + i)*16384;
    const float4* s4 = (const float4*)(Wt + sBase);
    #pragma unroll
    for (int p = 0; p < 4; ++p) {
        int idx = p*256 + t;
        int r = idx >> 5, c4 = idx & 31;
        float4 v = s4[r*64 + hf*32 + c4];
        *(float4*)&lds[r*133 + c4*4] = v;
    }
    __syncthreads();
    #pragma unroll
    for (int q = 0; q < 2; ++q) {
        int cl = q*256 + t;
        int ntl = cl >> 6, l = cl & 63;
        int g = l >> 4, c = l & 15;
        union { f16x8 v; } o;
        #pragma unroll
        for (int e = 0; e < 8; ++e)
            o.v[e] = (_Float16)lds[(g*8 + e)*133 + ntl*16 + c];
        *(f16x8*)(WF + pOut + 8192 + (size_t)hf*4096 + (size_t)cl*8) = o.v;
    }
}

// ---- hybrid MFMA slot-pair kernel: block (j, g) accumulates 16 i's ----
// Ws A-frags: staged once per block into 16KB LDS (double-buffered, 32KB total)
// via global_load_lds — shared by all 4 waves, no redundant HBM/L2 requests.
// Wt B-frags: wave-private quarter, direct global->VGPR.
// h: pre-converted fp16 (h16), direct global->VGPR (L2-resident).
__global__ __launch_bounds__(256) void k_pairs_mfma(const unsigned short* __restrict__ h16,
        const unsigned short* __restrict__ WF, float* __restrict__ part) {
    __shared__ unsigned short lds[2*8192];   // 2 x 16KB Ws-frag double buffer
    int j = blockIdx.x, g = blockIdx.y;
    int t = threadIdx.x, w = t >> 6, l = t & 63;
    int lg = l >> 4, c = l & 15;
    const unsigned short* pbase = WF + ((size_t)j*128 + g*16)*16384;
    // prologue: stage ii=0 Ws frags into buf 0
    #pragma unroll
    for (int q = 0; q < 4; ++q)
        GLD_LDS16(pbase + (size_t)(q*256 + t)*8, &lds[(q*256 + t)*8]);
    f32x4 acc[4];
    #pragma unroll
    for (int nt = 0; nt < 4; ++nt) acc[nt] = (f32x4){0.f,0.f,0.f,0.f};

    #pragma unroll 2
    for (int ii = 0; ii < 16; ++ii) {
        int cur = ii & 1;
        __syncthreads();    // stage(cur) drained; all waves done with prev buf
        if (ii < 15) {
            const unsigned short* src = pbase + (size_t)(ii+1)*16384;
            unsigned short* dst = &lds[(cur^1)*8192];
            #pragma unroll
            for (int q = 0; q < 4; ++q)
                GLD_LDS16(src + (size_t)(q*256 + t)*8, dst + (size_t)(q*256 + t)*8);
        }
        // Wt B-frags (wave w owns d-tiles w*4..w*4+3), direct to registers
        const unsigned short* bp = pbase + (size_t)ii*16384 + 8192;
        f16x8 bq[4];
        #pragma unroll
        for (int nt = 0; nt < 4; ++nt)
            bq[nt] = *(const f16x8*)(bp + (size_t)((w*4+nt)*64 + l)*8);
        // h B-frags from fp16 copy (zero pad rows b>=8)
        f16x8 hb[8];
        if (c < 8) {
            const unsigned short* hrow = h16 + ((size_t)c*NUM_SLOTS + (g*16+ii))*D_MODEL + lg*8;
            #pragma unroll
            for (int ks = 0; ks < 8; ++ks)
                hb[ks] = *(const f16x8*)(hrow + ks*32);
        } else {
            #pragma unroll
            for (int ks = 0; ks < 8; ++ks)
                #pragma unroll
                for (int e = 0; e < 8; ++e) hb[ks][e] = (_Float16)0.f;
        }
        // pass1: interT[r=0..31][b] = sum_d WsT[r][d] h[b][d]
        f32x4 d1[2];
        d1[0] = (f32x4){0.f,0.f,0.f,0.f};
        d1[1] = (f32x4){0.f,0.f,0.f,0.f};
        const unsigned short* buf = &lds[cur*8192];
        #pragma unroll
        for (int ks = 0; ks < 8; ++ks) {
            f16x8 a0 = *(const f16x8*)(buf + (size_t)((ks*2+0)*64 + l)*8);
            f16x8 a1 = *(const f16x8*)(buf + (size_t)((ks*2+1)*64 + l)*8);
            d1[0] = __builtin_amdgcn_mfma_f32_16x16x32_f16(a0, hb[ks], d1[0], 0, 0, 0);
            d1[1] = __builtin_amdgcn_mfma_f32_16x16x32_f16(a1, hb[ks], d1[1], 0, 0, 0);
        }
        // pack interT to fp16 pairs, shuffle into pass2 A-frag
        unsigned q0 = pk2(d1[0][0], d1[0][1]);
        unsigned q1 = pk2(d1[0][2], d1[0][3]);
        unsigned s0 = pk2(d1[1][0], d1[1][1]);
        unsigned s1 = pk2(d1[1][2], d1[1][3]);
        int srcLo = 32*(lg & 1) + c;
        int srcHi = srcLo + 16;
        unsigned a0s = (unsigned)__shfl((int)q0, srcLo, 64);
        unsigned a1s = (unsigned)__shfl((int)q1, srcLo, 64);
        unsigned a2s = (unsigned)__shfl((int)q0, srcHi, 64);
        unsigned a3s = (unsigned)__shfl((int)q1, srcHi, 64);
        unsigned b0s = (unsigned)__shfl((int)s0, srcLo, 64);
        unsigned b1s = (unsigned)__shfl((int)s1, srcLo, 64);
        unsigned b2s = (unsigned)__shfl((int)s0, srcHi, 64);
        unsigned b3s = (unsigned)__shfl((int)s1, srcHi, 64);
        bool himt = ((lg >> 1) & 1);
        union { unsigned u[4]; f16x8 v; } A2u;
        A2u.u[0] = himt ? b0s : a0s;
        A2u.u[1] = himt ? b1s : a1s;
        A2u.u[2] = himt ? b2s : a2s;
        A2u.u[3] = himt ? b3s : a3s;
        // pass2: out[b][d] += sum_r inter[b][r] Wt[r][d]
        #pragma unroll
        for (int nt = 0; nt < 4; ++nt)
            acc[nt] = __builtin_amdgcn_mfma_f32_16x16x32_f16(A2u.v, bq[nt], acc[nt], 0, 0, 0);
    }
    // store: lanes lg<2 hold rows b = lg*4+reg (0..7)
    if (lg < 2) {
        #pragma unroll
        for (int nt = 0; nt < 4; ++nt) {
            int d = (w*4 + nt)*16 + c;
            #pragma unroll
            for (int r = 0; r < 4; ++r) {
                int b = lg*4 + r;
                part[(((size_t)g*BATCH + b)*NUM_SLOTS + j)*D_MODEL + d] = acc[nt][r];
            }
        }
    }
}

// fallback fp32 pairs kernel (used when ws too small for WF)
__global__ __launch_bounds__(256) void k_pairs(const float* __restrict__ h,
        const float* __restrict__ Ws, const float* __restrict__ Wt,
        float* __restrict__ part) {
    int j = blockIdx.x;
    int g = blockIdx.y;
    int t = threadIdx.x;
    __shared__ float sh_h[BATCH][D_MODEL];
    __shared__ float sh_inter[BATCH][RANK];
    float acc[BATCH];
    #pragma unroll
    for (int b = 0; b < BATCH; ++b) acc[b] = 0.f;
    int tb = t >> 5, tr = t & 31;
    for (int ii = 0; ii < IPG; ++ii) {
        int i = g*IPG + ii;
        if (i == j) continue;
        #pragma unroll
        for (int b = 0; b < BATCH; ++b)
            sh_h[b][t] = h[((size_t)b*NUM_SLOTS + i)*D_MODEL + t];
        __syncthreads();
        const float* ws = Ws + ((size_t)i*NUM_SLOTS + j)*(D_MODEL*RANK);
        float accA = 0.f;
        #pragma unroll 8
        for (int d = 0; d < D_MODEL; ++d)
            accA += sh_h[tb][d] * ws[(size_t)d*RANK + tr];
        sh_inter[tb][tr] = accA;
        __syncthreads();
        const float* wt = Wt + ((size_t)i*NUM_SLOTS + j)*(RANK*D_MODEL);
        #pragma unroll 8
        for (int r = 0; r < RANK; ++r) {
            float w = wt[(size_t)r*D_MODEL + t];
            #pragma unroll
            for (int b = 0; b < BATCH; ++b) acc[b] += sh_inter[b][r] * w;
        }
        __syncthreads();
    }
    #pragma unroll
    for (int b = 0; b < BATCH; ++b)
        part[(((size_t)g*BATCH + b)*NUM_SLOTS + j)*D_MODEL + t] = acc[b];
}

// h = LN(h + relu(sum_g part)); writes fp32 and fp16 copies
__global__ __launch_bounds__(256) void k_ln(float* __restrict__ h,
        unsigned short* __restrict__ h16, const float* __restrict__ part,
        const float* __restrict__ gma, const float* __restrict__ bta) {
    int bj = blockIdx.x;
    int t = threadIdx.x;
    int b = bj >> 7, j = bj & 127;
    __shared__ float red[256];
    float v = 0.f;
    #pragma unroll
    for (int g = 0; g < IGROUPS; ++g)
        v += part[(((size_t)g*BATCH + b)*NUM_SLOTS + j)*D_MODEL + t];
    float x = h[(size_t)bj*D_MODEL + t] + fmaxf(v, 0.f);
    red[t] = x; __syncthreads();
    for (int o = 128; o > 0; o >>= 1) { if (t < o) red[t] += red[t+o]; __syncthreads(); }
    float mu = red[0] * (1.0f/D_MODEL); __syncthreads();
    float dx = x - mu;
    red[t] = dx*dx; __syncthreads();
    for (int o = 128; o > 0; o >>= 1) { if (t < o) red[t] += red[t+o]; __syncthreads(); }
    float var = red[0] * (1.0f/D_MODEL);
    float outv = dx * rsqrtf(var + LN_EPS) * gma[t] + bta[t];
    h[(size_t)bj*D_MODEL + t] = outv;
    h16[(size_t)bj*D_MODEL + t] = f2h(outv);
}

__global__ __launch_bounds__(128) void k_attn2(const float* __restrict__ Q,
        const float* __restrict__ Kf, float* __restrict__ A2) {
    int bl = blockIdx.x; int b = bl / SEQ;
    int s = threadIdx.x;
    __shared__ float q[D_MODEL];
    __shared__ float red[128];
    q[s]       = Q[(size_t)bl*D_MODEL + s];
    q[s + 128] = Q[(size_t)bl*D_MODEL + s + 128];
    __syncthreads();
    const float* kf = Kf + ((size_t)b*NUM_SLOTS + s)*D_MODEL;
    float acc = 0.f;
    #pragma unroll 8
    for (int d = 0; d < D_MODEL; ++d) acc += q[d]*kf[d];
    acc *= SM_SCALE;
    red[s] = acc; __syncthreads();
    for (int o = 64; o > 0; o >>= 1) { if (s < o) red[s] = fmaxf(red[s], red[s+o]); __syncthreads(); }
    float mx = red[0]; __syncthreads();
    float e = expf(acc - mx);
    red[s] = e; __syncthreads();
    for (int o = 64; o > 0; o >>= 1) { if (s < o) red[s] += red[s+o]; __syncthreads(); }
    A2[(size_t)bl*NUM_SLOTS + s] = e / red[0];
}

__global__ __launch_bounds__(256) void k_y(const float* __restrict__ A2,
        const float* __restrict__ Vf, float* __restrict__ Y) {
    int bl = blockIdx.x; int b = bl / SEQ;
    int d = threadIdx.x;
    const float* a = A2 + (size_t)bl*NUM_SLOTS;
    const float* v = Vf + (size_t)b*NUM_SLOTS*D_MODEL + d;
    float acc = 0.f;
    #pragma unroll 4
    for (int s = 0; s < NUM_SLOTS; ++s) acc += a[s]*v[(size_t)s*D_MODEL];
    Y[(size_t)bl*D_MODEL + d] = acc;
}

extern "C" void kernel_launch(void* const* d_in, const int* in_sizes, int n_in,
                              void* d_out, int out_size, void* d_ws, size_t ws_size,
                              hipStream_t stream) {
    const int*   ids    = (const int*)d_in[0];
    const int*   amask  = (const int*)d_in[1];
    const float* tok    = (const float*)d_in[2];
    const float* pos    = (const float*)d_in[3];
    const float* Hin    = (const float*)d_in[4];
    const float* Ws     = (const float*)d_in[5];
    const float* Wt     = (const float*)d_in[6];
    const float* Wq_in  = (const float*)d_in[7];
    const float* Wk_sl  = (const float*)d_in[8];
    const float* Wv_in  = (const float*)d_in[9];
    const float* Wq_out = (const float*)d_in[10];
    const float* Wk_fin = (const float*)d_in[11];
    const float* Wv_fin = (const float*)d_in[12];
    const float* Wop    = (const float*)d_in[13];
    const float* lnsc   = (const float*)d_in[14];
    const float* lnbs   = (const float*)d_in[15];
    float* out = (float*)d_out;

    const size_t WF_USH = (size_t)16384 * 16384;     // 512 MiB of ushorts
    const size_t F32_FLOATS = 18580480ULL;           // fp32+bf16+h16 scratch region
    const bool useF16 = ws_size >= WF_USH*2 + F32_FLOATS*4 + 256;

    unsigned short* WF = (unsigned short*)d_ws;
    float* ws = useF16 ? (float*)(WF + WF_USH) : (float*)d_ws;

    float* X    = ws;
    float* Qin  = X    + (size_t)NTOK*D_MODEL;
    float* Vin  = Qin  + (size_t)NTOK*D_MODEL;
    float* Ksl  = Vin  + (size_t)NTOK*D_MODEL;
    float* Asc  = Ksl  + (size_t)NUM_SLOTS*D_MODEL;
    float* cs   = Asc  + (size_t)NTOK*NUM_SLOTS;
    float* Hst  = cs   + (size_t)BATCH*NUM_SLOTS;
    float* part = Hst  + (size_t)BATCH*NUM_SLOTS*D_MODEL;
    float* Qout = part + (size_t)IGROUPS*BATCH*NUM_SLOTS*D_MODEL;
    float* Kf   = Qout + (size_t)NTOK*D_MODEL;
    float* Vf   = Kf   + (size_t)BATCH*NUM_SLOTS*D_MODEL;
    float* A2   = Vf   + (size_t)BATCH*NUM_SLOTS*D_MODEL;
    float* Yb   = A2   + (size_t)NTOK*NUM_SLOTS;
    unsigned short* Yh = (unsigned short*)(Yb + (size_t)NTOK*D_MODEL);
    unsigned short* Yl = Yh + (size_t)NTOK*D_MODEL;
    unsigned short* Wh = Yl + (size_t)NTOK*D_MODEL;
    unsigned short* Wl = Wh + (size_t)VOCAB*D_MODEL;
    unsigned short* Hst16 = Wl + (size_t)VOCAB*D_MODEL;

    // one-time weight conversions (independent of the rest)
    if (useF16) {
        k_convert_s<<<dim3(128, 128, 2), 256, 0, stream>>>(Ws, WF);
        k_convert_t<<<dim3(128, 128, 2), 256, 0, stream>>>(Wt, WF);
    }
    k_split<<<(VOCAB*D_MODEL/4 + 255)/256, 256, 0, stream>>>(Wop, Wh, Wl, VOCAB*D_MODEL/4);

    // embeddings
    k_embed<<<NTOK, 256, 0, stream>>>(ids, tok, pos, X);
    // compress projections
    k_gemm_nt<<<dim3(NTOK/64, 4), 256, 0, stream>>>(X, Wq_in, Qin, NTOK, D_MODEL, D_MODEL);
    k_gemm_nt<<<dim3(2, 4),       256, 0, stream>>>(Hin, Wk_sl, Ksl, NUM_SLOTS, D_MODEL, D_MODEL);
    k_gemm_nt<<<dim3(NTOK/64, 4), 256, 0, stream>>>(X, Wv_in, Vin, NTOK, D_MODEL, D_MODEL);
    // scores + softmax + mask
    k_gemm_nt<<<dim3(NTOK/64, 2), 256, 0, stream>>>(Qin, Ksl, Asc, NTOK, NUM_SLOTS, D_MODEL);
    k_softmax_mask<<<NTOK, 128, 0, stream>>>(Asc, amask);
    // column-normalize + aggregate into slots
    k_colsum<<<BATCH, 128, 0, stream>>>(Asc, cs);
    k_ir<<<BATCH*NUM_SLOTS, 256, 0, stream>>>(Asc, Vin, Hin, cs, Hst, Hst16);
    // bilinear slot-interaction steps
    for (int st = 0; st < N_STEPS; ++st) {
        if (useF16)
            k_pairs_mfma<<<dim3(NUM_SLOTS, IGROUPS), 256, 0, stream>>>(Hst16, WF, part);
        else
            k_pairs<<<dim3(NUM_SLOTS, IGROUPS), 256, 0, stream>>>(Hst, Ws, Wt, part);
        k_ln<<<BATCH*NUM_SLOTS, 256, 0, stream>>>(Hst, Hst16, part, lnsc + st*D_MODEL, lnbs + st*D_MODEL);
    }
    // expand projections
    k_gemm_nt<<<dim3(NTOK/64, 4), 256, 0, stream>>>(X, Wq_out, Qout, NTOK, D_MODEL, D_MODEL);
    k_gemm_nt<<<dim3(BATCH*NUM_SLOTS/64, 4), 256, 0, stream>>>(Hst, Wk_fin, Kf, BATCH*NUM_SLOTS, D_MODEL, D_MODEL);
    k_gemm_nt<<<dim3(BATCH*NUM_SLOTS/64, 4), 256, 0, stream>>>(Hst, Wv_fin, Vf, BATCH*NUM_SLOTS, D_MODEL, D_MODEL);
    // expand attention
    k_attn2<<<NTOK, 128, 0, stream>>>(Qout, Kf, A2);
    k_y<<<NTOK, 256, 0, stream>>>(A2, Vf, Yb);
    // logits
    k_split<<<(NTOK*D_MODEL/4 + 255)/256, 256, 0, stream>>>(Yb, Yh, Yl, NTOK*D_MODEL/4);
    k_logits<<<dim3(NTOK/128, VOCAB/128), 256, 0, stream>>>(Yh, Yl, Wh, Wl, out);
}

// Round 7
// 1556.697 us; speedup vs baseline: 1.3040x; 1.0191x over previous
//
#include <hip/hip_runtime.h>
#include <hip/hip_bf16.h>
#include <math.h>

#define D_MODEL 256
#define NUM_SLOTS 128
#define RANK 32
#define N_STEPS 6
#define VOCAB 32000
#define SEQ 512
#define BATCH 8
#define NTOK (BATCH*SEQ)
#define LN_EPS 1e-5f
#define SM_SCALE 0.0625f
#define IGROUPS 8
#define IPG (NUM_SLOTS/IGROUPS)

typedef __attribute__((ext_vector_type(8))) short bf16x8;
typedef __attribute__((ext_vector_type(8))) _Float16 f16x8;
typedef __attribute__((ext_vector_type(4))) float f32x4;

#define GLD_LDS16(g, l) __builtin_amdgcn_global_load_lds( \
    (const __attribute__((address_space(1))) unsigned int*)(g), \
    (__attribute__((address_space(3))) unsigned int*)(l), 16, 0, 0)

__device__ inline unsigned short f2bf(float x) {
    unsigned u = __float_as_uint(x);
    unsigned r = u + 0x7fff + ((u >> 16) & 1);
    return (unsigned short)(r >> 16);
}
__device__ inline float bf2f(unsigned short h) {
    return __uint_as_float(((unsigned)h) << 16);
}
__device__ inline unsigned pk2(float a, float b) {
    auto v = __builtin_amdgcn_cvt_pkrtz(a, b);
    union { decltype(v) x; unsigned u; } c;
    c.x = v;
    return c.u;
}
__device__ inline unsigned short f2h(float x) {
    union { _Float16 h; unsigned short u; } c;
    c.h = (_Float16)x;
    return c.u;
}

// X[b,l,:] = token_emb[ids[b,l],:] + pos_emb[l,:]
__global__ __launch_bounds__(256) void k_embed(const int* __restrict__ ids,
        const float* __restrict__ tok, const float* __restrict__ pos,
        float* __restrict__ X) {
    int bl = blockIdx.x;
    int d  = threadIdx.x;
    int l  = bl % SEQ;
    int id = ids[bl];
    X[(size_t)bl*D_MODEL + d] = tok[(size_t)id*D_MODEL + d] + pos[l*D_MODEL + d];
}

// C[m,n] = sum_k A[m,k]*B[n,k]   (both row-major, K contiguous)  64x64 tile
__global__ __launch_bounds__(256) void k_gemm_nt(const float* __restrict__ A,
        const float* __restrict__ B, float* __restrict__ C, int M, int N, int K) {
    __shared__ float As[32][64];
    __shared__ float Bs[32][64];
    int bm = blockIdx.x * 64, bn = blockIdx.y * 64;
    int t = threadIdx.x;
    int tm = (t & 15) * 4, tn = (t >> 4) * 4;
    float acc[4][4] = {};
    for (int k0 = 0; k0 < K; k0 += 32) {
        #pragma unroll
        for (int r = 0; r < 8; ++r) {
            int idx = r*256 + t;
            int m = idx >> 5, k = idx & 31;
            As[k][m] = A[(size_t)(bm+m)*K + k0 + k];
        }
        #pragma unroll
        for (int r = 0; r < 8; ++r) {
            int idx = r*256 + t;
            int n = idx >> 5, k = idx & 31;
            Bs[k][n] = B[(size_t)(bn+n)*K + k0 + k];
        }
        __syncthreads();
        #pragma unroll
        for (int k = 0; k < 32; ++k) {
            float4 a4 = *(const float4*)&As[k][tm];
            float4 b4 = *(const float4*)&Bs[k][tn];
            float a[4] = {a4.x,a4.y,a4.z,a4.w};
            float b[4] = {b4.x,b4.y,b4.z,b4.w};
            #pragma unroll
            for (int i = 0; i < 4; ++i)
                #pragma unroll
                for (int jj = 0; jj < 4; ++jj)
                    acc[i][jj] += a[i]*b[jj];
        }
        __syncthreads();
    }
    #pragma unroll
    for (int i = 0; i < 4; ++i) {
        float4 v = make_float4(acc[i][0],acc[i][1],acc[i][2],acc[i][3]);
        *(float4*)&C[(size_t)(bm+tm+i)*N + bn+tn] = v;
    }
}

// split fp32 -> bf16 hi + bf16 lo
__global__ __launch_bounds__(256) void k_split(const float* __restrict__ in,
        unsigned short* __restrict__ hi, unsigned short* __restrict__ lo, int n4) {
    int i = blockIdx.x*256 + threadIdx.x;
    if (i >= n4) return;
    float4 v = ((const float4*)in)[i];
    float f[4] = {v.x, v.y, v.z, v.w};
    ushort4 h, lw;
    unsigned short* hp = &h.x; unsigned short* lp = &lw.x;
    #pragma unroll
    for (int j = 0; j < 4; ++j) {
        unsigned short hb = f2bf(f[j]);
        hp[j] = hb;
        lp[j] = f2bf(f[j] - bf2f(hb));
    }
    ((ushort4*)hi)[i] = h;
    ((ushort4*)lo)[i] = lw;
}

// logits GEMM: 3-pass split-bf16 MFMA
__global__ __launch_bounds__(256) void k_logits(
        const unsigned short* __restrict__ Ahg, const unsigned short* __restrict__ Alg,
        const unsigned short* __restrict__ Bhg, const unsigned short* __restrict__ Blg,
        float* __restrict__ C) {
    __shared__ short lds[4*128*64];
    short* Ah = lds;
    short* Al = lds + 8192;
    short* Bh = lds + 16384;
    short* Bl = lds + 24576;
    int bm = blockIdx.x * 128, bn = blockIdx.y * 128;
    int t = threadIdx.x;
    int w = t >> 6, l = t & 63;
    int wr = w >> 1, wc = w & 1;
    int lr = l & 15, lk = l >> 4;
    f32x4 acc[4][4];
    #pragma unroll
    for (int mi = 0; mi < 4; ++mi)
        #pragma unroll
        for (int ni = 0; ni < 4; ++ni)
            acc[mi][ni] = (f32x4){0.f,0.f,0.f,0.f};

    for (int kc = 0; kc < 4; ++kc) {
        #pragma unroll
        for (int i = 0; i < 4; ++i) {
            int v = t + i*256;
            int row = v >> 3, cv = v & 7;
            int so = row*64 + ((cv ^ (row & 7)) << 3);
            size_t ga = (size_t)(bm+row)*256 + kc*64 + cv*8;
            size_t gb = (size_t)(bn+row)*256 + kc*64 + cv*8;
            *(bf16x8*)&Ah[so] = *(const bf16x8*)&Ahg[ga];
            *(bf16x8*)&Al[so] = *(const bf16x8*)&Alg[ga];
            *(bf16x8*)&Bh[so] = *(const bf16x8*)&Bhg[gb];
            *(bf16x8*)&Bl[so] = *(const bf16x8*)&Blg[gb];
        }
        __syncthreads();
        #pragma unroll
        for (int s = 0; s < 2; ++s) {
            bf16x8 ah[4], al[4], bh[4], bl[4];
            #pragma unroll
            for (int mi = 0; mi < 4; ++mi) {
                int row = wr*64 + mi*16 + lr;
                int off = row*64 + ((((s<<2)+lk) ^ (row&7)) << 3);
                ah[mi] = *(bf16x8*)&Ah[off];
                al[mi] = *(bf16x8*)&Al[off];
            }
            #pragma unroll
            for (int ni = 0; ni < 4; ++ni) {
                int row = wc*64 + ni*16 + lr;
                int off = row*64 + ((((s<<2)+lk) ^ (row&7)) << 3);
                bh[ni] = *(bf16x8*)&Bh[off];
                bl[ni] = *(bf16x8*)&Bl[off];
            }
            #pragma unroll
            for (int mi = 0; mi < 4; ++mi)
                #pragma unroll
                for (int ni = 0; ni < 4; ++ni) {
                    acc[mi][ni] = __builtin_amdgcn_mfma_f32_16x16x32_bf16(ah[mi], bh[ni], acc[mi][ni], 0, 0, 0);
                    acc[mi][ni] = __builtin_amdgcn_mfma_f32_16x16x32_bf16(ah[mi], bl[ni], acc[mi][ni], 0, 0, 0);
                    acc[mi][ni] = __builtin_amdgcn_mfma_f32_16x16x32_bf16(al[mi], bh[ni], acc[mi][ni], 0, 0, 0);
                }
        }
        __syncthreads();
    }
    #pragma unroll
    for (int mi = 0; mi < 4; ++mi)
        #pragma unroll
        for (int ni = 0; ni < 4; ++ni) {
            int col = bn + wc*64 + ni*16 + lr;
            #pragma unroll
            for (int r = 0; r < 4; ++r) {
                int row = bm + wr*64 + mi*16 + lk*4 + r;
                C[(size_t)row*VOCAB + col] = acc[mi][ni][r];
            }
        }
}

__global__ __launch_bounds__(128) void k_softmax_mask(float* __restrict__ A,
        const int* __restrict__ mask) {
    int row = blockIdx.x;
    int s = threadIdx.x;
    __shared__ float red[128];
    float v = A[(size_t)row*NUM_SLOTS + s] * SM_SCALE;
    red[s] = v; __syncthreads();
    for (int o = 64; o > 0; o >>= 1) { if (s < o) red[s] = fmaxf(red[s], red[s+o]); __syncthreads(); }
    float mx = red[0]; __syncthreads();
    float e = expf(v - mx);
    red[s] = e; __syncthreads();
    for (int o = 64; o > 0; o >>= 1) { if (s < o) red[s] += red[s+o]; __syncthreads(); }
    float sum = red[0];
    float m = (float)mask[row];
    A[(size_t)row*NUM_SLOTS + s] = e / sum * m;
}

__global__ __launch_bounds__(128) void k_colsum(const float* __restrict__ A,
        float* __restrict__ cs) {
    int b = blockIdx.x; int s = threadIdx.x;
    const float* Ab = A + (size_t)b*SEQ*NUM_SLOTS + s;
    float acc = 0.f;
    for (int l = 0; l < SEQ; ++l) acc += Ab[(size_t)l*NUM_SLOTS];
    cs[b*NUM_SLOTS + s] = acc + 1e-8f;
}

// H_state = H + IR; writes fp32 and fp16 copies
__global__ __launch_bounds__(256) void k_ir(const float* __restrict__ A,
        const float* __restrict__ V, const float* __restrict__ H,
        const float* __restrict__ cs, float* __restrict__ Hs,
        unsigned short* __restrict__ Hs16) {
    int bs = blockIdx.x; int b = bs >> 7; int s = bs & 127;
    int d = threadIdx.x;
    float inv = 1.0f / cs[bs];
    const float* Ab = A + (size_t)b*SEQ*NUM_SLOTS + s;
    const float* Vb = V + (size_t)b*SEQ*D_MODEL + d;
    float acc = 0.f;
    for (int l = 0; l < SEQ; ++l) acc += Ab[(size_t)l*NUM_SLOTS] * Vb[(size_t)l*D_MODEL];
    float v = H[s*D_MODEL + d] + acc * inv;
    Hs[(size_t)bs*D_MODEL + d] = v;
    Hs16[(size_t)bs*D_MODEL + d] = f2h(v);
}

// ---- one-time fp32->fp16 weight conversion into MFMA fragment order ----
// WF layout per pair p=(j*128+i): [0:8192) ushorts = Ws frags (A-op of pass1),
// chunk ((ks*2+mt)*64+l): e -> Ws[i,j][d=ks*32+(l>>4)*8+e][r=mt*16+(l&15)]
// [8192:16384) = Wt frags (B-op of pass2),
// chunk (nt*64+l): e -> Wt[i,j][r=(l>>4)*8+e][d=nt*16+(l&15)]

// Ws half: blockIdx.z = hf handles d in [hf*128, hf*128+128)
__global__ __launch_bounds__(256) void k_convert_s(const float* __restrict__ Ws,
        unsigned short* __restrict__ WF) {
    int i = blockIdx.x, j = blockIdx.y, hf = blockIdx.z;
    int t = threadIdx.x;
    __shared__ float lds[128*33];
    size_t sBase = ((size_t)i*128 + j)*8192;
    size_t pOut = ((size_t)j*128 + i)*16384;
    const float4* s4 = (const float4*)(Ws + sBase) + hf*1024;
    #pragma unroll
    for (int p = 0; p < 4; ++p) {
        int f4 = p*256 + t;
        float4 v = s4[f4];
        *(float4*)&lds[(f4 >> 3)*33 + 4*(f4 & 7)] = v;
    }
    __syncthreads();
    bool diag = (i == j);
    #pragma unroll
    for (int q = 0; q < 2; ++q) {
        int cl = q*256 + t;
        int ksl = cl >> 7, mt = (cl >> 6) & 1, l = cl & 63;
        int g = l >> 4, c = l & 15;
        union { f16x8 v; } o;
        #pragma unroll
        for (int e = 0; e < 8; ++e) {
            float f = diag ? 0.f : lds[(ksl*32 + g*8 + e)*33 + mt*16 + c];
            o.v[e] = (_Float16)f;
        }
        *(f16x8*)(WF + pOut + (size_t)hf*4096 + (size_t)cl*8) = o.v;
    }
}

// Wt half: blockIdx.z = hf handles d in [hf*128, hf*128+128)
__global__ __launch_bounds__(256) void k_convert_t(const float* __restrict__ Wt,
        unsigned short* __restrict__ WF) {
    int i = blockIdx.x, j = blockIdx.y, hf = blockIdx.z;
    int t = threadIdx.x;
    __shared__ float lds[32*133];
    size_t sBase = ((size_t)i*128 + j)*8192;
    size_t pOut = ((size_t)j*128 + i)*16384;
    const float4* s4 = (const float4*)(Wt + sBase);
    #pragma unroll
    for (int p = 0; p < 4; ++p) {
        int idx = p*256 + t;
        int r = idx >> 5, c4 = idx & 31;
        float4 v = s4[r*64 + hf*32 + c4];
        *(float4*)&lds[r*133 + c4*4] = v;
    }
    __syncthreads();
    #pragma unroll
    for (int q = 0; q < 2; ++q) {
        int cl = q*256 + t;
        int ntl = cl >> 6, l = cl & 63;
        int g = l >> 4, c = l & 15;
        union { f16x8 v; } o;
        #pragma unroll
        for (int e = 0; e < 8; ++e)
            o.v[e] = (_Float16)lds[(g*8 + e)*133 + ntl*16 + c];
        *(f16x8*)(WF + pOut + 8192 + (size_t)hf*4096 + (size_t)cl*8) = o.v;
    }
}

// ---- MFMA slot-pair kernel, deep-pipelined ----
// Per ii stage (global_load_lds, 20KB): Ws frags 16KB + h fp16 4KB (transposed
// [d16][b] chunks). Wt B-frags register-prefetched one ii ahead. No VMEM load
// is consumed in the iteration it's issued -> latency hidden by body + 4
// co-resident blocks/CU (40KB LDS, VGPR<=128 via launch_bounds).
__global__ __launch_bounds__(256, 4) void k_pairs_mfma(const unsigned short* __restrict__ h16,
        const unsigned short* __restrict__ WF, float* __restrict__ part) {
    __shared__ unsigned short lds[2*10240];   // 2 x (8192 Ws + 2048 h) ushorts = 40KB
    int j = blockIdx.x, g = blockIdx.y;
    int t = threadIdx.x, w = t >> 6, l = t & 63;
    int lg = l >> 4, c = l & 15;
    const unsigned short* pbase = WF + ((size_t)j*128 + g*16)*16384;

    // prologue: stage ii=0 (buf 0) + prefetch Wt frags for ii=0
    {
        const unsigned short* src = pbase;
        #pragma unroll
        for (int q = 0; q < 4; ++q)
            GLD_LDS16(src + (size_t)(q*256 + t)*8, &lds[(q*256 + t)*8]);
        const unsigned short* hsrc = h16 + ((size_t)(t&7)*NUM_SLOTS + g*16)*D_MODEL + (t>>3)*8;
        GLD_LDS16(hsrc, &lds[8192 + t*8]);
    }
    f16x8 bqn[4];
    #pragma unroll
    for (int nt = 0; nt < 4; ++nt)
        bqn[nt] = *(const f16x8*)(pbase + 8192 + (size_t)((w*4+nt)*64 + l)*8);

    f32x4 acc[4];
    #pragma unroll
    for (int nt = 0; nt < 4; ++nt) acc[nt] = (f32x4){0.f,0.f,0.f,0.f};
    f16x8 hzero;
    #pragma unroll
    for (int e = 0; e < 8; ++e) hzero[e] = (_Float16)0.f;

    #pragma unroll 2
    for (int ii = 0; ii < 16; ++ii) {
        int cur = ii & 1;
        __syncthreads();    // stage(ii) drained; all waves done with prev buf
        if (ii < 15) {
            const unsigned short* src = pbase + (size_t)(ii+1)*16384;
            unsigned short* dst = &lds[(cur^1)*10240];
            #pragma unroll
            for (int q = 0; q < 4; ++q)
                GLD_LDS16(src + (size_t)(q*256 + t)*8, dst + (size_t)(q*256 + t)*8);
            const unsigned short* hsrc = h16 + ((size_t)(t&7)*NUM_SLOTS + (g*16+ii+1))*D_MODEL + (t>>3)*8;
            GLD_LDS16(hsrc, dst + 8192 + (size_t)t*8);
        }
        // consume prefetched Wt frags; issue next ii's (consumed NEXT iter)
        f16x8 bq[4];
        #pragma unroll
        for (int nt = 0; nt < 4; ++nt) bq[nt] = bqn[nt];
        if (ii < 15) {
            const unsigned short* bp = pbase + (size_t)(ii+1)*16384 + 8192;
            #pragma unroll
            for (int nt = 0; nt < 4; ++nt)
                bqn[nt] = *(const f16x8*)(bp + (size_t)((w*4+nt)*64 + l)*8);
        }
        // pass1: interT[r=0..31][b] = sum_d WsT[r][d] h[b][d]
        const unsigned short* buf = &lds[cur*10240];
        f32x4 d1[2];
        d1[0] = (f32x4){0.f,0.f,0.f,0.f};
        d1[1] = (f32x4){0.f,0.f,0.f,0.f};
        #pragma unroll
        for (int ks = 0; ks < 8; ++ks) {
            f16x8 a0 = *(const f16x8*)(buf + (size_t)((ks*2+0)*64 + l)*8);
            f16x8 a1 = *(const f16x8*)(buf + (size_t)((ks*2+1)*64 + l)*8);
            // h frag from LDS: chunk (d16=ks*4+lg, b=c); b>=8 rows are zeros
            f16x8 hv = *(const f16x8*)(buf + 8192 + (size_t)(((ks*4+lg)*8 + (c&7)))*8);
            f16x8 hb = (c < 8) ? hv : hzero;
            d1[0] = __builtin_amdgcn_mfma_f32_16x16x32_f16(a0, hb, d1[0], 0, 0, 0);
            d1[1] = __builtin_amdgcn_mfma_f32_16x16x32_f16(a1, hb, d1[1], 0, 0, 0);
        }
        // pack interT to fp16 pairs, shuffle into pass2 A-frag
        unsigned q0 = pk2(d1[0][0], d1[0][1]);
        unsigned q1 = pk2(d1[0][2], d1[0][3]);
        unsigned s0 = pk2(d1[1][0], d1[1][1]);
        unsigned s1 = pk2(d1[1][2], d1[1][3]);
        int srcLo = 32*(lg & 1) + c;
        int srcHi = srcLo + 16;
        unsigned a0s = (unsigned)__shfl((int)q0, srcLo, 64);
        unsigned a1s = (unsigned)__shfl((int)q1, srcLo, 64);
        unsigned a2s = (unsigned)__shfl((int)q0, srcHi, 64);
        unsigned a3s = (unsigned)__shfl((int)q1, srcHi, 64);
        unsigned b0s = (unsigned)__shfl((int)s0, srcLo, 64);
        unsigned b1s = (unsigned)__shfl((int)s1, srcLo, 64);
        unsigned b2s = (unsigned)__shfl((int)s0, srcHi, 64);
        unsigned b3s = (unsigned)__shfl((int)s1, srcHi, 64);
        bool himt = ((lg >> 1) & 1);
        union { unsigned u[4]; f16x8 v; } A2u;
        A2u.u[0] = himt ? b0s : a0s;
        A2u.u[1] = himt ? b1s : a1s;
        A2u.u[2] = himt ? b2s : a2s;
        A2u.u[3] = himt ? b3s : a3s;
        // pass2: out[b][d] += sum_r inter[b][r] Wt[r][d]
        #pragma unroll
        for (int nt = 0; nt < 4; ++nt)
            acc[nt] = __builtin_amdgcn_mfma_f32_16x16x32_f16(A2u.v, bq[nt], acc[nt], 0, 0, 0);
    }
    // store: lanes lg<2 hold rows b = lg*4+reg (0..7)
    if (lg < 2) {
        #pragma unroll
        for (int nt = 0; nt < 4; ++nt) {
            int d = (w*4 + nt)*16 + c;
            #pragma unroll
            for (int r = 0; r < 4; ++r) {
                int b = lg*4 + r;
                part[(((size_t)g*BATCH + b)*NUM_SLOTS + j)*D_MODEL + d] = acc[nt][r];
            }
        }
    }
}

// fallback fp32 pairs kernel (used when ws too small for WF)
__global__ __launch_bounds__(256) void k_pairs(const float* __restrict__ h,
        const float* __restrict__ Ws, const float* __restrict__ Wt,
        float* __restrict__ part) {
    int j = blockIdx.x;
    int g = blockIdx.y;
    int t = threadIdx.x;
    __shared__ float sh_h[BATCH][D_MODEL];
    __shared__ float sh_inter[BATCH][RANK];
    float acc[BATCH];
    #pragma unroll
    for (int b = 0; b < BATCH; ++b) acc[b] = 0.f;
    int tb = t >> 5, tr = t & 31;
    for (int ii = 0; ii < IPG; ++ii) {
        int i = g*IPG + ii;
        if (i == j) continue;
        #pragma unroll
        for (int b = 0; b < BATCH; ++b)
            sh_h[b][t] = h[((size_t)b*NUM_SLOTS + i)*D_MODEL + t];
        __syncthreads();
        const float* ws = Ws + ((size_t)i*NUM_SLOTS + j)*(D_MODEL*RANK);
        float accA = 0.f;
        #pragma unroll 8
        for (int d = 0; d < D_MODEL; ++d)
            accA += sh_h[tb][d] * ws[(size_t)d*RANK + tr];
        sh_inter[tb][tr] = accA;
        __syncthreads();
        const float* wt = Wt + ((size_t)i*NUM_SLOTS + j)*(RANK*D_MODEL);
        #pragma unroll 8
        for (int r = 0; r < RANK; ++r) {
            float w = wt[(size_t)r*D_MODEL + t];
            #pragma unroll
            for (int b = 0; b < BATCH; ++b) acc[b] += sh_inter[b][r] * w;
        }
        __syncthreads();
    }
    #pragma unroll
    for (int b = 0; b < BATCH; ++b)
        part[(((size_t)g*BATCH + b)*NUM_SLOTS + j)*D_MODEL + t] = acc[b];
}

// h = LN(h + relu(sum_g part)); writes fp32 and fp16 copies
__global__ __launch_bounds__(256) void k_ln(float* __restrict__ h,
        unsigned short* __restrict__ h16, const float* __restrict__ part,
        const float* __restrict__ gma, const float* __restrict__ bta) {
    int bj = blockIdx.x;
    int t = threadIdx.x;
    int b = bj >> 7, j = bj & 127;
    __shared__ float red[256];
    float v = 0.f;
    #pragma unroll
    for (int g = 0; g < IGROUPS; ++g)
        v += part[(((size_t)g*BATCH + b)*NUM_SLOTS + j)*D_MODEL + t];
    float x = h[(size_t)bj*D_MODEL + t] + fmaxf(v, 0.f);
    red[t] = x; __syncthreads();
    for (int o = 128; o > 0; o >>= 1) { if (t < o) red[t] += red[t+o]; __syncthreads(); }
    float mu = red[0] * (1.0f/D_MODEL); __syncthreads();
    float dx = x - mu;
    red[t] = dx*dx; __syncthreads();
    for (int o = 128; o > 0; o >>= 1) { if (t < o) red[t] += red[t+o]; __syncthreads(); }
    float var = red[0] * (1.0f/D_MODEL);
    float outv = dx * rsqrtf(var + LN_EPS) * gma[t] + bta[t];
    h[(size_t)bj*D_MODEL + t] = outv;
    h16[(size_t)bj*D_MODEL + t] = f2h(outv);
}

__global__ __launch_bounds__(128) void k_attn2(const float* __restrict__ Q,
        const float* __restrict__ Kf, float* __restrict__ A2) {
    int bl = blockIdx.x; int b = bl / SEQ;
    int s = threadIdx.x;
    __shared__ float q[D_MODEL];
    __shared__ float red[128];
    q[s]       = Q[(size_t)bl*D_MODEL + s];
    q[s + 128] = Q[(size_t)bl*D_MODEL + s + 128];
    __syncthreads();
    const float* kf = Kf + ((size_t)b*NUM_SLOTS + s)*D_MODEL;
    float acc = 0.f;
    #pragma unroll 8
    for (int d = 0; d < D_MODEL; ++d) acc += q[d]*kf[d];
    acc *= SM_SCALE;
    red[s] = acc; __syncthreads();
    for (int o = 64; o > 0; o >>= 1) { if (s < o) red[s] = fmaxf(red[s], red[s+o]); __syncthreads(); }
    float mx = red[0]; __syncthreads();
    float e = expf(acc - mx);
    red[s] = e; __syncthreads();
    for (int o = 64; o > 0; o >>= 1) { if (s < o) red[s] += red[s+o]; __syncthreads(); }
    A2[(size_t)bl*NUM_SLOTS + s] = e / red[0];
}

__global__ __launch_bounds__(256) void k_y(const float* __restrict__ A2,
        const float* __restrict__ Vf, float* __restrict__ Y) {
    int bl = blockIdx.x; int b = bl / SEQ;
    int d = threadIdx.x;
    const float* a = A2 + (size_t)bl*NUM_SLOTS;
    const float* v = Vf + (size_t)b*NUM_SLOTS*D_MODEL + d;
    float acc = 0.f;
    #pragma unroll 4
    for (int s = 0; s < NUM_SLOTS; ++s) acc += a[s]*v[(size_t)s*D_MODEL];
    Y[(size_t)bl*D_MODEL + d] = acc;
}

extern "C" void kernel_launch(void* const* d_in, const int* in_sizes, int n_in,
                              void* d_out, int out_size, void* d_ws, size_t ws_size,
                              hipStream_t stream) {
    const int*   ids    = (const int*)d_in[0];
    const int*   amask  = (const int*)d_in[1];
    const float* tok    = (const float*)d_in[2];
    const float* pos    = (const float*)d_in[3];
    const float* Hin    = (const float*)d_in[4];
    const float* Ws     = (const float*)d_in[5];
    const float* Wt     = (const float*)d_in[6];
    const float* Wq_in  = (const float*)d_in[7];
    const float* Wk_sl  = (const float*)d_in[8];
    const float* Wv_in  = (const float*)d_in[9];
    const float* Wq_out = (const float*)d_in[10];
    const float* Wk_fin = (const float*)d_in[11];
    const float* Wv_fin = (const float*)d_in[12];
    const float* Wop    = (const float*)d_in[13];
    const float* lnsc   = (const float*)d_in[14];
    const float* lnbs   = (const float*)d_in[15];
    float* out = (float*)d_out;

    const size_t WF_USH = (size_t)16384 * 16384;     // 512 MiB of ushorts
    const size_t F32_FLOATS = 18580480ULL;           // fp32+bf16+h16 scratch region
    const bool useF16 = ws_size >= WF_USH*2 + F32_FLOATS*4 + 256;

    unsigned short* WF = (unsigned short*)d_ws;
    float* ws = useF16 ? (float*)(WF + WF_USH) : (float*)d_ws;

    float* X    = ws;
    float* Qin  = X    + (size_t)NTOK*D_MODEL;
    float* Vin  = Qin  + (size_t)NTOK*D_MODEL;
    float* Ksl  = Vin  + (size_t)NTOK*D_MODEL;
    float* Asc  = Ksl  + (size_t)NUM_SLOTS*D_MODEL;
    float* cs   = Asc  + (size_t)NTOK*NUM_SLOTS;
    float* Hst  = cs   + (size_t)BATCH*NUM_SLOTS;
    float* part = Hst  + (size_t)BATCH*NUM_SLOTS*D_MODEL;
    float* Qout = part + (size_t)IGROUPS*BATCH*NUM_SLOTS*D_MODEL;
    float* Kf   = Qout + (size_t)NTOK*D_MODEL;
    float* Vf   = Kf   + (size_t)BATCH*NUM_SLOTS*D_MODEL;
    float* A2   = Vf   + (size_t)BATCH*NUM_SLOTS*D_MODEL;
    float* Yb   = A2   + (size_t)NTOK*NUM_SLOTS;
    unsigned short* Yh = (unsigned short*)(Yb + (size_t)NTOK*D_MODEL);
    unsigned short* Yl = Yh + (size_t)NTOK*D_MODEL;
    unsigned short* Wh = Yl + (size_t)NTOK*D_MODEL;
    unsigned short* Wl = Wh + (size_t)VOCAB*D_MODEL;
    unsigned short* Hst16 = Wl + (size_t)VOCAB*D_MODEL;

    // one-time weight conversions (independent of the rest)
    if (useF16) {
        k_convert_s<<<dim3(128, 128, 2), 256, 0, stream>>>(Ws, WF);
        k_convert_t<<<dim3(128, 128, 2), 256, 0, stream>>>(Wt, WF);
    }
    k_split<<<(VOCAB*D_MODEL/4 + 255)/256, 256, 0, stream>>>(Wop, Wh, Wl, VOCAB*D_MODEL/4);

    // embeddings
    k_embed<<<NTOK, 256, 0, stream>>>(ids, tok, pos, X);
    // compress projections
    k_gemm_nt<<<dim3(NTOK/64, 4), 256, 0, stream>>>(X, Wq_in, Qin, NTOK, D_MODEL, D_MODEL);
    k_gemm_nt<<<dim3(2, 4),       256, 0, stream>>>(Hin, Wk_sl, Ksl, NUM_SLOTS, D_MODEL, D_MODEL);
    k_gemm_nt<<<dim3(NTOK/64, 4), 256, 0, stream>>>(X, Wv_in, Vin, NTOK, D_MODEL, D_MODEL);
    // scores + softmax + mask
    k_gemm_nt<<<dim3(NTOK/64, 2), 256, 0, stream>>>(Qin, Ksl, Asc, NTOK, NUM_SLOTS, D_MODEL);
    k_softmax_mask<<<NTOK, 128, 0, stream>>>(Asc, amask);
    // column-normalize + aggregate into slots
    k_colsum<<<BATCH, 128, 0, stream>>>(Asc, cs);
    k_ir<<<BATCH*NUM_SLOTS, 256, 0, stream>>>(Asc, Vin, Hin, cs, Hst, Hst16);
    // bilinear slot-interaction steps
    for (int st = 0; st < N_STEPS; ++st) {
        if (useF16)
            k_pairs_mfma<<<dim3(NUM_SLOTS, IGROUPS), 256, 0, stream>>>(Hst16, WF, part);
        else
            k_pairs<<<dim3(NUM_SLOTS, IGROUPS), 256, 0, stream>>>(Hst, Ws, Wt, part);
        k_ln<<<BATCH*NUM_SLOTS, 256, 0, stream>>>(Hst, Hst16, part, lnsc + st*D_MODEL, lnbs + st*D_MODEL);
    }
    // expand projections
    k_gemm_nt<<<dim3(NTOK/64, 4), 256, 0, stream>>>(X, Wq_out, Qout, NTOK, D_MODEL, D_MODEL);
    k_gemm_nt<<<dim3(BATCH*NUM_SLOTS/64, 4), 256, 0, stream>>>(Hst, Wk_fin, Kf, BATCH*NUM_SLOTS, D_MODEL, D_MODEL);
    k_gemm_nt<<<dim3(BATCH*NUM_SLOTS/64, 4), 256, 0, stream>>>(Hst, Wv_fin, Vf, BATCH*NUM_SLOTS, D_MODEL, D_MODEL);
    // expand attention
    k_attn2<<<NTOK, 128, 0, stream>>>(Qout, Kf, A2);
    k_y<<<NTOK, 256, 0, stream>>>(A2, Vf, Yb);
    // logits
    k_split<<<(NTOK*D_MODEL/4 + 255)/256, 256, 0, stream>>>(Yb, Yh, Yl, NTOK*D_MODEL/4);
    k_logits<<<dim3(NTOK/128, VOCAB/128), 256, 0, stream>>>(Yh, Yl, Wh, Wl, out);
}

// Round 8
// 1553.990 us; speedup vs baseline: 1.3062x; 1.0017x over previous
//
#include <hip/hip_runtime.h>
#include <hip/hip_bf16.h>
#include <math.h>

#define D_MODEL 256
#define NUM_SLOTS 128
#define RANK 32
#define N_STEPS 6
#define VOCAB 32000
#define SEQ 512
#define BATCH 8
#define NTOK (BATCH*SEQ)
#define LN_EPS 1e-5f
#define SM_SCALE 0.0625f
#define IGROUPS 8
#define IPG (NUM_SLOTS/IGROUPS)

typedef __attribute__((ext_vector_type(8))) short bf16x8;
typedef __attribute__((ext_vector_type(8))) _Float16 f16x8;
typedef __attribute__((ext_vector_type(4))) float f32x4;

#define GLD_LDS16(g, l) __builtin_amdgcn_global_load_lds( \
    (const __attribute__((address_space(1))) unsigned int*)(g), \
    (__attribute__((address_space(3))) unsigned int*)(l), 16, 0, 0)

__device__ inline unsigned short f2bf(float x) {
    unsigned u = __float_as_uint(x);
    unsigned r = u + 0x7fff + ((u >> 16) & 1);
    return (unsigned short)(r >> 16);
}
__device__ inline float bf2f(unsigned short h) {
    return __uint_as_float(((unsigned)h) << 16);
}
__device__ inline unsigned pk2(float a, float b) {
    auto v = __builtin_amdgcn_cvt_pkrtz(a, b);
    union { decltype(v) x; unsigned u; } c;
    c.x = v;
    return c.u;
}
__device__ inline unsigned short f2h(float x) {
    union { _Float16 h; unsigned short u; } c;
    c.h = (_Float16)x;
    return c.u;
}

// X[b,l,:] = token_emb[ids[b,l],:] + pos_emb[l,:]
__global__ __launch_bounds__(256) void k_embed(const int* __restrict__ ids,
        const float* __restrict__ tok, const float* __restrict__ pos,
        float* __restrict__ X) {
    int bl = blockIdx.x;
    int d  = threadIdx.x;
    int l  = bl % SEQ;
    int id = ids[bl];
    X[(size_t)bl*D_MODEL + d] = tok[(size_t)id*D_MODEL + d] + pos[l*D_MODEL + d];
}

// C[m,n] = sum_k A[m,k]*B[n,k]   (both row-major, K contiguous)  64x64 tile
__global__ __launch_bounds__(256) void k_gemm_nt(const float* __restrict__ A,
        const float* __restrict__ B, float* __restrict__ C, int M, int N, int K) {
    __shared__ float As[32][64];
    __shared__ float Bs[32][64];
    int bm = blockIdx.x * 64, bn = blockIdx.y * 64;
    int t = threadIdx.x;
    int tm = (t & 15) * 4, tn = (t >> 4) * 4;
    float acc[4][4] = {};
    for (int k0 = 0; k0 < K; k0 += 32) {
        #pragma unroll
        for (int r = 0; r < 8; ++r) {
            int idx = r*256 + t;
            int m = idx >> 5, k = idx & 31;
            As[k][m] = A[(size_t)(bm+m)*K + k0 + k];
        }
        #pragma unroll
        for (int r = 0; r < 8; ++r) {
            int idx = r*256 + t;
            int n = idx >> 5, k = idx & 31;
            Bs[k][n] = B[(size_t)(bn+n)*K + k0 + k];
        }
        __syncthreads();
        #pragma unroll
        for (int k = 0; k < 32; ++k) {
            float4 a4 = *(const float4*)&As[k][tm];
            float4 b4 = *(const float4*)&Bs[k][tn];
            float a[4] = {a4.x,a4.y,a4.z,a4.w};
            float b[4] = {b4.x,b4.y,b4.z,b4.w};
            #pragma unroll
            for (int i = 0; i < 4; ++i)
                #pragma unroll
                for (int jj = 0; jj < 4; ++jj)
                    acc[i][jj] += a[i]*b[jj];
        }
        __syncthreads();
    }
    #pragma unroll
    for (int i = 0; i < 4; ++i) {
        float4 v = make_float4(acc[i][0],acc[i][1],acc[i][2],acc[i][3]);
        *(float4*)&C[(size_t)(bm+tm+i)*N + bn+tn] = v;
    }
}

// split fp32 -> bf16 hi + bf16 lo
__global__ __launch_bounds__(256) void k_split(const float* __restrict__ in,
        unsigned short* __restrict__ hi, unsigned short* __restrict__ lo, int n4) {
    int i = blockIdx.x*256 + threadIdx.x;
    if (i >= n4) return;
    float4 v = ((const float4*)in)[i];
    float f[4] = {v.x, v.y, v.z, v.w};
    ushort4 h, lw;
    unsigned short* hp = &h.x; unsigned short* lp = &lw.x;
    #pragma unroll
    for (int j = 0; j < 4; ++j) {
        unsigned short hb = f2bf(f[j]);
        hp[j] = hb;
        lp[j] = f2bf(f[j] - bf2f(hb));
    }
    ((ushort4*)hi)[i] = h;
    ((ushort4*)lo)[i] = lw;
}

// logits GEMM: 3-pass split-bf16 MFMA
__global__ __launch_bounds__(256) void k_logits(
        const unsigned short* __restrict__ Ahg, const unsigned short* __restrict__ Alg,
        const unsigned short* __restrict__ Bhg, const unsigned short* __restrict__ Blg,
        float* __restrict__ C) {
    __shared__ short lds[4*128*64];
    short* Ah = lds;
    short* Al = lds + 8192;
    short* Bh = lds + 16384;
    short* Bl = lds + 24576;
    int bm = blockIdx.x * 128, bn = blockIdx.y * 128;
    int t = threadIdx.x;
    int w = t >> 6, l = t & 63;
    int wr = w >> 1, wc = w & 1;
    int lr = l & 15, lk = l >> 4;
    f32x4 acc[4][4];
    #pragma unroll
    for (int mi = 0; mi < 4; ++mi)
        #pragma unroll
        for (int ni = 0; ni < 4; ++ni)
            acc[mi][ni] = (f32x4){0.f,0.f,0.f,0.f};

    for (int kc = 0; kc < 4; ++kc) {
        #pragma unroll
        for (int i = 0; i < 4; ++i) {
            int v = t + i*256;
            int row = v >> 3, cv = v & 7;
            int so = row*64 + ((cv ^ (row & 7)) << 3);
            size_t ga = (size_t)(bm+row)*256 + kc*64 + cv*8;
            size_t gb = (size_t)(bn+row)*256 + kc*64 + cv*8;
            *(bf16x8*)&Ah[so] = *(const bf16x8*)&Ahg[ga];
            *(bf16x8*)&Al[so] = *(const bf16x8*)&Alg[ga];
            *(bf16x8*)&Bh[so] = *(const bf16x8*)&Bhg[gb];
            *(bf16x8*)&Bl[so] = *(const bf16x8*)&Blg[gb];
        }
        __syncthreads();
        #pragma unroll
        for (int s = 0; s < 2; ++s) {
            bf16x8 ah[4], al[4], bh[4], bl[4];
            #pragma unroll
            for (int mi = 0; mi < 4; ++mi) {
                int row = wr*64 + mi*16 + lr;
                int off = row*64 + ((((s<<2)+lk) ^ (row&7)) << 3);
                ah[mi] = *(bf16x8*)&Ah[off];
                al[mi] = *(bf16x8*)&Al[off];
            }
            #pragma unroll
            for (int ni = 0; ni < 4; ++ni) {
                int row = wc*64 + ni*16 + lr;
                int off = row*64 + ((((s<<2)+lk) ^ (row&7)) << 3);
                bh[ni] = *(bf16x8*)&Bh[off];
                bl[ni] = *(bf16x8*)&Bl[off];
            }
            #pragma unroll
            for (int mi = 0; mi < 4; ++mi)
                #pragma unroll
                for (int ni = 0; ni < 4; ++ni) {
                    acc[mi][ni] = __builtin_amdgcn_mfma_f32_16x16x32_bf16(ah[mi], bh[ni], acc[mi][ni], 0, 0, 0);
                    acc[mi][ni] = __builtin_amdgcn_mfma_f32_16x16x32_bf16(ah[mi], bl[ni], acc[mi][ni], 0, 0, 0);
                    acc[mi][ni] = __builtin_amdgcn_mfma_f32_16x16x32_bf16(al[mi], bh[ni], acc[mi][ni], 0, 0, 0);
                }
        }
        __syncthreads();
    }
    #pragma unroll
    for (int mi = 0; mi < 4; ++mi)
        #pragma unroll
        for (int ni = 0; ni < 4; ++ni) {
            int col = bn + wc*64 + ni*16 + lr;
            #pragma unroll
            for (int r = 0; r < 4; ++r) {
                int row = bm + wr*64 + mi*16 + lk*4 + r;
                C[(size_t)row*VOCAB + col] = acc[mi][ni][r];
            }
        }
}

__global__ __launch_bounds__(128) void k_softmax_mask(float* __restrict__ A,
        const int* __restrict__ mask) {
    int row = blockIdx.x;
    int s = threadIdx.x;
    __shared__ float red[128];
    float v = A[(size_t)row*NUM_SLOTS + s] * SM_SCALE;
    red[s] = v; __syncthreads();
    for (int o = 64; o > 0; o >>= 1) { if (s < o) red[s] = fmaxf(red[s], red[s+o]); __syncthreads(); }
    float mx = red[0]; __syncthreads();
    float e = expf(v - mx);
    red[s] = e; __syncthreads();
    for (int o = 64; o > 0; o >>= 1) { if (s < o) red[s] += red[s+o]; __syncthreads(); }
    float sum = red[0];
    float m = (float)mask[row];
    A[(size_t)row*NUM_SLOTS + s] = e / sum * m;
}

__global__ __launch_bounds__(128) void k_colsum(const float* __restrict__ A,
        float* __restrict__ cs) {
    int b = blockIdx.x; int s = threadIdx.x;
    const float* Ab = A + (size_t)b*SEQ*NUM_SLOTS + s;
    float acc = 0.f;
    for (int l = 0; l < SEQ; ++l) acc += Ab[(size_t)l*NUM_SLOTS];
    cs[b*NUM_SLOTS + s] = acc + 1e-8f;
}

// H_state = H + IR; writes fp32 and fp16 copies
__global__ __launch_bounds__(256) void k_ir(const float* __restrict__ A,
        const float* __restrict__ V, const float* __restrict__ H,
        const float* __restrict__ cs, float* __restrict__ Hs,
        unsigned short* __restrict__ Hs16) {
    int bs = blockIdx.x; int b = bs >> 7; int s = bs & 127;
    int d = threadIdx.x;
    float inv = 1.0f / cs[bs];
    const float* Ab = A + (size_t)b*SEQ*NUM_SLOTS + s;
    const float* Vb = V + (size_t)b*SEQ*D_MODEL + d;
    float acc = 0.f;
    for (int l = 0; l < SEQ; ++l) acc += Ab[(size_t)l*NUM_SLOTS] * Vb[(size_t)l*D_MODEL];
    float v = H[s*D_MODEL + d] + acc * inv;
    Hs[(size_t)bs*D_MODEL + d] = v;
    Hs16[(size_t)bs*D_MODEL + d] = f2h(v);
}

// ---- one-time fp32->fp16 weight conversion into MFMA fragment order ----
// Ws half: blockIdx.z = hf handles d in [hf*128, hf*128+128)
__global__ __launch_bounds__(256) void k_convert_s(const float* __restrict__ Ws,
        unsigned short* __restrict__ WF) {
    int i = blockIdx.x, j = blockIdx.y, hf = blockIdx.z;
    int t = threadIdx.x;
    __shared__ float lds[128*33];
    size_t sBase = ((size_t)i*128 + j)*8192;
    size_t pOut = ((size_t)j*128 + i)*16384;
    const float4* s4 = (const float4*)(Ws + sBase) + hf*1024;
    #pragma unroll
    for (int p = 0; p < 4; ++p) {
        int f4 = p*256 + t;
        float4 v = s4[f4];
        *(float4*)&lds[(f4 >> 3)*33 + 4*(f4 & 7)] = v;
    }
    __syncthreads();
    bool diag = (i == j);
    #pragma unroll
    for (int q = 0; q < 2; ++q) {
        int cl = q*256 + t;
        int ksl = cl >> 7, mt = (cl >> 6) & 1, l = cl & 63;
        int g = l >> 4, c = l & 15;
        union { f16x8 v; } o;
        #pragma unroll
        for (int e = 0; e < 8; ++e) {
            float f = diag ? 0.f : lds[(ksl*32 + g*8 + e)*33 + mt*16 + c];
            o.v[e] = (_Float16)f;
        }
        *(f16x8*)(WF + pOut + (size_t)hf*4096 + (size_t)cl*8) = o.v;
    }
}

// Wt half: blockIdx.z = hf handles d in [hf*128, hf*128+128)
__global__ __launch_bounds__(256) void k_convert_t(const float* __restrict__ Wt,
        unsigned short* __restrict__ WF) {
    int i = blockIdx.x, j = blockIdx.y, hf = blockIdx.z;
    int t = threadIdx.x;
    __shared__ float lds[32*133];
    size_t sBase = ((size_t)i*128 + j)*8192;
    size_t pOut = ((size_t)j*128 + i)*16384;
    const float4* s4 = (const float4*)(Wt + sBase);
    #pragma unroll
    for (int p = 0; p < 4; ++p) {
        int idx = p*256 + t;
        int r = idx >> 5, c4 = idx & 31;
        float4 v = s4[r*64 + hf*32 + c4];
        *(float4*)&lds[r*133 + c4*4] = v;
    }
    __syncthreads();
    #pragma unroll
    for (int q = 0; q < 2; ++q) {
        int cl = q*256 + t;
        int ntl = cl >> 6, l = cl & 63;
        int g = l >> 4, c = l & 15;
        union { f16x8 v; } o;
        #pragma unroll
        for (int e = 0; e < 8; ++e)
            o.v[e] = (_Float16)lds[(g*8 + e)*133 + ntl*16 + c];
        *(f16x8*)(WF + pOut + 8192 + (size_t)hf*4096 + (size_t)cl*8) = o.v;
    }
}

// ---- MFMA slot-pair kernel, deep-pipelined with COUNTED vmcnt barriers ----
// Per-thread VMEM issue order per iteration (pinned by sched_barrier):
//   [5x global_load_lds stage(ii+1)] then [4x Wt(ii+1) reg loads].
// At the top barrier only stage(ii) (issued a full iteration ago) must be
// drained -> s_waitcnt vmcnt(4), never vmcnt(0): the 4 Wt loads stay in
// flight across the barrier (T4 pattern).
__global__ __launch_bounds__(256, 4) void k_pairs_mfma(const unsigned short* __restrict__ h16,
        const unsigned short* __restrict__ WF, float* __restrict__ part) {
    __shared__ unsigned short lds[2*10240];   // 2 x (8192 Ws + 2048 h) ushorts = 40KB
    int j = blockIdx.x, g = blockIdx.y;
    int t = threadIdx.x, w = t >> 6, l = t & 63;
    int lg = l >> 4, c = l & 15;
    const unsigned short* pbase = WF + ((size_t)j*128 + g*16)*16384;

    // prologue: stage ii=0 (buf 0), then Wt(0) prefetch (order pinned)
    {
        const unsigned short* src = pbase;
        #pragma unroll
        for (int q = 0; q < 4; ++q)
            GLD_LDS16(src + (size_t)(q*256 + t)*8, &lds[(q*256 + t)*8]);
        const unsigned short* hsrc = h16 + ((size_t)(t&7)*NUM_SLOTS + g*16)*D_MODEL + (t>>3)*8;
        GLD_LDS16(hsrc, &lds[8192 + t*8]);
    }
    __builtin_amdgcn_sched_barrier(0);
    f16x8 bqn[4];
    #pragma unroll
    for (int nt = 0; nt < 4; ++nt)
        bqn[nt] = *(const f16x8*)(pbase + 8192 + (size_t)((w*4+nt)*64 + l)*8);
    __builtin_amdgcn_sched_barrier(0);

    f32x4 acc[4];
    #pragma unroll
    for (int nt = 0; nt < 4; ++nt) acc[nt] = (f32x4){0.f,0.f,0.f,0.f};
    f16x8 hzero;
    #pragma unroll
    for (int e = 0; e < 8; ++e) hzero[e] = (_Float16)0.f;

    #pragma unroll 2
    for (int ii = 0; ii < 16; ++ii) {
        int cur = ii & 1;
        // counted drain: stage(ii) complete, 4 Wt loads may remain in flight
        asm volatile("s_waitcnt vmcnt(4) lgkmcnt(0)" ::: "memory");
        __builtin_amdgcn_s_barrier();
        __builtin_amdgcn_sched_barrier(0);
        if (ii < 15) {
            const unsigned short* src = pbase + (size_t)(ii+1)*16384;
            unsigned short* dst = &lds[(cur^1)*10240];
            #pragma unroll
            for (int q = 0; q < 4; ++q)
                GLD_LDS16(src + (size_t)(q*256 + t)*8, dst + (size_t)(q*256 + t)*8);
            const unsigned short* hsrc = h16 + ((size_t)(t&7)*NUM_SLOTS + (g*16+ii+1))*D_MODEL + (t>>3)*8;
            GLD_LDS16(hsrc, dst + 8192 + (size_t)t*8);
        }
        __builtin_amdgcn_sched_barrier(0);
        // consume prefetched Wt frags; issue next ii's (consumed NEXT iter)
        f16x8 bq[4];
        #pragma unroll
        for (int nt = 0; nt < 4; ++nt) bq[nt] = bqn[nt];
        if (ii < 15) {
            const unsigned short* bp = pbase + (size_t)(ii+1)*16384 + 8192;
            #pragma unroll
            for (int nt = 0; nt < 4; ++nt)
                bqn[nt] = *(const f16x8*)(bp + (size_t)((w*4+nt)*64 + l)*8);
        }
        // pass1: interT[r=0..31][b] = sum_d WsT[r][d] h[b][d]
        const unsigned short* buf = &lds[cur*10240];
        f32x4 d1[2];
        d1[0] = (f32x4){0.f,0.f,0.f,0.f};
        d1[1] = (f32x4){0.f,0.f,0.f,0.f};
        #pragma unroll
        for (int ks = 0; ks < 8; ++ks) {
            f16x8 a0 = *(const f16x8*)(buf + (size_t)((ks*2+0)*64 + l)*8);
            f16x8 a1 = *(const f16x8*)(buf + (size_t)((ks*2+1)*64 + l)*8);
            f16x8 hv = *(const f16x8*)(buf + 8192 + (size_t)(((ks*4+lg)*8 + (c&7)))*8);
            f16x8 hb = (c < 8) ? hv : hzero;
            d1[0] = __builtin_amdgcn_mfma_f32_16x16x32_f16(a0, hb, d1[0], 0, 0, 0);
            d1[1] = __builtin_amdgcn_mfma_f32_16x16x32_f16(a1, hb, d1[1], 0, 0, 0);
        }
        // pack interT to fp16 pairs, shuffle into pass2 A-frag
        unsigned q0 = pk2(d1[0][0], d1[0][1]);
        unsigned q1 = pk2(d1[0][2], d1[0][3]);
        unsigned s0 = pk2(d1[1][0], d1[1][1]);
        unsigned s1 = pk2(d1[1][2], d1[1][3]);
        int srcLo = 32*(lg & 1) + c;
        int srcHi = srcLo + 16;
        unsigned a0s = (unsigned)__shfl((int)q0, srcLo, 64);
        unsigned a1s = (unsigned)__shfl((int)q1, srcLo, 64);
        unsigned a2s = (unsigned)__shfl((int)q0, srcHi, 64);
        unsigned a3s = (unsigned)__shfl((int)q1, srcHi, 64);
        unsigned b0s = (unsigned)__shfl((int)s0, srcLo, 64);
        unsigned b1s = (unsigned)__shfl((int)s1, srcLo, 64);
        unsigned b2s = (unsigned)__shfl((int)s0, srcHi, 64);
        unsigned b3s = (unsigned)__shfl((int)s1, srcHi, 64);
        bool himt = ((lg >> 1) & 1);
        union { unsigned u[4]; f16x8 v; } A2u;
        A2u.u[0] = himt ? b0s : a0s;
        A2u.u[1] = himt ? b1s : a1s;
        A2u.u[2] = himt ? b2s : a2s;
        A2u.u[3] = himt ? b3s : a3s;
        // pass2: out[b][d] += sum_r inter[b][r] Wt[r][d]
        #pragma unroll
        for (int nt = 0; nt < 4; ++nt)
            acc[nt] = __builtin_amdgcn_mfma_f32_16x16x32_f16(A2u.v, bq[nt], acc[nt], 0, 0, 0);
    }
    // store: lanes lg<2 hold rows b = lg*4+reg (0..7)
    if (lg < 2) {
        #pragma unroll
        for (int nt = 0; nt < 4; ++nt) {
            int d = (w*4 + nt)*16 + c;
            #pragma unroll
            for (int r = 0; r < 4; ++r) {
                int b = lg*4 + r;
                part[(((size_t)g*BATCH + b)*NUM_SLOTS + j)*D_MODEL + d] = acc[nt][r];
            }
        }
    }
}

// fallback fp32 pairs kernel (used when ws too small for WF)
__global__ __launch_bounds__(256) void k_pairs(const float* __restrict__ h,
        const float* __restrict__ Ws, const float* __restrict__ Wt,
        float* __restrict__ part) {
    int j = blockIdx.x;
    int g = blockIdx.y;
    int t = threadIdx.x;
    __shared__ float sh_h[BATCH][D_MODEL];
    __shared__ float sh_inter[BATCH][RANK];
    float acc[BATCH];
    #pragma unroll
    for (int b = 0; b < BATCH; ++b) acc[b] = 0.f;
    int tb = t >> 5, tr = t & 31;
    for (int ii = 0; ii < IPG; ++ii) {
        int i = g*IPG + ii;
        if (i == j) continue;
        #pragma unroll
        for (int b = 0; b < BATCH; ++b)
            sh_h[b][t] = h[((size_t)b*NUM_SLOTS + i)*D_MODEL + t];
        __syncthreads();
        const float* ws = Ws + ((size_t)i*NUM_SLOTS + j)*(D_MODEL*RANK);
        float accA = 0.f;
        #pragma unroll 8
        for (int d = 0; d < D_MODEL; ++d)
            accA += sh_h[tb][d] * ws[(size_t)d*RANK + tr];
        sh_inter[tb][tr] = accA;
        __syncthreads();
        const float* wt = Wt + ((size_t)i*NUM_SLOTS + j)*(RANK*D_MODEL);
        #pragma unroll 8
        for (int r = 0; r < RANK; ++r) {
            float w = wt[(size_t)r*D_MODEL + t];
            #pragma unroll
            for (int b = 0; b < BATCH; ++b) acc[b] += sh_inter[b][r] * w;
        }
        __syncthreads();
    }
    #pragma unroll
    for (int b = 0; b < BATCH; ++b)
        part[(((size_t)g*BATCH + b)*NUM_SLOTS + j)*D_MODEL + t] = acc[b];
}

// h = LN(h + relu(sum_g part)); writes fp32 and fp16 copies
__global__ __launch_bounds__(256) void k_ln(float* __restrict__ h,
        unsigned short* __restrict__ h16, const float* __restrict__ part,
        const float* __restrict__ gma, const float* __restrict__ bta) {
    int bj = blockIdx.x;
    int t = threadIdx.x;
    int b = bj >> 7, j = bj & 127;
    __shared__ float red[256];
    float v = 0.f;
    #pragma unroll
    for (int g = 0; g < IGROUPS; ++g)
        v += part[(((size_t)g*BATCH + b)*NUM_SLOTS + j)*D_MODEL + t];
    float x = h[(size_t)bj*D_MODEL + t] + fmaxf(v, 0.f);
    red[t] = x; __syncthreads();
    for (int o = 128; o > 0; o >>= 1) { if (t < o) red[t] += red[t+o]; __syncthreads(); }
    float mu = red[0] * (1.0f/D_MODEL); __syncthreads();
    float dx = x - mu;
    red[t] = dx*dx; __syncthreads();
    for (int o = 128; o > 0; o >>= 1) { if (t < o) red[t] += red[t+o]; __syncthreads(); }
    float var = red[0] * (1.0f/D_MODEL);
    float outv = dx * rsqrtf(var + LN_EPS) * gma[t] + bta[t];
    h[(size_t)bj*D_MODEL + t] = outv;
    h16[(size_t)bj*D_MODEL + t] = f2h(outv);
}

__global__ __launch_bounds__(128) void k_attn2(const float* __restrict__ Q,
        const float* __restrict__ Kf, float* __restrict__ A2) {
    int bl = blockIdx.x; int b = bl / SEQ;
    int s = threadIdx.x;
    __shared__ float q[D_MODEL];
    __shared__ float red[128];
    q[s]       = Q[(size_t)bl*D_MODEL + s];
    q[s + 128] = Q[(size_t)bl*D_MODEL + s + 128];
    __syncthreads();
    const float* kf = Kf + ((size_t)b*NUM_SLOTS + s)*D_MODEL;
    float acc = 0.f;
    #pragma unroll 8
    for (int d = 0; d < D_MODEL; ++d) acc += q[d]*kf[d];
    acc *= SM_SCALE;
    red[s] = acc; __syncthreads();
    for (int o = 64; o > 0; o >>= 1) { if (s < o) red[s] = fmaxf(red[s], red[s+o]); __syncthreads(); }
    float mx = red[0]; __syncthreads();
    float e = expf(acc - mx);
    red[s] = e; __syncthreads();
    for (int o = 64; o > 0; o >>= 1) { if (s < o) red[s] += red[s+o]; __syncthreads(); }
    A2[(size_t)bl*NUM_SLOTS + s] = e / red[0];
}

// Y = A2 @ Vf, written directly as split bf16 hi/lo for the logits GEMM
__global__ __launch_bounds__(256) void k_y(const float* __restrict__ A2,
        const float* __restrict__ Vf, unsigned short* __restrict__ Yh,
        unsigned short* __restrict__ Yl) {
    int bl = blockIdx.x; int b = bl / SEQ;
    int d = threadIdx.x;
    const float* a = A2 + (size_t)bl*NUM_SLOTS;
    const float* v = Vf + (size_t)b*NUM_SLOTS*D_MODEL + d;
    float acc = 0.f;
    #pragma unroll 4
    for (int s = 0; s < NUM_SLOTS; ++s) acc += a[s]*v[(size_t)s*D_MODEL];
    unsigned short hb = f2bf(acc);
    Yh[(size_t)bl*D_MODEL + d] = hb;
    Yl[(size_t)bl*D_MODEL + d] = f2bf(acc - bf2f(hb));
}

extern "C" void kernel_launch(void* const* d_in, const int* in_sizes, int n_in,
                              void* d_out, int out_size, void* d_ws, size_t ws_size,
                              hipStream_t stream) {
    const int*   ids    = (const int*)d_in[0];
    const int*   amask  = (const int*)d_in[1];
    const float* tok    = (const float*)d_in[2];
    const float* pos    = (const float*)d_in[3];
    const float* Hin    = (const float*)d_in[4];
    const float* Ws     = (const float*)d_in[5];
    const float* Wt     = (const float*)d_in[6];
    const float* Wq_in  = (const float*)d_in[7];
    const float* Wk_sl  = (const float*)d_in[8];
    const float* Wv_in  = (const float*)d_in[9];
    const float* Wq_out = (const float*)d_in[10];
    const float* Wk_fin = (const float*)d_in[11];
    const float* Wv_fin = (const float*)d_in[12];
    const float* Wop    = (const float*)d_in[13];
    const float* lnsc   = (const float*)d_in[14];
    const float* lnbs   = (const float*)d_in[15];
    float* out = (float*)d_out;

    const size_t WF_USH = (size_t)16384 * 16384;     // 512 MiB of ushorts
    const size_t F32_FLOATS = 18580480ULL;           // fp32+bf16+h16 scratch region
    const bool useF16 = ws_size >= WF_USH*2 + F32_FLOATS*4 + 256;

    unsigned short* WF = (unsigned short*)d_ws;
    float* ws = useF16 ? (float*)(WF + WF_USH) : (float*)d_ws;

    float* X    = ws;
    float* Qin  = X    + (size_t)NTOK*D_MODEL;
    float* Vin  = Qin  + (size_t)NTOK*D_MODEL;
    float* Ksl  = Vin  + (size_t)NTOK*D_MODEL;
    float* Asc  = Ksl  + (size_t)NUM_SLOTS*D_MODEL;
    float* cs   = Asc  + (size_t)NTOK*NUM_SLOTS;
    float* Hst  = cs   + (size_t)BATCH*NUM_SLOTS;
    float* part = Hst  + (size_t)BATCH*NUM_SLOTS*D_MODEL;
    float* Qout = part + (size_t)IGROUPS*BATCH*NUM_SLOTS*D_MODEL;
    float* Kf   = Qout + (size_t)NTOK*D_MODEL;
    float* Vf   = Kf   + (size_t)BATCH*NUM_SLOTS*D_MODEL;
    float* A2   = Vf   + (size_t)BATCH*NUM_SLOTS*D_MODEL;
    float* Yb   = A2   + (size_t)NTOK*NUM_SLOTS;
    unsigned short* Yh = (unsigned short*)(Yb + (size_t)NTOK*D_MODEL);
    unsigned short* Yl = Yh + (size_t)NTOK*D_MODEL;
    unsigned short* Wh = Yl + (size_t)NTOK*D_MODEL;
    unsigned short* Wl = Wh + (size_t)VOCAB*D_MODEL;
    unsigned short* Hst16 = Wl + (size_t)VOCAB*D_MODEL;

    // one-time weight conversions (independent of the rest)
    if (useF16) {
        k_convert_s<<<dim3(128, 128, 2), 256, 0, stream>>>(Ws, WF);
        k_convert_t<<<dim3(128, 128, 2), 256, 0, stream>>>(Wt, WF);
    }
    k_split<<<(VOCAB*D_MODEL/4 + 255)/256, 256, 0, stream>>>(Wop, Wh, Wl, VOCAB*D_MODEL/4);

    // embeddings
    k_embed<<<NTOK, 256, 0, stream>>>(ids, tok, pos, X);
    // compress projections
    k_gemm_nt<<<dim3(NTOK/64, 4), 256, 0, stream>>>(X, Wq_in, Qin, NTOK, D_MODEL, D_MODEL);
    k_gemm_nt<<<dim3(2, 4),       256, 0, stream>>>(Hin, Wk_sl, Ksl, NUM_SLOTS, D_MODEL, D_MODEL);
    k_gemm_nt<<<dim3(NTOK/64, 4), 256, 0, stream>>>(X, Wv_in, Vin, NTOK, D_MODEL, D_MODEL);
    // scores + softmax + mask
    k_gemm_nt<<<dim3(NTOK/64, 2), 256, 0, stream>>>(Qin, Ksl, Asc, NTOK, NUM_SLOTS, D_MODEL);
    k_softmax_mask<<<NTOK, 128, 0, stream>>>(Asc, amask);
    // column-normalize + aggregate into slots
    k_colsum<<<BATCH, 128, 0, stream>>>(Asc, cs);
    k_ir<<<BATCH*NUM_SLOTS, 256, 0, stream>>>(Asc, Vin, Hin, cs, Hst, Hst16);
    // bilinear slot-interaction steps
    for (int st = 0; st < N_STEPS; ++st) {
        if (useF16)
            k_pairs_mfma<<<dim3(NUM_SLOTS, IGROUPS), 256, 0, stream>>>(Hst16, WF, part);
        else
            k_pairs<<<dim3(NUM_SLOTS, IGROUPS), 256, 0, stream>>>(Hst, Ws, Wt, part);
        k_ln<<<BATCH*NUM_SLOTS, 256, 0, stream>>>(Hst, Hst16, part, lnsc + st*D_MODEL, lnbs + st*D_MODEL);
    }
    // expand projections
    k_gemm_nt<<<dim3(NTOK/64, 4), 256, 0, stream>>>(X, Wq_out, Qout, NTOK, D_MODEL, D_MODEL);
    k_gemm_nt<<<dim3(BATCH*NUM_SLOTS/64, 4), 256, 0, stream>>>(Hst, Wk_fin, Kf, BATCH*NUM_SLOTS, D_MODEL, D_MODEL);
    k_gemm_nt<<<dim3(BATCH*NUM_SLOTS/64, 4), 256, 0, stream>>>(Hst, Wv_fin, Vf, BATCH*NUM_SLOTS, D_MODEL, D_MODEL);
    // expand attention
    k_attn2<<<NTOK, 128, 0, stream>>>(Qout, Kf, A2);
    k_y<<<NTOK, 256, 0, stream>>>(A2, Vf, Yh, Yl);
    // logits
    k_logits<<<dim3(NTOK/128, VOCAB/128), 256, 0, stream>>>(Yh, Yl, Wh, Wl, out);
}

// Round 9
// 1512.974 us; speedup vs baseline: 1.3416x; 1.0271x over previous
//
#include <hip/hip_runtime.h>
#include <hip/hip_bf16.h>
#include <math.h>

#define D_MODEL 256
#define NUM_SLOTS 128
#define RANK 32
#define N_STEPS 6
#define VOCAB 32000
#define SEQ 512
#define BATCH 8
#define NTOK (BATCH*SEQ)
#define LN_EPS 1e-5f
#define SM_SCALE 0.0625f
#define IGROUPS 8
#define IPG (NUM_SLOTS/IGROUPS)

typedef __attribute__((ext_vector_type(8))) short bf16x8;
typedef __attribute__((ext_vector_type(8))) _Float16 f16x8;
typedef __attribute__((ext_vector_type(4))) float f32x4;

#define GLD_LDS16(g, l) __builtin_amdgcn_global_load_lds( \
    (const __attribute__((address_space(1))) unsigned int*)(g), \
    (__attribute__((address_space(3))) unsigned int*)(l), 16, 0, 0)

__device__ inline unsigned short f2bf(float x) {
    unsigned u = __float_as_uint(x);
    unsigned r = u + 0x7fff + ((u >> 16) & 1);
    return (unsigned short)(r >> 16);
}
__device__ inline float bf2f(unsigned short h) {
    return __uint_as_float(((unsigned)h) << 16);
}
__device__ inline unsigned pk2(float a, float b) {
    auto v = __builtin_amdgcn_cvt_pkrtz(a, b);
    union { decltype(v) x; unsigned u; } c;
    c.x = v;
    return c.u;
}
__device__ inline unsigned short f2h(float x) {
    union { _Float16 h; unsigned short u; } c;
    c.h = (_Float16)x;
    return c.u;
}
__device__ inline float h2f(unsigned short u) {
    union { unsigned short u; _Float16 h; } c;
    c.u = u;
    return (float)c.h;
}

// X[b,l,:] = token_emb[ids[b,l],:] + pos_emb[l,:]
__global__ __launch_bounds__(256) void k_embed(const int* __restrict__ ids,
        const float* __restrict__ tok, const float* __restrict__ pos,
        float* __restrict__ X) {
    int bl = blockIdx.x;
    int d  = threadIdx.x;
    int l  = bl % SEQ;
    int id = ids[bl];
    X[(size_t)bl*D_MODEL + d] = tok[(size_t)id*D_MODEL + d] + pos[l*D_MODEL + d];
}

// C[m,n] = sum_k A[m,k]*B[n,k]   (both row-major, K contiguous)  64x64 tile
__global__ __launch_bounds__(256) void k_gemm_nt(const float* __restrict__ A,
        const float* __restrict__ B, float* __restrict__ C, int M, int N, int K) {
    __shared__ float As[32][64];
    __shared__ float Bs[32][64];
    int bm = blockIdx.x * 64, bn = blockIdx.y * 64;
    int t = threadIdx.x;
    int tm = (t & 15) * 4, tn = (t >> 4) * 4;
    float acc[4][4] = {};
    for (int k0 = 0; k0 < K; k0 += 32) {
        #pragma unroll
        for (int r = 0; r < 8; ++r) {
            int idx = r*256 + t;
            int m = idx >> 5, k = idx & 31;
            As[k][m] = A[(size_t)(bm+m)*K + k0 + k];
        }
        #pragma unroll
        for (int r = 0; r < 8; ++r) {
            int idx = r*256 + t;
            int n = idx >> 5, k = idx & 31;
            Bs[k][n] = B[(size_t)(bn+n)*K + k0 + k];
        }
        __syncthreads();
        #pragma unroll
        for (int k = 0; k < 32; ++k) {
            float4 a4 = *(const float4*)&As[k][tm];
            float4 b4 = *(const float4*)&Bs[k][tn];
            float a[4] = {a4.x,a4.y,a4.z,a4.w};
            float b[4] = {b4.x,b4.y,b4.z,b4.w};
            #pragma unroll
            for (int i = 0; i < 4; ++i)
                #pragma unroll
                for (int jj = 0; jj < 4; ++jj)
                    acc[i][jj] += a[i]*b[jj];
        }
        __syncthreads();
    }
    #pragma unroll
    for (int i = 0; i < 4; ++i) {
        float4 v = make_float4(acc[i][0],acc[i][1],acc[i][2],acc[i][3]);
        *(float4*)&C[(size_t)(bm+tm+i)*N + bn+tn] = v;
    }
}

// 3 projections (Qin, Vin, Qout) from the same A=X, selected by blockIdx.z
__global__ __launch_bounds__(256) void k_gemm3(const float* __restrict__ A,
        const float* __restrict__ B0, const float* __restrict__ B1,
        const float* __restrict__ B2, float* __restrict__ C0,
        float* __restrict__ C1, float* __restrict__ C2) {
    const int K = D_MODEL, N = D_MODEL;
    const float* B = blockIdx.z == 0 ? B0 : (blockIdx.z == 1 ? B1 : B2);
    float* C = blockIdx.z == 0 ? C0 : (blockIdx.z == 1 ? C1 : C2);
    __shared__ float As[32][64];
    __shared__ float Bs[32][64];
    int bm = blockIdx.x * 64, bn = blockIdx.y * 64;
    int t = threadIdx.x;
    int tm = (t & 15) * 4, tn = (t >> 4) * 4;
    float acc[4][4] = {};
    for (int k0 = 0; k0 < K; k0 += 32) {
        #pragma unroll
        for (int r = 0; r < 8; ++r) {
            int idx = r*256 + t;
            int m = idx >> 5, k = idx & 31;
            As[k][m] = A[(size_t)(bm+m)*K + k0 + k];
        }
        #pragma unroll
        for (int r = 0; r < 8; ++r) {
            int idx = r*256 + t;
            int n = idx >> 5, k = idx & 31;
            Bs[k][n] = B[(size_t)(bn+n)*K + k0 + k];
        }
        __syncthreads();
        #pragma unroll
        for (int k = 0; k < 32; ++k) {
            float4 a4 = *(const float4*)&As[k][tm];
            float4 b4 = *(const float4*)&Bs[k][tn];
            float a[4] = {a4.x,a4.y,a4.z,a4.w};
            float b[4] = {b4.x,b4.y,b4.z,b4.w};
            #pragma unroll
            for (int i = 0; i < 4; ++i)
                #pragma unroll
                for (int jj = 0; jj < 4; ++jj)
                    acc[i][jj] += a[i]*b[jj];
        }
        __syncthreads();
    }
    #pragma unroll
    for (int i = 0; i < 4; ++i) {
        float4 v = make_float4(acc[i][0],acc[i][1],acc[i][2],acc[i][3]);
        *(float4*)&C[(size_t)(bm+tm+i)*N + bn+tn] = v;
    }
}

// fp32 -> fp16 (for W_out_proj)
__global__ __launch_bounds__(256) void k_split16(const float* __restrict__ in,
        unsigned short* __restrict__ o, int n4) {
    int i = blockIdx.x*256 + threadIdx.x;
    if (i >= n4) return;
    float4 v = ((const float4*)in)[i];
    ushort4 h;
    h.x = f2h(v.x); h.y = f2h(v.y); h.z = f2h(v.z); h.w = f2h(v.w);
    ((ushort4*)o)[i] = h;
}

// logits GEMM: 2-pass fp16-split MFMA. C = (Yh+Yl) * W16^T, fp32 accum.
__global__ __launch_bounds__(256) void k_logits(
        const unsigned short* __restrict__ Ahg, const unsigned short* __restrict__ Alg,
        const unsigned short* __restrict__ Bhg, float* __restrict__ C) {
    __shared__ short lds[3*128*64];
    short* Ah = lds;
    short* Al = lds + 8192;
    short* Bh = lds + 16384;
    int bm = blockIdx.x * 128, bn = blockIdx.y * 128;
    int t = threadIdx.x;
    int w = t >> 6, l = t & 63;
    int wr = w >> 1, wc = w & 1;
    int lr = l & 15, lk = l >> 4;
    f32x4 acc[4][4];
    #pragma unroll
    for (int mi = 0; mi < 4; ++mi)
        #pragma unroll
        for (int ni = 0; ni < 4; ++ni)
            acc[mi][ni] = (f32x4){0.f,0.f,0.f,0.f};

    for (int kc = 0; kc < 4; ++kc) {
        #pragma unroll
        for (int i = 0; i < 4; ++i) {
            int v = t + i*256;
            int row = v >> 3, cv = v & 7;
            int so = row*64 + ((cv ^ (row & 7)) << 3);
            size_t ga = (size_t)(bm+row)*256 + kc*64 + cv*8;
            size_t gb = (size_t)(bn+row)*256 + kc*64 + cv*8;
            *(bf16x8*)&Ah[so] = *(const bf16x8*)&Ahg[ga];
            *(bf16x8*)&Al[so] = *(const bf16x8*)&Alg[ga];
            *(bf16x8*)&Bh[so] = *(const bf16x8*)&Bhg[gb];
        }
        __syncthreads();
        #pragma unroll
        for (int s = 0; s < 2; ++s) {
            f16x8 ah[4], al[4], bh[4];
            #pragma unroll
            for (int mi = 0; mi < 4; ++mi) {
                int row = wr*64 + mi*16 + lr;
                int off = row*64 + ((((s<<2)+lk) ^ (row&7)) << 3);
                ah[mi] = *(f16x8*)&Ah[off];
                al[mi] = *(f16x8*)&Al[off];
            }
            #pragma unroll
            for (int ni = 0; ni < 4; ++ni) {
                int row = wc*64 + ni*16 + lr;
                int off = row*64 + ((((s<<2)+lk) ^ (row&7)) << 3);
                bh[ni] = *(f16x8*)&Bh[off];
            }
            #pragma unroll
            for (int mi = 0; mi < 4; ++mi)
                #pragma unroll
                for (int ni = 0; ni < 4; ++ni) {
                    acc[mi][ni] = __builtin_amdgcn_mfma_f32_16x16x32_f16(ah[mi], bh[ni], acc[mi][ni], 0, 0, 0);
                    acc[mi][ni] = __builtin_amdgcn_mfma_f32_16x16x32_f16(al[mi], bh[ni], acc[mi][ni], 0, 0, 0);
                }
        }
        __syncthreads();
    }
    #pragma unroll
    for (int mi = 0; mi < 4; ++mi)
        #pragma unroll
        for (int ni = 0; ni < 4; ++ni) {
            int col = bn + wc*64 + ni*16 + lr;
            #pragma unroll
            for (int r = 0; r < 4; ++r) {
                int row = bm + wr*64 + mi*16 + lk*4 + r;
                C[(size_t)row*VOCAB + col] = acc[mi][ni][r];
            }
        }
}

__global__ __launch_bounds__(128) void k_softmax_mask(float* __restrict__ A,
        const int* __restrict__ mask) {
    int row = blockIdx.x;
    int s = threadIdx.x;
    __shared__ float red[128];
    float v = A[(size_t)row*NUM_SLOTS + s] * SM_SCALE;
    red[s] = v; __syncthreads();
    for (int o = 64; o > 0; o >>= 1) { if (s < o) red[s] = fmaxf(red[s], red[s+o]); __syncthreads(); }
    float mx = red[0]; __syncthreads();
    float e = expf(v - mx);
    red[s] = e; __syncthreads();
    for (int o = 64; o > 0; o >>= 1) { if (s < o) red[s] += red[s+o]; __syncthreads(); }
    float sum = red[0];
    float m = (float)mask[row];
    A[(size_t)row*NUM_SLOTS + s] = e / sum * m;
}

// partial column sums: block (b, chunk) sums 64 l's
__global__ __launch_bounds__(128) void k_colsum(const float* __restrict__ A,
        float* __restrict__ csp) {
    int b = blockIdx.x; int ch = blockIdx.y; int s = threadIdx.x;
    const float* Ab = A + ((size_t)b*SEQ + ch*64)*NUM_SLOTS + s;
    float a0 = 0.f, a1 = 0.f, a2 = 0.f, a3 = 0.f;
    #pragma unroll
    for (int l = 0; l < 64; l += 4) {
        a0 += Ab[(size_t)(l+0)*NUM_SLOTS];
        a1 += Ab[(size_t)(l+1)*NUM_SLOTS];
        a2 += Ab[(size_t)(l+2)*NUM_SLOTS];
        a3 += Ab[(size_t)(l+3)*NUM_SLOTS];
    }
    csp[(b*8 + ch)*NUM_SLOTS + s] = (a0+a1) + (a2+a3);
}

// H_state = H + IR; writes fp32 and fp16 copies; sums 8 colsum partials
__global__ __launch_bounds__(256) void k_ir(const float* __restrict__ A,
        const float* __restrict__ V, const float* __restrict__ H,
        const float* __restrict__ csp, float* __restrict__ Hs,
        unsigned short* __restrict__ Hs16) {
    int bs = blockIdx.x; int b = bs >> 7; int s = bs & 127;
    int d = threadIdx.x;
    float sum = 1e-8f;
    #pragma unroll
    for (int p = 0; p < 8; ++p) sum += csp[(b*8 + p)*NUM_SLOTS + s];
    float inv = 1.0f / sum;
    const float* Ab = A + (size_t)b*SEQ*NUM_SLOTS + s;
    const float* Vb = V + (size_t)b*SEQ*D_MODEL + d;
    float a0 = 0.f, a1 = 0.f, a2 = 0.f, a3 = 0.f;
    for (int l = 0; l < SEQ; l += 4) {
        a0 += Ab[(size_t)(l+0)*NUM_SLOTS] * Vb[(size_t)(l+0)*D_MODEL];
        a1 += Ab[(size_t)(l+1)*NUM_SLOTS] * Vb[(size_t)(l+1)*D_MODEL];
        a2 += Ab[(size_t)(l+2)*NUM_SLOTS] * Vb[(size_t)(l+2)*D_MODEL];
        a3 += Ab[(size_t)(l+3)*NUM_SLOTS] * Vb[(size_t)(l+3)*D_MODEL];
    }
    float acc = (a0+a1) + (a2+a3);
    float v = H[s*D_MODEL + d] + acc * inv;
    Hs[(size_t)bs*D_MODEL + d] = v;
    Hs16[(size_t)bs*D_MODEL + d] = f2h(v);
}

// ---- one-time fp32->fp16 weight conversion into MFMA fragment order ----
__global__ __launch_bounds__(256) void k_convert_s(const float* __restrict__ Ws,
        unsigned short* __restrict__ WF) {
    int i = blockIdx.x, j = blockIdx.y, hf = blockIdx.z;
    int t = threadIdx.x;
    __shared__ float lds[128*33];
    size_t sBase = ((size_t)i*128 + j)*8192;
    size_t pOut = ((size_t)j*128 + i)*16384;
    const float4* s4 = (const float4*)(Ws + sBase) + hf*1024;
    #pragma unroll
    for (int p = 0; p < 4; ++p) {
        int f4 = p*256 + t;
        float4 v = s4[f4];
        *(float4*)&lds[(f4 >> 3)*33 + 4*(f4 & 7)] = v;
    }
    __syncthreads();
    bool diag = (i == j);
    #pragma unroll
    for (int q = 0; q < 2; ++q) {
        int cl = q*256 + t;
        int ksl = cl >> 7, mt = (cl >> 6) & 1, l = cl & 63;
        int g = l >> 4, c = l & 15;
        union { f16x8 v; } o;
        #pragma unroll
        for (int e = 0; e < 8; ++e) {
            float f = diag ? 0.f : lds[(ksl*32 + g*8 + e)*33 + mt*16 + c];
            o.v[e] = (_Float16)f;
        }
        *(f16x8*)(WF + pOut + (size_t)hf*4096 + (size_t)cl*8) = o.v;
    }
}

__global__ __launch_bounds__(256) void k_convert_t(const float* __restrict__ Wt,
        unsigned short* __restrict__ WF) {
    int i = blockIdx.x, j = blockIdx.y, hf = blockIdx.z;
    int t = threadIdx.x;
    __shared__ float lds[32*133];
    size_t sBase = ((size_t)i*128 + j)*8192;
    size_t pOut = ((size_t)j*128 + i)*16384;
    const float4* s4 = (const float4*)(Wt + sBase);
    #pragma unroll
    for (int p = 0; p < 4; ++p) {
        int idx = p*256 + t;
        int r = idx >> 5, c4 = idx & 31;
        float4 v = s4[r*64 + hf*32 + c4];
        *(float4*)&lds[r*133 + c4*4] = v;
    }
    __syncthreads();
    #pragma unroll
    for (int q = 0; q < 2; ++q) {
        int cl = q*256 + t;
        int ntl = cl >> 6, l = cl & 63;
        int g = l >> 4, c = l & 15;
        union { f16x8 v; } o;
        #pragma unroll
        for (int e = 0; e < 8; ++e)
            o.v[e] = (_Float16)lds[(g*8 + e)*133 + ntl*16 + c];
        *(f16x8*)(WF + pOut + 8192 + (size_t)hf*4096 + (size_t)cl*8) = o.v;
    }
}

// ---- MFMA slot-pair kernel (round-8 structure, unchanged) ----
__global__ __launch_bounds__(256, 4) void k_pairs_mfma(const unsigned short* __restrict__ h16,
        const unsigned short* __restrict__ WF, float* __restrict__ part) {
    __shared__ unsigned short lds[2*10240];
    int j = blockIdx.x, g = blockIdx.y;
    int t = threadIdx.x, w = t >> 6, l = t & 63;
    int lg = l >> 4, c = l & 15;
    const unsigned short* pbase = WF + ((size_t)j*128 + g*16)*16384;

    {
        const unsigned short* src = pbase;
        #pragma unroll
        for (int q = 0; q < 4; ++q)
            GLD_LDS16(src + (size_t)(q*256 + t)*8, &lds[(q*256 + t)*8]);
        const unsigned short* hsrc = h16 + ((size_t)(t&7)*NUM_SLOTS + g*16)*D_MODEL + (t>>3)*8;
        GLD_LDS16(hsrc, &lds[8192 + t*8]);
    }
    __builtin_amdgcn_sched_barrier(0);
    f16x8 bqn[4];
    #pragma unroll
    for (int nt = 0; nt < 4; ++nt)
        bqn[nt] = *(const f16x8*)(pbase + 8192 + (size_t)((w*4+nt)*64 + l)*8);
    __builtin_amdgcn_sched_barrier(0);

    f32x4 acc[4];
    #pragma unroll
    for (int nt = 0; nt < 4; ++nt) acc[nt] = (f32x4){0.f,0.f,0.f,0.f};
    f16x8 hzero;
    #pragma unroll
    for (int e = 0; e < 8; ++e) hzero[e] = (_Float16)0.f;

    #pragma unroll 2
    for (int ii = 0; ii < 16; ++ii) {
        int cur = ii & 1;
        asm volatile("s_waitcnt vmcnt(4) lgkmcnt(0)" ::: "memory");
        __builtin_amdgcn_s_barrier();
        __builtin_amdgcn_sched_barrier(0);
        if (ii < 15) {
            const unsigned short* src = pbase + (size_t)(ii+1)*16384;
            unsigned short* dst = &lds[(cur^1)*10240];
            #pragma unroll
            for (int q = 0; q < 4; ++q)
                GLD_LDS16(src + (size_t)(q*256 + t)*8, dst + (size_t)(q*256 + t)*8);
            const unsigned short* hsrc = h16 + ((size_t)(t&7)*NUM_SLOTS + (g*16+ii+1))*D_MODEL + (t>>3)*8;
            GLD_LDS16(hsrc, dst + 8192 + (size_t)t*8);
        }
        __builtin_amdgcn_sched_barrier(0);
        f16x8 bq[4];
        #pragma unroll
        for (int nt = 0; nt < 4; ++nt) bq[nt] = bqn[nt];
        if (ii < 15) {
            const unsigned short* bp = pbase + (size_t)(ii+1)*16384 + 8192;
            #pragma unroll
            for (int nt = 0; nt < 4; ++nt)
                bqn[nt] = *(const f16x8*)(bp + (size_t)((w*4+nt)*64 + l)*8);
        }
        const unsigned short* buf = &lds[cur*10240];
        f32x4 d1[2];
        d1[0] = (f32x4){0.f,0.f,0.f,0.f};
        d1[1] = (f32x4){0.f,0.f,0.f,0.f};
        #pragma unroll
        for (int ks = 0; ks < 8; ++ks) {
            f16x8 a0 = *(const f16x8*)(buf + (size_t)((ks*2+0)*64 + l)*8);
            f16x8 a1 = *(const f16x8*)(buf + (size_t)((ks*2+1)*64 + l)*8);
            f16x8 hv = *(const f16x8*)(buf + 8192 + (size_t)(((ks*4+lg)*8 + (c&7)))*8);
            f16x8 hb = (c < 8) ? hv : hzero;
            d1[0] = __builtin_amdgcn_mfma_f32_16x16x32_f16(a0, hb, d1[0], 0, 0, 0);
            d1[1] = __builtin_amdgcn_mfma_f32_16x16x32_f16(a1, hb, d1[1], 0, 0, 0);
        }
        unsigned q0 = pk2(d1[0][0], d1[0][1]);
        unsigned q1 = pk2(d1[0][2], d1[0][3]);
        unsigned s0 = pk2(d1[1][0], d1[1][1]);
        unsigned s1 = pk2(d1[1][2], d1[1][3]);
        int srcLo = 32*(lg & 1) + c;
        int srcHi = srcLo + 16;
        unsigned a0s = (unsigned)__shfl((int)q0, srcLo, 64);
        unsigned a1s = (unsigned)__shfl((int)q1, srcLo, 64);
        unsigned a2s = (unsigned)__shfl((int)q0, srcHi, 64);
        unsigned a3s = (unsigned)__shfl((int)q1, srcHi, 64);
        unsigned b0s = (unsigned)__shfl((int)s0, srcLo, 64);
        unsigned b1s = (unsigned)__shfl((int)s1, srcLo, 64);
        unsigned b2s = (unsigned)__shfl((int)s0, srcHi, 64);
        unsigned b3s = (unsigned)__shfl((int)s1, srcHi, 64);
        bool himt = ((lg >> 1) & 1);
        union { unsigned u[4]; f16x8 v; } A2u;
        A2u.u[0] = himt ? b0s : a0s;
        A2u.u[1] = himt ? b1s : a1s;
        A2u.u[2] = himt ? b2s : a2s;
        A2u.u[3] = himt ? b3s : a3s;
        #pragma unroll
        for (int nt = 0; nt < 4; ++nt)
            acc[nt] = __builtin_amdgcn_mfma_f32_16x16x32_f16(A2u.v, bq[nt], acc[nt], 0, 0, 0);
    }
    if (lg < 2) {
        #pragma unroll
        for (int nt = 0; nt < 4; ++nt) {
            int d = (w*4 + nt)*16 + c;
            #pragma unroll
            for (int r = 0; r < 4; ++r) {
                int b = lg*4 + r;
                part[(((size_t)g*BATCH + b)*NUM_SLOTS + j)*D_MODEL + d] = acc[nt][r];
            }
        }
    }
}

// fallback fp32 pairs kernel (used when ws too small for WF)
__global__ __launch_bounds__(256) void k_pairs(const float* __restrict__ h,
        const float* __restrict__ Ws, const float* __restrict__ Wt,
        float* __restrict__ part) {
    int j = blockIdx.x;
    int g = blockIdx.y;
    int t = threadIdx.x;
    __shared__ float sh_h[BATCH][D_MODEL];
    __shared__ float sh_inter[BATCH][RANK];
    float acc[BATCH];
    #pragma unroll
    for (int b = 0; b < BATCH; ++b) acc[b] = 0.f;
    int tb = t >> 5, tr = t & 31;
    for (int ii = 0; ii < IPG; ++ii) {
        int i = g*IPG + ii;
        if (i == j) continue;
        #pragma unroll
        for (int b = 0; b < BATCH; ++b)
            sh_h[b][t] = h[((size_t)b*NUM_SLOTS + i)*D_MODEL + t];
        __syncthreads();
        const float* ws = Ws + ((size_t)i*NUM_SLOTS + j)*(D_MODEL*RANK);
        float accA = 0.f;
        #pragma unroll 8
        for (int d = 0; d < D_MODEL; ++d)
            accA += sh_h[tb][d] * ws[(size_t)d*RANK + tr];
        sh_inter[tb][tr] = accA;
        __syncthreads();
        const float* wt = Wt + ((size_t)i*NUM_SLOTS + j)*(RANK*D_MODEL);
        #pragma unroll 8
        for (int r = 0; r < RANK; ++r) {
            float w = wt[(size_t)r*D_MODEL + t];
            #pragma unroll
            for (int b = 0; b < BATCH; ++b) acc[b] += sh_inter[b][r] * w;
        }
        __syncthreads();
    }
    #pragma unroll
    for (int b = 0; b < BATCH; ++b)
        part[(((size_t)g*BATCH + b)*NUM_SLOTS + j)*D_MODEL + t] = acc[b];
}

// h = LN(h + relu(sum_g part)); writes fp32 and fp16 copies
__global__ __launch_bounds__(256) void k_ln(float* __restrict__ h,
        unsigned short* __restrict__ h16, const float* __restrict__ part,
        const float* __restrict__ gma, const float* __restrict__ bta) {
    int bj = blockIdx.x;
    int t = threadIdx.x;
    int b = bj >> 7, j = bj & 127;
    __shared__ float red[256];
    float v = 0.f;
    #pragma unroll
    for (int g = 0; g < IGROUPS; ++g)
        v += part[(((size_t)g*BATCH + b)*NUM_SLOTS + j)*D_MODEL + t];
    float x = h[(size_t)bj*D_MODEL + t] + fmaxf(v, 0.f);
    red[t] = x; __syncthreads();
    for (int o = 128; o > 0; o >>= 1) { if (t < o) red[t] += red[t+o]; __syncthreads(); }
    float mu = red[0] * (1.0f/D_MODEL); __syncthreads();
    float dx = x - mu;
    red[t] = dx*dx; __syncthreads();
    for (int o = 128; o > 0; o >>= 1) { if (t < o) red[t] += red[t+o]; __syncthreads(); }
    float var = red[0] * (1.0f/D_MODEL);
    float outv = dx * rsqrtf(var + LN_EPS) * gma[t] + bta[t];
    h[(size_t)bj*D_MODEL + t] = outv;
    h16[(size_t)bj*D_MODEL + t] = f2h(outv);
}

__global__ __launch_bounds__(128) void k_attn2(const float* __restrict__ Q,
        const float* __restrict__ Kf, float* __restrict__ A2) {
    int bl = blockIdx.x; int b = bl / SEQ;
    int s = threadIdx.x;
    __shared__ float q[D_MODEL];
    __shared__ float red[128];
    q[s]       = Q[(size_t)bl*D_MODEL + s];
    q[s + 128] = Q[(size_t)bl*D_MODEL + s + 128];
    __syncthreads();
    const float* kf = Kf + ((size_t)b*NUM_SLOTS + s)*D_MODEL;
    float acc = 0.f;
    #pragma unroll 8
    for (int d = 0; d < D_MODEL; ++d) acc += q[d]*kf[d];
    acc *= SM_SCALE;
    red[s] = acc; __syncthreads();
    for (int o = 64; o > 0; o >>= 1) { if (s < o) red[s] = fmaxf(red[s], red[s+o]); __syncthreads(); }
    float mx = red[0]; __syncthreads();
    float e = expf(acc - mx);
    red[s] = e; __syncthreads();
    for (int o = 64; o > 0; o >>= 1) { if (s < o) red[s] += red[s+o]; __syncthreads(); }
    A2[(size_t)bl*NUM_SLOTS + s] = e / red[0];
}

// Y = A2 @ Vf, written as split fp16 hi/lo for the logits GEMM
__global__ __launch_bounds__(256) void k_y(const float* __restrict__ A2,
        const float* __restrict__ Vf, unsigned short* __restrict__ Yh,
        unsigned short* __restrict__ Yl) {
    int bl = blockIdx.x; int b = bl / SEQ;
    int d = threadIdx.x;
    const float* a = A2 + (size_t)bl*NUM_SLOTS;
    const float* v = Vf + (size_t)b*NUM_SLOTS*D_MODEL + d;
    float acc = 0.f;
    #pragma unroll 4
    for (int s = 0; s < NUM_SLOTS; ++s) acc += a[s]*v[(size_t)s*D_MODEL];
    unsigned short yh = f2h(acc);
    Yh[(size_t)bl*D_MODEL + d] = yh;
    Yl[(size_t)bl*D_MODEL + d] = f2h(acc - h2f(yh));
}

extern "C" void kernel_launch(void* const* d_in, const int* in_sizes, int n_in,
                              void* d_out, int out_size, void* d_ws, size_t ws_size,
                              hipStream_t stream) {
    const int*   ids    = (const int*)d_in[0];
    const int*   amask  = (const int*)d_in[1];
    const float* tok    = (const float*)d_in[2];
    const float* pos    = (const float*)d_in[3];
    const float* Hin    = (const float*)d_in[4];
    const float* Ws     = (const float*)d_in[5];
    const float* Wt     = (const float*)d_in[6];
    const float* Wq_in  = (const float*)d_in[7];
    const float* Wk_sl  = (const float*)d_in[8];
    const float* Wv_in  = (const float*)d_in[9];
    const float* Wq_out = (const float*)d_in[10];
    const float* Wk_fin = (const float*)d_in[11];
    const float* Wv_fin = (const float*)d_in[12];
    const float* Wop    = (const float*)d_in[13];
    const float* lnsc   = (const float*)d_in[14];
    const float* lnbs   = (const float*)d_in[15];
    float* out = (float*)d_out;

    const size_t WF_USH = (size_t)16384 * 16384;     // 512 MiB of ushorts
    const size_t F32_FLOATS = 18600000ULL;           // fp32+fp16 scratch region
    const bool useF16 = ws_size >= WF_USH*2 + F32_FLOATS*4 + 256;

    unsigned short* WF = (unsigned short*)d_ws;
    float* ws = useF16 ? (float*)(WF + WF_USH) : (float*)d_ws;

    float* X    = ws;
    float* Qin  = X    + (size_t)NTOK*D_MODEL;
    float* Vin  = Qin  + (size_t)NTOK*D_MODEL;
    float* Ksl  = Vin  + (size_t)NTOK*D_MODEL;
    float* Asc  = Ksl  + (size_t)NUM_SLOTS*D_MODEL;
    float* csp  = Asc  + (size_t)NTOK*NUM_SLOTS;          // 8*8*128 partials
    float* Hst  = csp  + (size_t)BATCH*8*NUM_SLOTS;
    float* part = Hst  + (size_t)BATCH*NUM_SLOTS*D_MODEL;
    float* Qout = part + (size_t)IGROUPS*BATCH*NUM_SLOTS*D_MODEL;
    float* Kf   = Qout + (size_t)NTOK*D_MODEL;
    float* Vf   = Kf   + (size_t)BATCH*NUM_SLOTS*D_MODEL;
    float* A2   = Vf   + (size_t)BATCH*NUM_SLOTS*D_MODEL;
    float* Yb   = A2   + (size_t)NTOK*NUM_SLOTS;
    unsigned short* Yh = (unsigned short*)(Yb + (size_t)NTOK*D_MODEL);
    unsigned short* Yl = Yh + (size_t)NTOK*D_MODEL;
    unsigned short* Wf16 = Yl + (size_t)NTOK*D_MODEL;
    unsigned short* Hst16 = Wf16 + (size_t)VOCAB*D_MODEL;

    // one-time weight conversions (independent of the rest)
    if (useF16) {
        k_convert_s<<<dim3(128, 128, 2), 256, 0, stream>>>(Ws, WF);
        k_convert_t<<<dim3(128, 128, 2), 256, 0, stream>>>(Wt, WF);
    }
    k_split16<<<(VOCAB*D_MODEL/4 + 255)/256, 256, 0, stream>>>(Wop, Wf16, VOCAB*D_MODEL/4);

    // embeddings
    k_embed<<<NTOK, 256, 0, stream>>>(ids, tok, pos, X);
    // X projections (Qin, Vin, Qout) fused into one dispatch
    k_gemm3<<<dim3(NTOK/64, 4, 3), 256, 0, stream>>>(X, Wq_in, Wv_in, Wq_out, Qin, Vin, Qout);
    k_gemm_nt<<<dim3(2, 4), 256, 0, stream>>>(Hin, Wk_sl, Ksl, NUM_SLOTS, D_MODEL, D_MODEL);
    // scores + softmax + mask
    k_gemm_nt<<<dim3(NTOK/64, 2), 256, 0, stream>>>(Qin, Ksl, Asc, NTOK, NUM_SLOTS, D_MODEL);
    k_softmax_mask<<<NTOK, 128, 0, stream>>>(Asc, amask);
    // column-normalize + aggregate into slots
    k_colsum<<<dim3(BATCH, 8), 128, 0, stream>>>(Asc, csp);
    k_ir<<<BATCH*NUM_SLOTS, 256, 0, stream>>>(Asc, Vin, Hin, csp, Hst, Hst16);
    // bilinear slot-interaction steps
    for (int st = 0; st < N_STEPS; ++st) {
        if (useF16)
            k_pairs_mfma<<<dim3(NUM_SLOTS, IGROUPS), 256, 0, stream>>>(Hst16, WF, part);
        else
            k_pairs<<<dim3(NUM_SLOTS, IGROUPS), 256, 0, stream>>>(Hst, Ws, Wt, part);
        k_ln<<<BATCH*NUM_SLOTS, 256, 0, stream>>>(Hst, Hst16, part, lnsc + st*D_MODEL, lnbs + st*D_MODEL);
    }
    // expand projections
    k_gemm_nt<<<dim3(BATCH*NUM_SLOTS/64, 4), 256, 0, stream>>>(Hst, Wk_fin, Kf, BATCH*NUM_SLOTS, D_MODEL, D_MODEL);
    k_gemm_nt<<<dim3(BATCH*NUM_SLOTS/64, 4), 256, 0, stream>>>(Hst, Wv_fin, Vf, BATCH*NUM_SLOTS, D_MODEL, D_MODEL);
    // expand attention
    k_attn2<<<NTOK, 128, 0, stream>>>(Qout, Kf, A2);
    k_y<<<NTOK, 256, 0, stream>>>(A2, Vf, Yh, Yl);
    // logits: 2-pass fp16-split MFMA
    k_logits<<<dim3(NTOK/128, VOCAB/128), 256, 0, stream>>>(Yh, Yl, Wf16, out);
}

// Round 10
// 1471.180 us; speedup vs baseline: 1.3798x; 1.0284x over previous
//
#include <hip/hip_runtime.h>
#include <hip/hip_bf16.h>
#include <math.h>

#define D_MODEL 256
#define NUM_SLOTS 128
#define RANK 32
#define N_STEPS 6
#define VOCAB 32000
#define SEQ 512
#define BATCH 8
#define NTOK (BATCH*SEQ)
#define LN_EPS 1e-5f
#define SM_SCALE 0.0625f
#define IGROUPS 8
#define IPG (NUM_SLOTS/IGROUPS)

typedef __attribute__((ext_vector_type(8))) short bf16x8;
typedef __attribute__((ext_vector_type(8))) _Float16 f16x8;
typedef __attribute__((ext_vector_type(4))) float f32x4;

#define GLD_LDS16(g, l) __builtin_amdgcn_global_load_lds( \
    (const __attribute__((address_space(1))) unsigned int*)(g), \
    (__attribute__((address_space(3))) unsigned int*)(l), 16, 0, 0)

__device__ inline unsigned short f2bf(float x) {
    unsigned u = __float_as_uint(x);
    unsigned r = u + 0x7fff + ((u >> 16) & 1);
    return (unsigned short)(r >> 16);
}
__device__ inline float bf2f(unsigned short h) {
    return __uint_as_float(((unsigned)h) << 16);
}
__device__ inline unsigned pk2(float a, float b) {
    auto v = __builtin_amdgcn_cvt_pkrtz(a, b);
    union { decltype(v) x; unsigned u; } c;
    c.x = v;
    return c.u;
}
__device__ inline unsigned short f2h(float x) {
    union { _Float16 h; unsigned short u; } c;
    c.h = (_Float16)x;
    return c.u;
}
__device__ inline float h2f(unsigned short u) {
    union { unsigned short u; _Float16 h; } c;
    c.u = u;
    return (float)c.h;
}

// X[b,l,:] = token_emb[ids[b,l],:] + pos_emb[l,:]
__global__ __launch_bounds__(256) void k_embed(const int* __restrict__ ids,
        const float* __restrict__ tok, const float* __restrict__ pos,
        float* __restrict__ X) {
    int bl = blockIdx.x;
    int d  = threadIdx.x;
    int l  = bl % SEQ;
    int id = ids[bl];
    X[(size_t)bl*D_MODEL + d] = tok[(size_t)id*D_MODEL + d] + pos[l*D_MODEL + d];
}

// C[m,n] = sum_k A[m,k]*B[n,k]   (both row-major, K contiguous)  64x64 tile
__global__ __launch_bounds__(256) void k_gemm_nt(const float* __restrict__ A,
        const float* __restrict__ B, float* __restrict__ C, int M, int N, int K) {
    __shared__ float As[32][64];
    __shared__ float Bs[32][64];
    int bm = blockIdx.x * 64, bn = blockIdx.y * 64;
    int t = threadIdx.x;
    int tm = (t & 15) * 4, tn = (t >> 4) * 4;
    float acc[4][4] = {};
    for (int k0 = 0; k0 < K; k0 += 32) {
        #pragma unroll
        for (int r = 0; r < 8; ++r) {
            int idx = r*256 + t;
            int m = idx >> 5, k = idx & 31;
            As[k][m] = A[(size_t)(bm+m)*K + k0 + k];
        }
        #pragma unroll
        for (int r = 0; r < 8; ++r) {
            int idx = r*256 + t;
            int n = idx >> 5, k = idx & 31;
            Bs[k][n] = B[(size_t)(bn+n)*K + k0 + k];
        }
        __syncthreads();
        #pragma unroll
        for (int k = 0; k < 32; ++k) {
            float4 a4 = *(const float4*)&As[k][tm];
            float4 b4 = *(const float4*)&Bs[k][tn];
            float a[4] = {a4.x,a4.y,a4.z,a4.w};
            float b[4] = {b4.x,b4.y,b4.z,b4.w};
            #pragma unroll
            for (int i = 0; i < 4; ++i)
                #pragma unroll
                for (int jj = 0; jj < 4; ++jj)
                    acc[i][jj] += a[i]*b[jj];
        }
        __syncthreads();
    }
    #pragma unroll
    for (int i = 0; i < 4; ++i) {
        float4 v = make_float4(acc[i][0],acc[i][1],acc[i][2],acc[i][3]);
        *(float4*)&C[(size_t)(bm+tm+i)*N + bn+tn] = v;
    }
}

// 3 projections (Qin, Vin, Qout) from the same A=X, selected by blockIdx.z
__global__ __launch_bounds__(256) void k_gemm3(const float* __restrict__ A,
        const float* __restrict__ B0, const float* __restrict__ B1,
        const float* __restrict__ B2, float* __restrict__ C0,
        float* __restrict__ C1, float* __restrict__ C2) {
    const int K = D_MODEL, N = D_MODEL;
    const float* B = blockIdx.z == 0 ? B0 : (blockIdx.z == 1 ? B1 : B2);
    float* C = blockIdx.z == 0 ? C0 : (blockIdx.z == 1 ? C1 : C2);
    __shared__ float As[32][64];
    __shared__ float Bs[32][64];
    int bm = blockIdx.x * 64, bn = blockIdx.y * 64;
    int t = threadIdx.x;
    int tm = (t & 15) * 4, tn = (t >> 4) * 4;
    float acc[4][4] = {};
    for (int k0 = 0; k0 < K; k0 += 32) {
        #pragma unroll
        for (int r = 0; r < 8; ++r) {
            int idx = r*256 + t;
            int m = idx >> 5, k = idx & 31;
            As[k][m] = A[(size_t)(bm+m)*K + k0 + k];
        }
        #pragma unroll
        for (int r = 0; r < 8; ++r) {
            int idx = r*256 + t;
            int n = idx >> 5, k = idx & 31;
            Bs[k][n] = B[(size_t)(bn+n)*K + k0 + k];
        }
        __syncthreads();
        #pragma unroll
        for (int k = 0; k < 32; ++k) {
            float4 a4 = *(const float4*)&As[k][tm];
            float4 b4 = *(const float4*)&Bs[k][tn];
            float a[4] = {a4.x,a4.y,a4.z,a4.w};
            float b[4] = {b4.x,b4.y,b4.z,b4.w};
            #pragma unroll
            for (int i = 0; i < 4; ++i)
                #pragma unroll
                for (int jj = 0; jj < 4; ++jj)
                    acc[i][jj] += a[i]*b[jj];
        }
        __syncthreads();
    }
    #pragma unroll
    for (int i = 0; i < 4; ++i) {
        float4 v = make_float4(acc[i][0],acc[i][1],acc[i][2],acc[i][3]);
        *(float4*)&C[(size_t)(bm+tm+i)*N + bn+tn] = v;
    }
}

// Kf/Vf projections from Hst, selected by blockIdx.z
__global__ __launch_bounds__(256) void k_kfvf(const float* __restrict__ A,
        const float* __restrict__ B0, const float* __restrict__ B1,
        float* __restrict__ C0, float* __restrict__ C1) {
    const int K = D_MODEL, N = D_MODEL;
    const float* B = blockIdx.z == 0 ? B0 : B1;
    float* C = blockIdx.z == 0 ? C0 : C1;
    __shared__ float As[32][64];
    __shared__ float Bs[32][64];
    int bm = blockIdx.x * 64, bn = blockIdx.y * 64;
    int t = threadIdx.x;
    int tm = (t & 15) * 4, tn = (t >> 4) * 4;
    float acc[4][4] = {};
    for (int k0 = 0; k0 < K; k0 += 32) {
        #pragma unroll
        for (int r = 0; r < 8; ++r) {
            int idx = r*256 + t;
            int m = idx >> 5, k = idx & 31;
            As[k][m] = A[(size_t)(bm+m)*K + k0 + k];
        }
        #pragma unroll
        for (int r = 0; r < 8; ++r) {
            int idx = r*256 + t;
            int n = idx >> 5, k = idx & 31;
            Bs[k][n] = B[(size_t)(bn+n)*K + k0 + k];
        }
        __syncthreads();
        #pragma unroll
        for (int k = 0; k < 32; ++k) {
            float4 a4 = *(const float4*)&As[k][tm];
            float4 b4 = *(const float4*)&Bs[k][tn];
            float a[4] = {a4.x,a4.y,a4.z,a4.w};
            float b[4] = {b4.x,b4.y,b4.z,b4.w};
            #pragma unroll
            for (int i = 0; i < 4; ++i)
                #pragma unroll
                for (int jj = 0; jj < 4; ++jj)
                    acc[i][jj] += a[i]*b[jj];
        }
        __syncthreads();
    }
    #pragma unroll
    for (int i = 0; i < 4; ++i) {
        float4 v = make_float4(acc[i][0],acc[i][1],acc[i][2],acc[i][3]);
        *(float4*)&C[(size_t)(bm+tm+i)*N + bn+tn] = v;
    }
}

// fp32 -> fp16 (for W_out_proj)
__global__ __launch_bounds__(256) void k_split16(const float* __restrict__ in,
        unsigned short* __restrict__ o, int n4) {
    int i = blockIdx.x*256 + threadIdx.x;
    if (i >= n4) return;
    float4 v = ((const float4*)in)[i];
    ushort4 h;
    h.x = f2h(v.x); h.y = f2h(v.y); h.z = f2h(v.z); h.w = f2h(v.w);
    ((ushort4*)o)[i] = h;
}

// logits GEMM: 2-pass fp16-split MFMA, m97-style global_load_lds staging.
// C = (Yh+Yl) * W16^T, fp32 accum. 128x128 tile, BK=64, single-buffer 48KB.
__global__ __launch_bounds__(256) void k_logits(
        const unsigned short* __restrict__ Ahg, const unsigned short* __restrict__ Alg,
        const unsigned short* __restrict__ Bhg, float* __restrict__ C) {
    __shared__ unsigned short lds[3*8192];   // Ah | Al | Bh, each [128][64] linear
    int bm = blockIdx.x * 128, bn = blockIdx.y * 128;
    int t = threadIdx.x;
    int w = t >> 6, l = t & 63;
    int wr = w >> 1, wc = w & 1;
    int lr = l & 15, lk = l >> 4;
    f32x4 acc[4][4];
    #pragma unroll
    for (int mi = 0; mi < 4; ++mi)
        #pragma unroll
        for (int ni = 0; ni < 4; ++ni)
            acc[mi][ni] = (f32x4){0.f,0.f,0.f,0.f};

    for (int kc = 0; kc < 4; ++kc) {
        if (kc) __syncthreads();      // prev compute done before overwrite
        #pragma unroll
        for (int i = 0; i < 4; ++i) {
            int c = t + i*256;        // chunk 0..1023; row = c>>3, col8 = c&7
            int row = c >> 3, c8 = c & 7;
            size_t ga = (size_t)(bm+row)*256 + kc*64 + c8*8;
            size_t gb = (size_t)(bn+row)*256 + kc*64 + c8*8;
            GLD_LDS16(Ahg + ga, &lds[c*8]);
            GLD_LDS16(Alg + ga, &lds[8192 + c*8]);
            GLD_LDS16(Bhg + gb, &lds[16384 + c*8]);
        }
        __syncthreads();              // drains vmcnt(0) -> LDS ready
        #pragma unroll
        for (int s = 0; s < 2; ++s) {
            f16x8 ah[4], al[4], bh[4];
            #pragma unroll
            for (int mi = 0; mi < 4; ++mi) {
                int off = (wr*64 + mi*16 + lr)*64 + s*32 + lk*8;
                ah[mi] = *(const f16x8*)&lds[off];
                al[mi] = *(const f16x8*)&lds[8192 + off];
            }
            #pragma unroll
            for (int ni = 0; ni < 4; ++ni) {
                int off = (wc*64 + ni*16 + lr)*64 + s*32 + lk*8;
                bh[ni] = *(const f16x8*)&lds[16384 + off];
            }
            #pragma unroll
            for (int mi = 0; mi < 4; ++mi)
                #pragma unroll
                for (int ni = 0; ni < 4; ++ni) {
                    acc[mi][ni] = __builtin_amdgcn_mfma_f32_16x16x32_f16(ah[mi], bh[ni], acc[mi][ni], 0, 0, 0);
                    acc[mi][ni] = __builtin_amdgcn_mfma_f32_16x16x32_f16(al[mi], bh[ni], acc[mi][ni], 0, 0, 0);
                }
        }
    }
    #pragma unroll
    for (int mi = 0; mi < 4; ++mi)
        #pragma unroll
        for (int ni = 0; ni < 4; ++ni) {
            int col = bn + wc*64 + ni*16 + lr;
            #pragma unroll
            for (int r = 0; r < 4; ++r) {
                int row = bm + wr*64 + mi*16 + lk*4 + r;
                C[(size_t)row*VOCAB + col] = acc[mi][ni][r];
            }
        }
}

__global__ __launch_bounds__(128) void k_softmax_mask(float* __restrict__ A,
        const int* __restrict__ mask) {
    int row = blockIdx.x;
    int s = threadIdx.x;
    __shared__ float red[128];
    float v = A[(size_t)row*NUM_SLOTS + s] * SM_SCALE;
    red[s] = v; __syncthreads();
    for (int o = 64; o > 0; o >>= 1) { if (s < o) red[s] = fmaxf(red[s], red[s+o]); __syncthreads(); }
    float mx = red[0]; __syncthreads();
    float e = expf(v - mx);
    red[s] = e; __syncthreads();
    for (int o = 64; o > 0; o >>= 1) { if (s < o) red[s] += red[s+o]; __syncthreads(); }
    float sum = red[0];
    float m = (float)mask[row];
    A[(size_t)row*NUM_SLOTS + s] = e / sum * m;
}

// partial column sums: block (b, chunk) sums 64 l's
__global__ __launch_bounds__(128) void k_colsum(const float* __restrict__ A,
        float* __restrict__ csp) {
    int b = blockIdx.x; int ch = blockIdx.y; int s = threadIdx.x;
    const float* Ab = A + ((size_t)b*SEQ + ch*64)*NUM_SLOTS + s;
    float a0 = 0.f, a1 = 0.f, a2 = 0.f, a3 = 0.f;
    #pragma unroll
    for (int l = 0; l < 64; l += 4) {
        a0 += Ab[(size_t)(l+0)*NUM_SLOTS];
        a1 += Ab[(size_t)(l+1)*NUM_SLOTS];
        a2 += Ab[(size_t)(l+2)*NUM_SLOTS];
        a3 += Ab[(size_t)(l+3)*NUM_SLOTS];
    }
    csp[(b*8 + ch)*NUM_SLOTS + s] = (a0+a1) + (a2+a3);
}

// H_state = H + IR; writes fp32 and fp16 copies; sums 8 colsum partials
__global__ __launch_bounds__(256) void k_ir(const float* __restrict__ A,
        const float* __restrict__ V, const float* __restrict__ H,
        const float* __restrict__ csp, float* __restrict__ Hs,
        unsigned short* __restrict__ Hs16) {
    int bs = blockIdx.x; int b = bs >> 7; int s = bs & 127;
    int d = threadIdx.x;
    float sum = 1e-8f;
    #pragma unroll
    for (int p = 0; p < 8; ++p) sum += csp[(b*8 + p)*NUM_SLOTS + s];
    float inv = 1.0f / sum;
    const float* Ab = A + (size_t)b*SEQ*NUM_SLOTS + s;
    const float* Vb = V + (size_t)b*SEQ*D_MODEL + d;
    float a0 = 0.f, a1 = 0.f, a2 = 0.f, a3 = 0.f;
    for (int l = 0; l < SEQ; l += 4) {
        a0 += Ab[(size_t)(l+0)*NUM_SLOTS] * Vb[(size_t)(l+0)*D_MODEL];
        a1 += Ab[(size_t)(l+1)*NUM_SLOTS] * Vb[(size_t)(l+1)*D_MODEL];
        a2 += Ab[(size_t)(l+2)*NUM_SLOTS] * Vb[(size_t)(l+2)*D_MODEL];
        a3 += Ab[(size_t)(l+3)*NUM_SLOTS] * Vb[(size_t)(l+3)*D_MODEL];
    }
    float acc = (a0+a1) + (a2+a3);
    float v = H[s*D_MODEL + d] + acc * inv;
    Hs[(size_t)bs*D_MODEL + d] = v;
    Hs16[(size_t)bs*D_MODEL + d] = f2h(v);
}

// ---- one-time fp32->fp16 weight conversion into MFMA fragment order ----
// blockIdx.z: 0,1 = Ws halves; 2,3 = Wt halves.
__global__ __launch_bounds__(256) void k_convert(const float* __restrict__ Ws,
        const float* __restrict__ Wt, unsigned short* __restrict__ WF) {
    int i = blockIdx.x, j = blockIdx.y, z = blockIdx.z;
    int t = threadIdx.x;
    __shared__ float lds[4352];
    size_t sBase = ((size_t)i*128 + j)*8192;
    size_t pOut = ((size_t)j*128 + i)*16384;
    if (z < 2) {
        int hf = z;
        const float4* s4 = (const float4*)(Ws + sBase) + hf*1024;
        #pragma unroll
        for (int p = 0; p < 4; ++p) {
            int f4 = p*256 + t;
            float4 v = s4[f4];
            *(float4*)&lds[(f4 >> 3)*33 + 4*(f4 & 7)] = v;
        }
        __syncthreads();
        bool diag = (i == j);
        #pragma unroll
        for (int q = 0; q < 2; ++q) {
            int cl = q*256 + t;
            int ksl = cl >> 7, mt = (cl >> 6) & 1, l = cl & 63;
            int g = l >> 4, c = l & 15;
            union { f16x8 v; } o;
            #pragma unroll
            for (int e = 0; e < 8; ++e) {
                float f = diag ? 0.f : lds[(ksl*32 + g*8 + e)*33 + mt*16 + c];
                o.v[e] = (_Float16)f;
            }
            *(f16x8*)(WF + pOut + (size_t)hf*4096 + (size_t)cl*8) = o.v;
        }
    } else {
        int hf = z - 2;
        const float4* s4 = (const float4*)(Wt + sBase);
        #pragma unroll
        for (int p = 0; p < 4; ++p) {
            int idx = p*256 + t;
            int r = idx >> 5, c4 = idx & 31;
            float4 v = s4[r*64 + hf*32 + c4];
            *(float4*)&lds[r*133 + c4*4] = v;
        }
        __syncthreads();
        #pragma unroll
        for (int q = 0; q < 2; ++q) {
            int cl = q*256 + t;
            int ntl = cl >> 6, l = cl & 63;
            int g = l >> 4, c = l & 15;
            union { f16x8 v; } o;
            #pragma unroll
            for (int e = 0; e < 8; ++e)
                o.v[e] = (_Float16)lds[(g*8 + e)*133 + ntl*16 + c];
            *(f16x8*)(WF + pOut + 8192 + (size_t)hf*4096 + (size_t)cl*8) = o.v;
        }
    }
}

// ---- MFMA slot-pair kernel (round-8 structure, unchanged) ----
__global__ __launch_bounds__(256, 4) void k_pairs_mfma(const unsigned short* __restrict__ h16,
        const unsigned short* __restrict__ WF, float* __restrict__ part) {
    __shared__ unsigned short lds[2*10240];
    int j = blockIdx.x, g = blockIdx.y;
    int t = threadIdx.x, w = t >> 6, l = t & 63;
    int lg = l >> 4, c = l & 15;
    const unsigned short* pbase = WF + ((size_t)j*128 + g*16)*16384;

    {
        const unsigned short* src = pbase;
        #pragma unroll
        for (int q = 0; q < 4; ++q)
            GLD_LDS16(src + (size_t)(q*256 + t)*8, &lds[(q*256 + t)*8]);
        const unsigned short* hsrc = h16 + ((size_t)(t&7)*NUM_SLOTS + g*16)*D_MODEL + (t>>3)*8;
        GLD_LDS16(hsrc, &lds[8192 + t*8]);
    }
    __builtin_amdgcn_sched_barrier(0);
    f16x8 bqn[4];
    #pragma unroll
    for (int nt = 0; nt < 4; ++nt)
        bqn[nt] = *(const f16x8*)(pbase + 8192 + (size_t)((w*4+nt)*64 + l)*8);
    __builtin_amdgcn_sched_barrier(0);

    f32x4 acc[4];
    #pragma unroll
    for (int nt = 0; nt < 4; ++nt) acc[nt] = (f32x4){0.f,0.f,0.f,0.f};
    f16x8 hzero;
    #pragma unroll
    for (int e = 0; e < 8; ++e) hzero[e] = (_Float16)0.f;

    #pragma unroll 2
    for (int ii = 0; ii < 16; ++ii) {
        int cur = ii & 1;
        asm volatile("s_waitcnt vmcnt(4) lgkmcnt(0)" ::: "memory");
        __builtin_amdgcn_s_barrier();
        __builtin_amdgcn_sched_barrier(0);
        if (ii < 15) {
            const unsigned short* src = pbase + (size_t)(ii+1)*16384;
            unsigned short* dst = &lds[(cur^1)*10240];
            #pragma unroll
            for (int q = 0; q < 4; ++q)
                GLD_LDS16(src + (size_t)(q*256 + t)*8, dst + (size_t)(q*256 + t)*8);
            const unsigned short* hsrc = h16 + ((size_t)(t&7)*NUM_SLOTS + (g*16+ii+1))*D_MODEL + (t>>3)*8;
            GLD_LDS16(hsrc, dst + 8192 + (size_t)t*8);
        }
        __builtin_amdgcn_sched_barrier(0);
        f16x8 bq[4];
        #pragma unroll
        for (int nt = 0; nt < 4; ++nt) bq[nt] = bqn[nt];
        if (ii < 15) {
            const unsigned short* bp = pbase + (size_t)(ii+1)*16384 + 8192;
            #pragma unroll
            for (int nt = 0; nt < 4; ++nt)
                bqn[nt] = *(const f16x8*)(bp + (size_t)((w*4+nt)*64 + l)*8);
        }
        const unsigned short* buf = &lds[cur*10240];
        f32x4 d1[2];
        d1[0] = (f32x4){0.f,0.f,0.f,0.f};
        d1[1] = (f32x4){0.f,0.f,0.f,0.f};
        #pragma unroll
        for (int ks = 0; ks < 8; ++ks) {
            f16x8 a0 = *(const f16x8*)(buf + (size_t)((ks*2+0)*64 + l)*8);
            f16x8 a1 = *(const f16x8*)(buf + (size_t)((ks*2+1)*64 + l)*8);
            f16x8 hv = *(const f16x8*)(buf + 8192 + (size_t)(((ks*4+lg)*8 + (c&7)))*8);
            f16x8 hb = (c < 8) ? hv : hzero;
            d1[0] = __builtin_amdgcn_mfma_f32_16x16x32_f16(a0, hb, d1[0], 0, 0, 0);
            d1[1] = __builtin_amdgcn_mfma_f32_16x16x32_f16(a1, hb, d1[1], 0, 0, 0);
        }
        unsigned q0 = pk2(d1[0][0], d1[0][1]);
        unsigned q1 = pk2(d1[0][2], d1[0][3]);
        unsigned s0 = pk2(d1[1][0], d1[1][1]);
        unsigned s1 = pk2(d1[1][2], d1[1][3]);
        int srcLo = 32*(lg & 1) + c;
        int srcHi = srcLo + 16;
        unsigned a0s = (unsigned)__shfl((int)q0, srcLo, 64);
        unsigned a1s = (unsigned)__shfl((int)q1, srcLo, 64);
        unsigned a2s = (unsigned)__shfl((int)q0, srcHi, 64);
        unsigned a3s = (unsigned)__shfl((int)q1, srcHi, 64);
        unsigned b0s = (unsigned)__shfl((int)s0, srcLo, 64);
        unsigned b1s = (unsigned)__shfl((int)s1, srcLo, 64);
        unsigned b2s = (unsigned)__shfl((int)s0, srcHi, 64);
        unsigned b3s = (unsigned)__shfl((int)s1, srcHi, 64);
        bool himt = ((lg >> 1) & 1);
        union { unsigned u[4]; f16x8 v; } A2u;
        A2u.u[0] = himt ? b0s : a0s;
        A2u.u[1] = himt ? b1s : a1s;
        A2u.u[2] = himt ? b2s : a2s;
        A2u.u[3] = himt ? b3s : a3s;
        #pragma unroll
        for (int nt = 0; nt < 4; ++nt)
            acc[nt] = __builtin_amdgcn_mfma_f32_16x16x32_f16(A2u.v, bq[nt], acc[nt], 0, 0, 0);
    }
    if (lg < 2) {
        #pragma unroll
        for (int nt = 0; nt < 4; ++nt) {
            int d = (w*4 + nt)*16 + c;
            #pragma unroll
            for (int r = 0; r < 4; ++r) {
                int b = lg*4 + r;
                part[(((size_t)g*BATCH + b)*NUM_SLOTS + j)*D_MODEL + d] = acc[nt][r];
            }
        }
    }
}

// fallback fp32 pairs kernel (used when ws too small for WF)
__global__ __launch_bounds__(256) void k_pairs(const float* __restrict__ h,
        const float* __restrict__ Ws, const float* __restrict__ Wt,
        float* __restrict__ part) {
    int j = blockIdx.x;
    int g = blockIdx.y;
    int t = threadIdx.x;
    __shared__ float sh_h[BATCH][D_MODEL];
    __shared__ float sh_inter[BATCH][RANK];
    float acc[BATCH];
    #pragma unroll
    for (int b = 0; b < BATCH; ++b) acc[b] = 0.f;
    int tb = t >> 5, tr = t & 31;
    for (int ii = 0; ii < IPG; ++ii) {
        int i = g*IPG + ii;
        if (i == j) continue;
        #pragma unroll
        for (int b = 0; b < BATCH; ++b)
            sh_h[b][t] = h[((size_t)b*NUM_SLOTS + i)*D_MODEL + t];
        __syncthreads();
        const float* ws = Ws + ((size_t)i*NUM_SLOTS + j)*(D_MODEL*RANK);
        float accA = 0.f;
        #pragma unroll 8
        for (int d = 0; d < D_MODEL; ++d)
            accA += sh_h[tb][d] * ws[(size_t)d*RANK + tr];
        sh_inter[tb][tr] = accA;
        __syncthreads();
        const float* wt = Wt + ((size_t)i*NUM_SLOTS + j)*(RANK*D_MODEL);
        #pragma unroll 8
        for (int r = 0; r < RANK; ++r) {
            float w = wt[(size_t)r*D_MODEL + t];
            #pragma unroll
            for (int b = 0; b < BATCH; ++b) acc[b] += sh_inter[b][r] * w;
        }
        __syncthreads();
    }
    #pragma unroll
    for (int b = 0; b < BATCH; ++b)
        part[(((size_t)g*BATCH + b)*NUM_SLOTS + j)*D_MODEL + t] = acc[b];
}

// h = LN(h + relu(sum_g part)); writes fp32 and fp16 copies
__global__ __launch_bounds__(256) void k_ln(float* __restrict__ h,
        unsigned short* __restrict__ h16, const float* __restrict__ part,
        const float* __restrict__ gma, const float* __restrict__ bta) {
    int bj = blockIdx.x;
    int t = threadIdx.x;
    int b = bj >> 7, j = bj & 127;
    __shared__ float red[256];
    float v = 0.f;
    #pragma unroll
    for (int g = 0; g < IGROUPS; ++g)
        v += part[(((size_t)g*BATCH + b)*NUM_SLOTS + j)*D_MODEL + t];
    float x = h[(size_t)bj*D_MODEL + t] + fmaxf(v, 0.f);
    red[t] = x; __syncthreads();
    for (int o = 128; o > 0; o >>= 1) { if (t < o) red[t] += red[t+o]; __syncthreads(); }
    float mu = red[0] * (1.0f/D_MODEL); __syncthreads();
    float dx = x - mu;
    red[t] = dx*dx; __syncthreads();
    for (int o = 128; o > 0; o >>= 1) { if (t < o) red[t] += red[t+o]; __syncthreads(); }
    float var = red[0] * (1.0f/D_MODEL);
    float outv = dx * rsqrtf(var + LN_EPS) * gma[t] + bta[t];
    h[(size_t)bj*D_MODEL + t] = outv;
    h16[(size_t)bj*D_MODEL + t] = f2h(outv);
}

// fused expand attention: scores -> softmax -> Y, written as fp16 hi/lo split
__global__ __launch_bounds__(256) void k_attn2y(const float* __restrict__ Q,
        const float* __restrict__ Kf, const float* __restrict__ Vf,
        unsigned short* __restrict__ Yh, unsigned short* __restrict__ Yl) {
    int bl = blockIdx.x; int b = bl / SEQ;
    int t = threadIdx.x;
    __shared__ float q[D_MODEL];
    __shared__ float prt[2][128];
    __shared__ float a[128];
    __shared__ float red[128];
    q[t] = Q[(size_t)bl*D_MODEL + t];
    __syncthreads();
    int s = t & 127, hf = t >> 7;
    const float* kf = Kf + ((size_t)b*NUM_SLOTS + s)*D_MODEL + hf*128;
    float accp = 0.f;
    #pragma unroll 8
    for (int d = 0; d < 128; ++d) accp += q[hf*128 + d]*kf[d];
    prt[hf][s] = accp;
    __syncthreads();
    float v = 0.f;
    if (t < 128) { v = (prt[0][t] + prt[1][t]) * SM_SCALE; red[t] = v; }
    __syncthreads();
    for (int o = 64; o > 0; o >>= 1) { if (t < o) red[t] = fmaxf(red[t], red[t+o]); __syncthreads(); }
    float mx = red[0]; __syncthreads();
    if (t < 128) { float e = expf(v - mx); a[t] = e; red[t] = e; }
    __syncthreads();
    for (int o = 64; o > 0; o >>= 1) { if (t < o) red[t] += red[t+o]; __syncthreads(); }
    float inv = 1.0f / red[0];
    __syncthreads();
    // phase 2: Y[d] = (sum_s e_s * Vf[s,d]) / sum_e
    const float* vf = Vf + (size_t)b*NUM_SLOTS*D_MODEL + t;
    float y0 = 0.f, y1 = 0.f, y2 = 0.f, y3 = 0.f;
    #pragma unroll
    for (int s2 = 0; s2 < NUM_SLOTS; s2 += 4) {
        y0 += a[s2+0]*vf[(size_t)(s2+0)*D_MODEL];
        y1 += a[s2+1]*vf[(size_t)(s2+1)*D_MODEL];
        y2 += a[s2+2]*vf[(size_t)(s2+2)*D_MODEL];
        y3 += a[s2+3]*vf[(size_t)(s2+3)*D_MODEL];
    }
    float y = ((y0+y1) + (y2+y3)) * inv;
    unsigned short yh = f2h(y);
    Yh[(size_t)bl*D_MODEL + t] = yh;
    Yl[(size_t)bl*D_MODEL + t] = f2h(y - h2f(yh));
}

extern "C" void kernel_launch(void* const* d_in, const int* in_sizes, int n_in,
                              void* d_out, int out_size, void* d_ws, size_t ws_size,
                              hipStream_t stream) {
    const int*   ids    = (const int*)d_in[0];
    const int*   amask  = (const int*)d_in[1];
    const float* tok    = (const float*)d_in[2];
    const float* pos    = (const float*)d_in[3];
    const float* Hin    = (const float*)d_in[4];
    const float* Ws     = (const float*)d_in[5];
    const float* Wt     = (const float*)d_in[6];
    const float* Wq_in  = (const float*)d_in[7];
    const float* Wk_sl  = (const float*)d_in[8];
    const float* Wv_in  = (const float*)d_in[9];
    const float* Wq_out = (const float*)d_in[10];
    const float* Wk_fin = (const float*)d_in[11];
    const float* Wv_fin = (const float*)d_in[12];
    const float* Wop    = (const float*)d_in[13];
    const float* lnsc   = (const float*)d_in[14];
    const float* lnbs   = (const float*)d_in[15];
    float* out = (float*)d_out;

    const size_t WF_USH = (size_t)16384 * 16384;     // 512 MiB of ushorts
    const size_t F32_FLOATS = 18600000ULL;           // fp32+fp16 scratch region
    const bool useF16 = ws_size >= WF_USH*2 + F32_FLOATS*4 + 256;

    unsigned short* WF = (unsigned short*)d_ws;
    float* ws = useF16 ? (float*)(WF + WF_USH) : (float*)d_ws;

    float* X    = ws;
    float* Qin  = X    + (size_t)NTOK*D_MODEL;
    float* Vin  = Qin  + (size_t)NTOK*D_MODEL;
    float* Ksl  = Vin  + (size_t)NTOK*D_MODEL;
    float* Asc  = Ksl  + (size_t)NUM_SLOTS*D_MODEL;
    float* csp  = Asc  + (size_t)NTOK*NUM_SLOTS;          // 8*8*128 partials
    float* Hst  = csp  + (size_t)BATCH*8*NUM_SLOTS;
    float* part = Hst  + (size_t)BATCH*NUM_SLOTS*D_MODEL;
    float* Qout = part + (size_t)IGROUPS*BATCH*NUM_SLOTS*D_MODEL;
    float* Kf   = Qout + (size_t)NTOK*D_MODEL;
    float* Vf   = Kf   + (size_t)BATCH*NUM_SLOTS*D_MODEL;
    float* A2   = Vf   + (size_t)BATCH*NUM_SLOTS*D_MODEL; // unused (kept for layout)
    float* Yb   = A2   + (size_t)NTOK*NUM_SLOTS;          // unused (kept for layout)
    unsigned short* Yh = (unsigned short*)(Yb + (size_t)NTOK*D_MODEL);
    unsigned short* Yl = Yh + (size_t)NTOK*D_MODEL;
    unsigned short* Wf16 = Yl + (size_t)NTOK*D_MODEL;
    unsigned short* Hst16 = Wf16 + (size_t)VOCAB*D_MODEL;

    // one-time weight conversions (independent of the rest)
    if (useF16)
        k_convert<<<dim3(128, 128, 4), 256, 0, stream>>>(Ws, Wt, WF);
    k_split16<<<(VOCAB*D_MODEL/4 + 255)/256, 256, 0, stream>>>(Wop, Wf16, VOCAB*D_MODEL/4);

    // embeddings
    k_embed<<<NTOK, 256, 0, stream>>>(ids, tok, pos, X);
    // X projections (Qin, Vin, Qout) fused into one dispatch
    k_gemm3<<<dim3(NTOK/64, 4, 3), 256, 0, stream>>>(X, Wq_in, Wv_in, Wq_out, Qin, Vin, Qout);
    k_gemm_nt<<<dim3(2, 4), 256, 0, stream>>>(Hin, Wk_sl, Ksl, NUM_SLOTS, D_MODEL, D_MODEL);
    // scores + softmax + mask
    k_gemm_nt<<<dim3(NTOK/64, 2), 256, 0, stream>>>(Qin, Ksl, Asc, NTOK, NUM_SLOTS, D_MODEL);
    k_softmax_mask<<<NTOK, 128, 0, stream>>>(Asc, amask);
    // column-normalize + aggregate into slots
    k_colsum<<<dim3(BATCH, 8), 128, 0, stream>>>(Asc, csp);
    k_ir<<<BATCH*NUM_SLOTS, 256, 0, stream>>>(Asc, Vin, Hin, csp, Hst, Hst16);
    // bilinear slot-interaction steps
    for (int st = 0; st < N_STEPS; ++st) {
        if (useF16)
            k_pairs_mfma<<<dim3(NUM_SLOTS, IGROUPS), 256, 0, stream>>>(Hst16, WF, part);
        else
            k_pairs<<<dim3(NUM_SLOTS, IGROUPS), 256, 0, stream>>>(Hst, Ws, Wt, part);
        k_ln<<<BATCH*NUM_SLOTS, 256, 0, stream>>>(Hst, Hst16, part, lnsc + st*D_MODEL, lnbs + st*D_MODEL);
    }
    // expand projections (Kf, Vf fused)
    k_kfvf<<<dim3(BATCH*NUM_SLOTS/64, 4, 2), 256, 0, stream>>>(Hst, Wk_fin, Wv_fin, Kf, Vf);
    // fused expand attention + Y + fp16 split
    k_attn2y<<<NTOK, 256, 0, stream>>>(Qout, Kf, Vf, Yh, Yl);
    // logits: 2-pass fp16-split MFMA with global_load_lds staging
    k_logits<<<dim3(NTOK/128, VOCAB/128), 256, 0, stream>>>(Yh, Yl, Wf16, out);
}

// Round 11
// 1470.204 us; speedup vs baseline: 1.3807x; 1.0007x over previous
//
#include <hip/hip_runtime.h>
#include <hip/hip_bf16.h>
#include <math.h>

#define D_MODEL 256
#define NUM_SLOTS 128
#define RANK 32
#define N_STEPS 6
#define VOCAB 32000
#define SEQ 512
#define BATCH 8
#define NTOK (BATCH*SEQ)
#define LN_EPS 1e-5f
#define SM_SCALE 0.0625f
#define IGROUPS 8
#define IPG (NUM_SLOTS/IGROUPS)

typedef __attribute__((ext_vector_type(8))) short bf16x8;
typedef __attribute__((ext_vector_type(8))) _Float16 f16x8;
typedef __attribute__((ext_vector_type(4))) float f32x4;

#define GLD_LDS16(g, l) __builtin_amdgcn_global_load_lds( \
    (const __attribute__((address_space(1))) unsigned int*)(g), \
    (__attribute__((address_space(3))) unsigned int*)(l), 16, 0, 0)

__device__ inline unsigned short f2bf(float x) {
    unsigned u = __float_as_uint(x);
    unsigned r = u + 0x7fff + ((u >> 16) & 1);
    return (unsigned short)(r >> 16);
}
__device__ inline float bf2f(unsigned short h) {
    return __uint_as_float(((unsigned)h) << 16);
}
__device__ inline unsigned pk2(float a, float b) {
    auto v = __builtin_amdgcn_cvt_pkrtz(a, b);
    union { decltype(v) x; unsigned u; } c;
    c.x = v;
    return c.u;
}
__device__ inline unsigned short f2h(float x) {
    union { _Float16 h; unsigned short u; } c;
    c.h = (_Float16)x;
    return c.u;
}
__device__ inline float h2f(unsigned short u) {
    union { unsigned short u; _Float16 h; } c;
    c.u = u;
    return (float)c.h;
}

// X[b,l,:] = token_emb[ids[b,l],:] + pos_emb[l,:]
__global__ __launch_bounds__(256) void k_embed(const int* __restrict__ ids,
        const float* __restrict__ tok, const float* __restrict__ pos,
        float* __restrict__ X) {
    int bl = blockIdx.x;
    int d  = threadIdx.x;
    int l  = bl % SEQ;
    int id = ids[bl];
    X[(size_t)bl*D_MODEL + d] = tok[(size_t)id*D_MODEL + d] + pos[l*D_MODEL + d];
}

// C[m,n] = sum_k A[m,k]*B[n,k]   (both row-major, K contiguous)  64x64 tile
__global__ __launch_bounds__(256) void k_gemm_nt(const float* __restrict__ A,
        const float* __restrict__ B, float* __restrict__ C, int M, int N, int K) {
    __shared__ float As[32][64];
    __shared__ float Bs[32][64];
    int bm = blockIdx.x * 64, bn = blockIdx.y * 64;
    int t = threadIdx.x;
    int tm = (t & 15) * 4, tn = (t >> 4) * 4;
    float acc[4][4] = {};
    for (int k0 = 0; k0 < K; k0 += 32) {
        #pragma unroll
        for (int r = 0; r < 8; ++r) {
            int idx = r*256 + t;
            int m = idx >> 5, k = idx & 31;
            As[k][m] = A[(size_t)(bm+m)*K + k0 + k];
        }
        #pragma unroll
        for (int r = 0; r < 8; ++r) {
            int idx = r*256 + t;
            int n = idx >> 5, k = idx & 31;
            Bs[k][n] = B[(size_t)(bn+n)*K + k0 + k];
        }
        __syncthreads();
        #pragma unroll
        for (int k = 0; k < 32; ++k) {
            float4 a4 = *(const float4*)&As[k][tm];
            float4 b4 = *(const float4*)&Bs[k][tn];
            float a[4] = {a4.x,a4.y,a4.z,a4.w};
            float b[4] = {b4.x,b4.y,b4.z,b4.w};
            #pragma unroll
            for (int i = 0; i < 4; ++i)
                #pragma unroll
                for (int jj = 0; jj < 4; ++jj)
                    acc[i][jj] += a[i]*b[jj];
        }
        __syncthreads();
    }
    #pragma unroll
    for (int i = 0; i < 4; ++i) {
        float4 v = make_float4(acc[i][0],acc[i][1],acc[i][2],acc[i][3]);
        *(float4*)&C[(size_t)(bm+tm+i)*N + bn+tn] = v;
    }
}

// 3 projections (Qin, Vin, Qout) from the same A=X, selected by blockIdx.z
__global__ __launch_bounds__(256) void k_gemm3(const float* __restrict__ A,
        const float* __restrict__ B0, const float* __restrict__ B1,
        const float* __restrict__ B2, float* __restrict__ C0,
        float* __restrict__ C1, float* __restrict__ C2) {
    const int K = D_MODEL, N = D_MODEL;
    const float* B = blockIdx.z == 0 ? B0 : (blockIdx.z == 1 ? B1 : B2);
    float* C = blockIdx.z == 0 ? C0 : (blockIdx.z == 1 ? C1 : C2);
    __shared__ float As[32][64];
    __shared__ float Bs[32][64];
    int bm = blockIdx.x * 64, bn = blockIdx.y * 64;
    int t = threadIdx.x;
    int tm = (t & 15) * 4, tn = (t >> 4) * 4;
    float acc[4][4] = {};
    for (int k0 = 0; k0 < K; k0 += 32) {
        #pragma unroll
        for (int r = 0; r < 8; ++r) {
            int idx = r*256 + t;
            int m = idx >> 5, k = idx & 31;
            As[k][m] = A[(size_t)(bm+m)*K + k0 + k];
        }
        #pragma unroll
        for (int r = 0; r < 8; ++r) {
            int idx = r*256 + t;
            int n = idx >> 5, k = idx & 31;
            Bs[k][n] = B[(size_t)(bn+n)*K + k0 + k];
        }
        __syncthreads();
        #pragma unroll
        for (int k = 0; k < 32; ++k) {
            float4 a4 = *(const float4*)&As[k][tm];
            float4 b4 = *(const float4*)&Bs[k][tn];
            float a[4] = {a4.x,a4.y,a4.z,a4.w};
            float b[4] = {b4.x,b4.y,b4.z,b4.w};
            #pragma unroll
            for (int i = 0; i < 4; ++i)
                #pragma unroll
                for (int jj = 0; jj < 4; ++jj)
                    acc[i][jj] += a[i]*b[jj];
        }
        __syncthreads();
    }
    #pragma unroll
    for (int i = 0; i < 4; ++i) {
        float4 v = make_float4(acc[i][0],acc[i][1],acc[i][2],acc[i][3]);
        *(float4*)&C[(size_t)(bm+tm+i)*N + bn+tn] = v;
    }
}

// Kf/Vf projections from Hst, selected by blockIdx.z
__global__ __launch_bounds__(256) void k_kfvf(const float* __restrict__ A,
        const float* __restrict__ B0, const float* __restrict__ B1,
        float* __restrict__ C0, float* __restrict__ C1) {
    const int K = D_MODEL, N = D_MODEL;
    const float* B = blockIdx.z == 0 ? B0 : B1;
    float* C = blockIdx.z == 0 ? C0 : C1;
    __shared__ float As[32][64];
    __shared__ float Bs[32][64];
    int bm = blockIdx.x * 64, bn = blockIdx.y * 64;
    int t = threadIdx.x;
    int tm = (t & 15) * 4, tn = (t >> 4) * 4;
    float acc[4][4] = {};
    for (int k0 = 0; k0 < K; k0 += 32) {
        #pragma unroll
        for (int r = 0; r < 8; ++r) {
            int idx = r*256 + t;
            int m = idx >> 5, k = idx & 31;
            As[k][m] = A[(size_t)(bm+m)*K + k0 + k];
        }
        #pragma unroll
        for (int r = 0; r < 8; ++r) {
            int idx = r*256 + t;
            int n = idx >> 5, k = idx & 31;
            Bs[k][n] = B[(size_t)(bn+n)*K + k0 + k];
        }
        __syncthreads();
        #pragma unroll
        for (int k = 0; k < 32; ++k) {
            float4 a4 = *(const float4*)&As[k][tm];
            float4 b4 = *(const float4*)&Bs[k][tn];
            float a[4] = {a4.x,a4.y,a4.z,a4.w};
            float b[4] = {b4.x,b4.y,b4.z,b4.w};
            #pragma unroll
            for (int i = 0; i < 4; ++i)
                #pragma unroll
                for (int jj = 0; jj < 4; ++jj)
                    acc[i][jj] += a[i]*b[jj];
        }
        __syncthreads();
    }
    #pragma unroll
    for (int i = 0; i < 4; ++i) {
        float4 v = make_float4(acc[i][0],acc[i][1],acc[i][2],acc[i][3]);
        *(float4*)&C[(size_t)(bm+tm+i)*N + bn+tn] = v;
    }
}

// fp32 -> fp16 (for W_out_proj)
__global__ __launch_bounds__(256) void k_split16(const float* __restrict__ in,
        unsigned short* __restrict__ o, int n4) {
    int i = blockIdx.x*256 + threadIdx.x;
    if (i >= n4) return;
    float4 v = ((const float4*)in)[i];
    ushort4 h;
    h.x = f2h(v.x); h.y = f2h(v.y); h.z = f2h(v.z); h.w = f2h(v.w);
    ((ushort4*)o)[i] = h;
}

// logits GEMM: 2-pass fp16-split MFMA, m97-style global_load_lds staging.
__global__ __launch_bounds__(256) void k_logits(
        const unsigned short* __restrict__ Ahg, const unsigned short* __restrict__ Alg,
        const unsigned short* __restrict__ Bhg, float* __restrict__ C) {
    __shared__ unsigned short lds[3*8192];   // Ah | Al | Bh, each [128][64] linear
    int bm = blockIdx.x * 128, bn = blockIdx.y * 128;
    int t = threadIdx.x;
    int w = t >> 6, l = t & 63;
    int wr = w >> 1, wc = w & 1;
    int lr = l & 15, lk = l >> 4;
    f32x4 acc[4][4];
    #pragma unroll
    for (int mi = 0; mi < 4; ++mi)
        #pragma unroll
        for (int ni = 0; ni < 4; ++ni)
            acc[mi][ni] = (f32x4){0.f,0.f,0.f,0.f};

    for (int kc = 0; kc < 4; ++kc) {
        if (kc) __syncthreads();
        #pragma unroll
        for (int i = 0; i < 4; ++i) {
            int c = t + i*256;
            int row = c >> 3, c8 = c & 7;
            size_t ga = (size_t)(bm+row)*256 + kc*64 + c8*8;
            size_t gb = (size_t)(bn+row)*256 + kc*64 + c8*8;
            GLD_LDS16(Ahg + ga, &lds[c*8]);
            GLD_LDS16(Alg + ga, &lds[8192 + c*8]);
            GLD_LDS16(Bhg + gb, &lds[16384 + c*8]);
        }
        __syncthreads();
        #pragma unroll
        for (int s = 0; s < 2; ++s) {
            f16x8 ah[4], al[4], bh[4];
            #pragma unroll
            for (int mi = 0; mi < 4; ++mi) {
                int off = (wr*64 + mi*16 + lr)*64 + s*32 + lk*8;
                ah[mi] = *(const f16x8*)&lds[off];
                al[mi] = *(const f16x8*)&lds[8192 + off];
            }
            #pragma unroll
            for (int ni = 0; ni < 4; ++ni) {
                int off = (wc*64 + ni*16 + lr)*64 + s*32 + lk*8;
                bh[ni] = *(const f16x8*)&lds[16384 + off];
            }
            #pragma unroll
            for (int mi = 0; mi < 4; ++mi)
                #pragma unroll
                for (int ni = 0; ni < 4; ++ni) {
                    acc[mi][ni] = __builtin_amdgcn_mfma_f32_16x16x32_f16(ah[mi], bh[ni], acc[mi][ni], 0, 0, 0);
                    acc[mi][ni] = __builtin_amdgcn_mfma_f32_16x16x32_f16(al[mi], bh[ni], acc[mi][ni], 0, 0, 0);
                }
        }
    }
    #pragma unroll
    for (int mi = 0; mi < 4; ++mi)
        #pragma unroll
        for (int ni = 0; ni < 4; ++ni) {
            int col = bn + wc*64 + ni*16 + lr;
            #pragma unroll
            for (int r = 0; r < 4; ++r) {
                int row = bm + wr*64 + mi*16 + lk*4 + r;
                C[(size_t)row*VOCAB + col] = acc[mi][ni][r];
            }
        }
}

__global__ __launch_bounds__(128) void k_softmax_mask(float* __restrict__ A,
        const int* __restrict__ mask) {
    int row = blockIdx.x;
    int s = threadIdx.x;
    __shared__ float red[128];
    float v = A[(size_t)row*NUM_SLOTS + s] * SM_SCALE;
    red[s] = v; __syncthreads();
    for (int o = 64; o > 0; o >>= 1) { if (s < o) red[s] = fmaxf(red[s], red[s+o]); __syncthreads(); }
    float mx = red[0]; __syncthreads();
    float e = expf(v - mx);
    red[s] = e; __syncthreads();
    for (int o = 64; o > 0; o >>= 1) { if (s < o) red[s] += red[s+o]; __syncthreads(); }
    float sum = red[0];
    float m = (float)mask[row];
    A[(size_t)row*NUM_SLOTS + s] = e / sum * m;
}

// partial column sums: block (b, chunk) sums 64 l's
__global__ __launch_bounds__(128) void k_colsum(const float* __restrict__ A,
        float* __restrict__ csp) {
    int b = blockIdx.x; int ch = blockIdx.y; int s = threadIdx.x;
    const float* Ab = A + ((size_t)b*SEQ + ch*64)*NUM_SLOTS + s;
    float a0 = 0.f, a1 = 0.f, a2 = 0.f, a3 = 0.f;
    #pragma unroll
    for (int l = 0; l < 64; l += 4) {
        a0 += Ab[(size_t)(l+0)*NUM_SLOTS];
        a1 += Ab[(size_t)(l+1)*NUM_SLOTS];
        a2 += Ab[(size_t)(l+2)*NUM_SLOTS];
        a3 += Ab[(size_t)(l+3)*NUM_SLOTS];
    }
    csp[(b*8 + ch)*NUM_SLOTS + s] = (a0+a1) + (a2+a3);
}

// H_state = H + IR; writes fp32 and fp16 copies; sums 8 colsum partials
__global__ __launch_bounds__(256) void k_ir(const float* __restrict__ A,
        const float* __restrict__ V, const float* __restrict__ H,
        const float* __restrict__ csp, float* __restrict__ Hs,
        unsigned short* __restrict__ Hs16) {
    int bs = blockIdx.x; int b = bs >> 7; int s = bs & 127;
    int d = threadIdx.x;
    float sum = 1e-8f;
    #pragma unroll
    for (int p = 0; p < 8; ++p) sum += csp[(b*8 + p)*NUM_SLOTS + s];
    float inv = 1.0f / sum;
    const float* Ab = A + (size_t)b*SEQ*NUM_SLOTS + s;
    const float* Vb = V + (size_t)b*SEQ*D_MODEL + d;
    float a0 = 0.f, a1 = 0.f, a2 = 0.f, a3 = 0.f;
    for (int l = 0; l < SEQ; l += 4) {
        a0 += Ab[(size_t)(l+0)*NUM_SLOTS] * Vb[(size_t)(l+0)*D_MODEL];
        a1 += Ab[(size_t)(l+1)*NUM_SLOTS] * Vb[(size_t)(l+1)*D_MODEL];
        a2 += Ab[(size_t)(l+2)*NUM_SLOTS] * Vb[(size_t)(l+2)*D_MODEL];
        a3 += Ab[(size_t)(l+3)*NUM_SLOTS] * Vb[(size_t)(l+3)*D_MODEL];
    }
    float acc = (a0+a1) + (a2+a3);
    float v = H[s*D_MODEL + d] + acc * inv;
    Hs[(size_t)bs*D_MODEL + d] = v;
    Hs16[(size_t)bs*D_MODEL + d] = f2h(v);
}

// ---- one-time fp32->fp16 weight conversion, BARRIER-FREE per-wave ----
// Each wave owns a 32x32 sub-tile end-to-end: load 4KB -> private padded LDS
// [32][33] -> wave-local lgkmcnt(0) (no __syncthreads) -> convert + store
// fragment chunks. z: 0,1 = Ws d-halves (wave -> ks=z*4+w); 2,3 = Wt nt-pairs
// (wave -> p0=(z-2)*8+w*2). Bit-identical output to the previous k_convert.
__global__ __launch_bounds__(256) void k_convert(const float* __restrict__ Ws,
        const float* __restrict__ Wt, unsigned short* __restrict__ WF) {
    int i = blockIdx.x, j = blockIdx.y, z = blockIdx.z;
    int t = threadIdx.x, w = t >> 6, l = t & 63;
    __shared__ float lds[4*1056];            // 4 waves x [32][33] f32
    float* lw = &lds[w*1056];
    size_t sBase = ((size_t)i*128 + j)*8192;
    size_t pOut = ((size_t)j*128 + i)*16384;
    int g = l >> 4, c = l & 15;
    if (z < 2) {
        int ks = z*4 + w;                    // d-group [ks*32, ks*32+32)
        const float4* s4 = (const float4*)(Ws + sBase) + ks*256;
        #pragma unroll
        for (int q = 0; q < 4; ++q) {
            int idx = q*64 + l;
            float4 v = s4[idx];
            *(float4*)&lw[(idx>>3)*33 + 4*(idx&7)] = v;   // [d_local][r]
        }
        asm volatile("s_waitcnt lgkmcnt(0)" ::: "memory");
        bool diag = (i == j);
        #pragma unroll
        for (int mt = 0; mt < 2; ++mt) {
            union { f16x8 v; } o;
            #pragma unroll
            for (int e = 0; e < 8; ++e) {
                float f = diag ? 0.f : lw[(g*8 + e)*33 + mt*16 + c];
                o.v[e] = (_Float16)f;
            }
            *(f16x8*)(WF + pOut + (size_t)((ks*2 + mt)*64 + l)*8) = o.v;
        }
    } else {
        int p0 = (z - 2)*8 + w*2;            // nt in {p0,p0+1}, d in [p0*16,+32)
        const float4* s4 = (const float4*)(Wt + sBase);
        #pragma unroll
        for (int q = 0; q < 4; ++q) {
            int idx = q*64 + l;
            int r = idx >> 3, c8 = idx & 7;
            float4 v = s4[r*64 + p0*4 + c8];
            *(float4*)&lw[r*33 + 4*c8] = v;               // [r][d_local]
        }
        asm volatile("s_waitcnt lgkmcnt(0)" ::: "memory");
        #pragma unroll
        for (int dn = 0; dn < 2; ++dn) {
            int nt = p0 + dn;
            union { f16x8 v; } o;
            #pragma unroll
            for (int e = 0; e < 8; ++e)
                o.v[e] = (_Float16)lw[(g*8 + e)*33 + dn*16 + c];
            *(f16x8*)(WF + pOut + 8192 + (size_t)(nt*64 + l)*8) = o.v;
        }
    }
}

// ---- MFMA slot-pair kernel (frozen structure) ----
__global__ __launch_bounds__(256, 4) void k_pairs_mfma(const unsigned short* __restrict__ h16,
        const unsigned short* __restrict__ WF, float* __restrict__ part) {
    __shared__ unsigned short lds[2*10240];
    int j = blockIdx.x, g = blockIdx.y;
    int t = threadIdx.x, w = t >> 6, l = t & 63;
    int lg = l >> 4, c = l & 15;
    const unsigned short* pbase = WF + ((size_t)j*128 + g*16)*16384;

    {
        const unsigned short* src = pbase;
        #pragma unroll
        for (int q = 0; q < 4; ++q)
            GLD_LDS16(src + (size_t)(q*256 + t)*8, &lds[(q*256 + t)*8]);
        const unsigned short* hsrc = h16 + ((size_t)(t&7)*NUM_SLOTS + g*16)*D_MODEL + (t>>3)*8;
        GLD_LDS16(hsrc, &lds[8192 + t*8]);
    }
    __builtin_amdgcn_sched_barrier(0);
    f16x8 bqn[4];
    #pragma unroll
    for (int nt = 0; nt < 4; ++nt)
        bqn[nt] = *(const f16x8*)(pbase + 8192 + (size_t)((w*4+nt)*64 + l)*8);
    __builtin_amdgcn_sched_barrier(0);

    f32x4 acc[4];
    #pragma unroll
    for (int nt = 0; nt < 4; ++nt) acc[nt] = (f32x4){0.f,0.f,0.f,0.f};
    f16x8 hzero;
    #pragma unroll
    for (int e = 0; e < 8; ++e) hzero[e] = (_Float16)0.f;

    #pragma unroll 2
    for (int ii = 0; ii < 16; ++ii) {
        int cur = ii & 1;
        asm volatile("s_waitcnt vmcnt(4) lgkmcnt(0)" ::: "memory");
        __builtin_amdgcn_s_barrier();
        __builtin_amdgcn_sched_barrier(0);
        if (ii < 15) {
            const unsigned short* src = pbase + (size_t)(ii+1)*16384;
            unsigned short* dst = &lds[(cur^1)*10240];
            #pragma unroll
            for (int q = 0; q < 4; ++q)
                GLD_LDS16(src + (size_t)(q*256 + t)*8, dst + (size_t)(q*256 + t)*8);
            const unsigned short* hsrc = h16 + ((size_t)(t&7)*NUM_SLOTS + (g*16+ii+1))*D_MODEL + (t>>3)*8;
            GLD_LDS16(hsrc, dst + 8192 + (size_t)t*8);
        }
        __builtin_amdgcn_sched_barrier(0);
        f16x8 bq[4];
        #pragma unroll
        for (int nt = 0; nt < 4; ++nt) bq[nt] = bqn[nt];
        if (ii < 15) {
            const unsigned short* bp = pbase + (size_t)(ii+1)*16384 + 8192;
            #pragma unroll
            for (int nt = 0; nt < 4; ++nt)
                bqn[nt] = *(const f16x8*)(bp + (size_t)((w*4+nt)*64 + l)*8);
        }
        const unsigned short* buf = &lds[cur*10240];
        f32x4 d1[2];
        d1[0] = (f32x4){0.f,0.f,0.f,0.f};
        d1[1] = (f32x4){0.f,0.f,0.f,0.f};
        #pragma unroll
        for (int ks = 0; ks < 8; ++ks) {
            f16x8 a0 = *(const f16x8*)(buf + (size_t)((ks*2+0)*64 + l)*8);
            f16x8 a1 = *(const f16x8*)(buf + (size_t)((ks*2+1)*64 + l)*8);
            f16x8 hv = *(const f16x8*)(buf + 8192 + (size_t)(((ks*4+lg)*8 + (c&7)))*8);
            f16x8 hb = (c < 8) ? hv : hzero;
            d1[0] = __builtin_amdgcn_mfma_f32_16x16x32_f16(a0, hb, d1[0], 0, 0, 0);
            d1[1] = __builtin_amdgcn_mfma_f32_16x16x32_f16(a1, hb, d1[1], 0, 0, 0);
        }
        unsigned q0 = pk2(d1[0][0], d1[0][1]);
        unsigned q1 = pk2(d1[0][2], d1[0][3]);
        unsigned s0 = pk2(d1[1][0], d1[1][1]);
        unsigned s1 = pk2(d1[1][2], d1[1][3]);
        int srcLo = 32*(lg & 1) + c;
        int srcHi = srcLo + 16;
        unsigned a0s = (unsigned)__shfl((int)q0, srcLo, 64);
        unsigned a1s = (unsigned)__shfl((int)q1, srcLo, 64);
        unsigned a2s = (unsigned)__shfl((int)q0, srcHi, 64);
        unsigned a3s = (unsigned)__shfl((int)q1, srcHi, 64);
        unsigned b0s = (unsigned)__shfl((int)s0, srcLo, 64);
        unsigned b1s = (unsigned)__shfl((int)s1, srcLo, 64);
        unsigned b2s = (unsigned)__shfl((int)s0, srcHi, 64);
        unsigned b3s = (unsigned)__shfl((int)s1, srcHi, 64);
        bool himt = ((lg >> 1) & 1);
        union { unsigned u[4]; f16x8 v; } A2u;
        A2u.u[0] = himt ? b0s : a0s;
        A2u.u[1] = himt ? b1s : a1s;
        A2u.u[2] = himt ? b2s : a2s;
        A2u.u[3] = himt ? b3s : a3s;
        #pragma unroll
        for (int nt = 0; nt < 4; ++nt)
            acc[nt] = __builtin_amdgcn_mfma_f32_16x16x32_f16(A2u.v, bq[nt], acc[nt], 0, 0, 0);
    }
    if (lg < 2) {
        #pragma unroll
        for (int nt = 0; nt < 4; ++nt) {
            int d = (w*4 + nt)*16 + c;
            #pragma unroll
            for (int r = 0; r < 4; ++r) {
                int b = lg*4 + r;
                part[(((size_t)g*BATCH + b)*NUM_SLOTS + j)*D_MODEL + d] = acc[nt][r];
            }
        }
    }
}

// fallback fp32 pairs kernel (used when ws too small for WF)
__global__ __launch_bounds__(256) void k_pairs(const float* __restrict__ h,
        const float* __restrict__ Ws, const float* __restrict__ Wt,
        float* __restrict__ part) {
    int j = blockIdx.x;
    int g = blockIdx.y;
    int t = threadIdx.x;
    __shared__ float sh_h[BATCH][D_MODEL];
    __shared__ float sh_inter[BATCH][RANK];
    float acc[BATCH];
    #pragma unroll
    for (int b = 0; b < BATCH; ++b) acc[b] = 0.f;
    int tb = t >> 5, tr = t & 31;
    for (int ii = 0; ii < IPG; ++ii) {
        int i = g*IPG + ii;
        if (i == j) continue;
        #pragma unroll
        for (int b = 0; b < BATCH; ++b)
            sh_h[b][t] = h[((size_t)b*NUM_SLOTS + i)*D_MODEL + t];
        __syncthreads();
        const float* ws = Ws + ((size_t)i*NUM_SLOTS + j)*(D_MODEL*RANK);
        float accA = 0.f;
        #pragma unroll 8
        for (int d = 0; d < D_MODEL; ++d)
            accA += sh_h[tb][d] * ws[(size_t)d*RANK + tr];
        sh_inter[tb][tr] = accA;
        __syncthreads();
        const float* wt = Wt + ((size_t)i*NUM_SLOTS + j)*(RANK*D_MODEL);
        #pragma unroll 8
        for (int r = 0; r < RANK; ++r) {
            float w = wt[(size_t)r*D_MODEL + t];
            #pragma unroll
            for (int b = 0; b < BATCH; ++b) acc[b] += sh_inter[b][r] * w;
        }
        __syncthreads();
    }
    #pragma unroll
    for (int b = 0; b < BATCH; ++b)
        part[(((size_t)g*BATCH + b)*NUM_SLOTS + j)*D_MODEL + t] = acc[b];
}

// h = LN(h + relu(sum_g part)); writes fp32 and fp16 copies
__global__ __launch_bounds__(256) void k_ln(float* __restrict__ h,
        unsigned short* __restrict__ h16, const float* __restrict__ part,
        const float* __restrict__ gma, const float* __restrict__ bta) {
    int bj = blockIdx.x;
    int t = threadIdx.x;
    int b = bj >> 7, j = bj & 127;
    __shared__ float red[256];
    float v = 0.f;
    #pragma unroll
    for (int g = 0; g < IGROUPS; ++g)
        v += part[(((size_t)g*BATCH + b)*NUM_SLOTS + j)*D_MODEL + t];
    float x = h[(size_t)bj*D_MODEL + t] + fmaxf(v, 0.f);
    red[t] = x; __syncthreads();
    for (int o = 128; o > 0; o >>= 1) { if (t < o) red[t] += red[t+o]; __syncthreads(); }
    float mu = red[0] * (1.0f/D_MODEL); __syncthreads();
    float dx = x - mu;
    red[t] = dx*dx; __syncthreads();
    for (int o = 128; o > 0; o >>= 1) { if (t < o) red[t] += red[t+o]; __syncthreads(); }
    float var = red[0] * (1.0f/D_MODEL);
    float outv = dx * rsqrtf(var + LN_EPS) * gma[t] + bta[t];
    h[(size_t)bj*D_MODEL + t] = outv;
    h16[(size_t)bj*D_MODEL + t] = f2h(outv);
}

// fused expand attention: scores -> softmax -> Y, written as fp16 hi/lo split
__global__ __launch_bounds__(256) void k_attn2y(const float* __restrict__ Q,
        const float* __restrict__ Kf, const float* __restrict__ Vf,
        unsigned short* __restrict__ Yh, unsigned short* __restrict__ Yl) {
    int bl = blockIdx.x; int b = bl / SEQ;
    int t = threadIdx.x;
    __shared__ float q[D_MODEL];
    __shared__ float prt[2][128];
    __shared__ float a[128];
    __shared__ float red[128];
    q[t] = Q[(size_t)bl*D_MODEL + t];
    __syncthreads();
    int s = t & 127, hf = t >> 7;
    const float* kf = Kf + ((size_t)b*NUM_SLOTS + s)*D_MODEL + hf*128;
    float accp = 0.f;
    #pragma unroll 8
    for (int d = 0; d < 128; ++d) accp += q[hf*128 + d]*kf[d];
    prt[hf][s] = accp;
    __syncthreads();
    float v = 0.f;
    if (t < 128) { v = (prt[0][t] + prt[1][t]) * SM_SCALE; red[t] = v; }
    __syncthreads();
    for (int o = 64; o > 0; o >>= 1) { if (t < o) red[t] = fmaxf(red[t], red[t+o]); __syncthreads(); }
    float mx = red[0]; __syncthreads();
    if (t < 128) { float e = expf(v - mx); a[t] = e; red[t] = e; }
    __syncthreads();
    for (int o = 64; o > 0; o >>= 1) { if (t < o) red[t] += red[t+o]; __syncthreads(); }
    float inv = 1.0f / red[0];
    __syncthreads();
    const float* vf = Vf + (size_t)b*NUM_SLOTS*D_MODEL + t;
    float y0 = 0.f, y1 = 0.f, y2 = 0.f, y3 = 0.f;
    #pragma unroll
    for (int s2 = 0; s2 < NUM_SLOTS; s2 += 4) {
        y0 += a[s2+0]*vf[(size_t)(s2+0)*D_MODEL];
        y1 += a[s2+1]*vf[(size_t)(s2+1)*D_MODEL];
        y2 += a[s2+2]*vf[(size_t)(s2+2)*D_MODEL];
        y3 += a[s2+3]*vf[(size_t)(s2+3)*D_MODEL];
    }
    float y = ((y0+y1) + (y2+y3)) * inv;
    unsigned short yh = f2h(y);
    Yh[(size_t)bl*D_MODEL + t] = yh;
    Yl[(size_t)bl*D_MODEL + t] = f2h(y - h2f(yh));
}

extern "C" void kernel_launch(void* const* d_in, const int* in_sizes, int n_in,
                              void* d_out, int out_size, void* d_ws, size_t ws_size,
                              hipStream_t stream) {
    const int*   ids    = (const int*)d_in[0];
    const int*   amask  = (const int*)d_in[1];
    const float* tok    = (const float*)d_in[2];
    const float* pos    = (const float*)d_in[3];
    const float* Hin    = (const float*)d_in[4];
    const float* Ws     = (const float*)d_in[5];
    const float* Wt     = (const float*)d_in[6];
    const float* Wq_in  = (const float*)d_in[7];
    const float* Wk_sl  = (const float*)d_in[8];
    const float* Wv_in  = (const float*)d_in[9];
    const float* Wq_out = (const float*)d_in[10];
    const float* Wk_fin = (const float*)d_in[11];
    const float* Wv_fin = (const float*)d_in[12];
    const float* Wop    = (const float*)d_in[13];
    const float* lnsc   = (const float*)d_in[14];
    const float* lnbs   = (const float*)d_in[15];
    float* out = (float*)d_out;

    const size_t WF_USH = (size_t)16384 * 16384;     // 512 MiB of ushorts
    const size_t F32_FLOATS = 18600000ULL;           // fp32+fp16 scratch region
    const bool useF16 = ws_size >= WF_USH*2 + F32_FLOATS*4 + 256;

    unsigned short* WF = (unsigned short*)d_ws;
    float* ws = useF16 ? (float*)(WF + WF_USH) : (float*)d_ws;

    float* X    = ws;
    float* Qin  = X    + (size_t)NTOK*D_MODEL;
    float* Vin  = Qin  + (size_t)NTOK*D_MODEL;
    float* Ksl  = Vin  + (size_t)NTOK*D_MODEL;
    float* Asc  = Ksl  + (size_t)NUM_SLOTS*D_MODEL;
    float* csp  = Asc  + (size_t)NTOK*NUM_SLOTS;
    float* Hst  = csp  + (size_t)BATCH*8*NUM_SLOTS;
    float* part = Hst  + (size_t)BATCH*NUM_SLOTS*D_MODEL;
    float* Qout = part + (size_t)IGROUPS*BATCH*NUM_SLOTS*D_MODEL;
    float* Kf   = Qout + (size_t)NTOK*D_MODEL;
    float* Vf   = Kf   + (size_t)BATCH*NUM_SLOTS*D_MODEL;
    float* A2   = Vf   + (size_t)BATCH*NUM_SLOTS*D_MODEL;
    float* Yb   = A2   + (size_t)NTOK*NUM_SLOTS;
    unsigned short* Yh = (unsigned short*)(Yb + (size_t)NTOK*D_MODEL);
    unsigned short* Yl = Yh + (size_t)NTOK*D_MODEL;
    unsigned short* Wf16 = Yl + (size_t)NTOK*D_MODEL;
    unsigned short* Hst16 = Wf16 + (size_t)VOCAB*D_MODEL;

    // one-time weight conversions (independent of the rest)
    if (useF16)
        k_convert<<<dim3(128, 128, 4), 256, 0, stream>>>(Ws, Wt, WF);
    k_split16<<<(VOCAB*D_MODEL/4 + 255)/256, 256, 0, stream>>>(Wop, Wf16, VOCAB*D_MODEL/4);

    // embeddings
    k_embed<<<NTOK, 256, 0, stream>>>(ids, tok, pos, X);
    // X projections (Qin, Vin, Qout) fused into one dispatch
    k_gemm3<<<dim3(NTOK/64, 4, 3), 256, 0, stream>>>(X, Wq_in, Wv_in, Wq_out, Qin, Vin, Qout);
    k_gemm_nt<<<dim3(2, 4), 256, 0, stream>>>(Hin, Wk_sl, Ksl, NUM_SLOTS, D_MODEL, D_MODEL);
    // scores + softmax + mask
    k_gemm_nt<<<dim3(NTOK/64, 2), 256, 0, stream>>>(Qin, Ksl, Asc, NTOK, NUM_SLOTS, D_MODEL);
    k_softmax_mask<<<NTOK, 128, 0, stream>>>(Asc, amask);
    // column-normalize + aggregate into slots
    k_colsum<<<dim3(BATCH, 8), 128, 0, stream>>>(Asc, csp);
    k_ir<<<BATCH*NUM_SLOTS, 256, 0, stream>>>(Asc, Vin, Hin, csp, Hst, Hst16);
    // bilinear slot-interaction steps
    for (int st = 0; st < N_STEPS; ++st) {
        if (useF16)
            k_pairs_mfma<<<dim3(NUM_SLOTS, IGROUPS), 256, 0, stream>>>(Hst16, WF, part);
        else
            k_pairs<<<dim3(NUM_SLOTS, IGROUPS), 256, 0, stream>>>(Hst, Ws, Wt, part);
        k_ln<<<BATCH*NUM_SLOTS, 256, 0, stream>>>(Hst, Hst16, part, lnsc + st*D_MODEL, lnbs + st*D_MODEL);
    }
    // expand projections (Kf, Vf fused)
    k_kfvf<<<dim3(BATCH*NUM_SLOTS/64, 4, 2), 256, 0, stream>>>(Hst, Wk_fin, Wv_fin, Kf, Vf);
    // fused expand attention + Y + fp16 split
    k_attn2y<<<NTOK, 256, 0, stream>>>(Qout, Kf, Vf, Yh, Yl);
    // logits: 2-pass fp16-split MFMA with global_load_lds staging
    k_logits<<<dim3(NTOK/128, VOCAB/128), 256, 0, stream>>>(Yh, Yl, Wf16, out);
}

// Round 12
// 1425.922 us; speedup vs baseline: 1.4235x; 1.0311x over previous
//
#include <hip/hip_runtime.h>
#include <hip/hip_bf16.h>
#include <math.h>

#define D_MODEL 256
#define NUM_SLOTS 128
#define RANK 32
#define N_STEPS 6
#define VOCAB 32000
#define SEQ 512
#define BATCH 8
#define NTOK (BATCH*SEQ)
#define LN_EPS 1e-5f
#define SM_SCALE 0.0625f
#define IGROUPS 8
#define IPG (NUM_SLOTS/IGROUPS)

typedef __attribute__((ext_vector_type(8))) short bf16x8;
typedef __attribute__((ext_vector_type(8))) _Float16 f16x8;
typedef __attribute__((ext_vector_type(4))) float f32x4;

#define GLD_LDS16(g, l) __builtin_amdgcn_global_load_lds( \
    (const __attribute__((address_space(1))) unsigned int*)(g), \
    (__attribute__((address_space(3))) unsigned int*)(l), 16, 0, 0)

__device__ inline unsigned short f2bf(float x) {
    unsigned u = __float_as_uint(x);
    unsigned r = u + 0x7fff + ((u >> 16) & 1);
    return (unsigned short)(r >> 16);
}
__device__ inline float bf2f(unsigned short h) {
    return __uint_as_float(((unsigned)h) << 16);
}
__device__ inline unsigned pk2(float a, float b) {
    auto v = __builtin_amdgcn_cvt_pkrtz(a, b);
    union { decltype(v) x; unsigned u; } c;
    c.x = v;
    return c.u;
}
__device__ inline unsigned short f2h(float x) {
    union { _Float16 h; unsigned short u; } c;
    c.h = (_Float16)x;
    return c.u;
}
__device__ inline float h2f(unsigned short u) {
    union { unsigned short u; _Float16 h; } c;
    c.u = u;
    return (float)c.h;
}

// X[b,l,:] = token_emb[ids[b,l],:] + pos_emb[l,:]
__global__ __launch_bounds__(256) void k_embed(const int* __restrict__ ids,
        const float* __restrict__ tok, const float* __restrict__ pos,
        float* __restrict__ X) {
    int bl = blockIdx.x;
    int d  = threadIdx.x;
    int l  = bl % SEQ;
    int id = ids[bl];
    X[(size_t)bl*D_MODEL + d] = tok[(size_t)id*D_MODEL + d] + pos[l*D_MODEL + d];
}

// C[m,n] = sum_k A[m,k]*B[n,k]   (both row-major, K contiguous)  64x64 tile
__global__ __launch_bounds__(256) void k_gemm_nt(const float* __restrict__ A,
        const float* __restrict__ B, float* __restrict__ C, int M, int N, int K) {
    __shared__ float As[32][64];
    __shared__ float Bs[32][64];
    int bm = blockIdx.x * 64, bn = blockIdx.y * 64;
    int t = threadIdx.x;
    int tm = (t & 15) * 4, tn = (t >> 4) * 4;
    float acc[4][4] = {};
    for (int k0 = 0; k0 < K; k0 += 32) {
        #pragma unroll
        for (int r = 0; r < 8; ++r) {
            int idx = r*256 + t;
            int m = idx >> 5, k = idx & 31;
            As[k][m] = A[(size_t)(bm+m)*K + k0 + k];
        }
        #pragma unroll
        for (int r = 0; r < 8; ++r) {
            int idx = r*256 + t;
            int n = idx >> 5, k = idx & 31;
            Bs[k][n] = B[(size_t)(bn+n)*K + k0 + k];
        }
        __syncthreads();
        #pragma unroll
        for (int k = 0; k < 32; ++k) {
            float4 a4 = *(const float4*)&As[k][tm];
            float4 b4 = *(const float4*)&Bs[k][tn];
            float a[4] = {a4.x,a4.y,a4.z,a4.w};
            float b[4] = {b4.x,b4.y,b4.z,b4.w};
            #pragma unroll
            for (int i = 0; i < 4; ++i)
                #pragma unroll
                for (int jj = 0; jj < 4; ++jj)
                    acc[i][jj] += a[i]*b[jj];
        }
        __syncthreads();
    }
    #pragma unroll
    for (int i = 0; i < 4; ++i) {
        float4 v = make_float4(acc[i][0],acc[i][1],acc[i][2],acc[i][3]);
        *(float4*)&C[(size_t)(bm+tm+i)*N + bn+tn] = v;
    }
}

// 3 projections (Qin, Vin, Qout) from the same A=X, selected by blockIdx.z
__global__ __launch_bounds__(256) void k_gemm3(const float* __restrict__ A,
        const float* __restrict__ B0, const float* __restrict__ B1,
        const float* __restrict__ B2, float* __restrict__ C0,
        float* __restrict__ C1, float* __restrict__ C2) {
    const int K = D_MODEL, N = D_MODEL;
    const float* B = blockIdx.z == 0 ? B0 : (blockIdx.z == 1 ? B1 : B2);
    float* C = blockIdx.z == 0 ? C0 : (blockIdx.z == 1 ? C1 : C2);
    __shared__ float As[32][64];
    __shared__ float Bs[32][64];
    int bm = blockIdx.x * 64, bn = blockIdx.y * 64;
    int t = threadIdx.x;
    int tm = (t & 15) * 4, tn = (t >> 4) * 4;
    float acc[4][4] = {};
    for (int k0 = 0; k0 < K; k0 += 32) {
        #pragma unroll
        for (int r = 0; r < 8; ++r) {
            int idx = r*256 + t;
            int m = idx >> 5, k = idx & 31;
            As[k][m] = A[(size_t)(bm+m)*K + k0 + k];
        }
        #pragma unroll
        for (int r = 0; r < 8; ++r) {
            int idx = r*256 + t;
            int n = idx >> 5, k = idx & 31;
            Bs[k][n] = B[(size_t)(bn+n)*K + k0 + k];
        }
        __syncthreads();
        #pragma unroll
        for (int k = 0; k < 32; ++k) {
            float4 a4 = *(const float4*)&As[k][tm];
            float4 b4 = *(const float4*)&Bs[k][tn];
            float a[4] = {a4.x,a4.y,a4.z,a4.w};
            float b[4] = {b4.x,b4.y,b4.z,b4.w};
            #pragma unroll
            for (int i = 0; i < 4; ++i)
                #pragma unroll
                for (int jj = 0; jj < 4; ++jj)
                    acc[i][jj] += a[i]*b[jj];
        }
        __syncthreads();
    }
    #pragma unroll
    for (int i = 0; i < 4; ++i) {
        float4 v = make_float4(acc[i][0],acc[i][1],acc[i][2],acc[i][3]);
        *(float4*)&C[(size_t)(bm+tm+i)*N + bn+tn] = v;
    }
}

// Kf/Vf projections from Hst, selected by blockIdx.z
__global__ __launch_bounds__(256) void k_kfvf(const float* __restrict__ A,
        const float* __restrict__ B0, const float* __restrict__ B1,
        float* __restrict__ C0, float* __restrict__ C1) {
    const int K = D_MODEL, N = D_MODEL;
    const float* B = blockIdx.z == 0 ? B0 : B1;
    float* C = blockIdx.z == 0 ? C0 : C1;
    __shared__ float As[32][64];
    __shared__ float Bs[32][64];
    int bm = blockIdx.x * 64, bn = blockIdx.y * 64;
    int t = threadIdx.x;
    int tm = (t & 15) * 4, tn = (t >> 4) * 4;
    float acc[4][4] = {};
    for (int k0 = 0; k0 < K; k0 += 32) {
        #pragma unroll
        for (int r = 0; r < 8; ++r) {
            int idx = r*256 + t;
            int m = idx >> 5, k = idx & 31;
            As[k][m] = A[(size_t)(bm+m)*K + k0 + k];
        }
        #pragma unroll
        for (int r = 0; r < 8; ++r) {
            int idx = r*256 + t;
            int n = idx >> 5, k = idx & 31;
            Bs[k][n] = B[(size_t)(bn+n)*K + k0 + k];
        }
        __syncthreads();
        #pragma unroll
        for (int k = 0; k < 32; ++k) {
            float4 a4 = *(const float4*)&As[k][tm];
            float4 b4 = *(const float4*)&Bs[k][tn];
            float a[4] = {a4.x,a4.y,a4.z,a4.w};
            float b[4] = {b4.x,b4.y,b4.z,b4.w};
            #pragma unroll
            for (int i = 0; i < 4; ++i)
                #pragma unroll
                for (int jj = 0; jj < 4; ++jj)
                    acc[i][jj] += a[i]*b[jj];
        }
        __syncthreads();
    }
    #pragma unroll
    for (int i = 0; i < 4; ++i) {
        float4 v = make_float4(acc[i][0],acc[i][1],acc[i][2],acc[i][3]);
        *(float4*)&C[(size_t)(bm+tm+i)*N + bn+tn] = v;
    }
}

// fp32 -> fp16 (for W_out_proj)
__global__ __launch_bounds__(256) void k_split16(const float* __restrict__ in,
        unsigned short* __restrict__ o, int n4) {
    int i = blockIdx.x*256 + threadIdx.x;
    if (i >= n4) return;
    float4 v = ((const float4*)in)[i];
    ushort4 h;
    h.x = f2h(v.x); h.y = f2h(v.y); h.z = f2h(v.z); h.w = f2h(v.w);
    ((ushort4*)o)[i] = h;
}

// logits GEMM: 1-pass fp16 MFMA, global_load_lds staging. C = Y16 * W16^T.
__global__ __launch_bounds__(256) void k_logits(
        const unsigned short* __restrict__ Ahg,
        const unsigned short* __restrict__ Bhg, float* __restrict__ C) {
    __shared__ unsigned short lds[2*8192];   // Ah | Bh, each [128][64] linear
    int bm = blockIdx.x * 128, bn = blockIdx.y * 128;
    int t = threadIdx.x;
    int w = t >> 6, l = t & 63;
    int wr = w >> 1, wc = w & 1;
    int lr = l & 15, lk = l >> 4;
    f32x4 acc[4][4];
    #pragma unroll
    for (int mi = 0; mi < 4; ++mi)
        #pragma unroll
        for (int ni = 0; ni < 4; ++ni)
            acc[mi][ni] = (f32x4){0.f,0.f,0.f,0.f};

    for (int kc = 0; kc < 4; ++kc) {
        if (kc) __syncthreads();
        #pragma unroll
        for (int i = 0; i < 4; ++i) {
            int c = t + i*256;
            int row = c >> 3, c8 = c & 7;
            size_t ga = (size_t)(bm+row)*256 + kc*64 + c8*8;
            size_t gb = (size_t)(bn+row)*256 + kc*64 + c8*8;
            GLD_LDS16(Ahg + ga, &lds[c*8]);
            GLD_LDS16(Bhg + gb, &lds[8192 + c*8]);
        }
        __syncthreads();
        #pragma unroll
        for (int s = 0; s < 2; ++s) {
            f16x8 ah[4], bh[4];
            #pragma unroll
            for (int mi = 0; mi < 4; ++mi) {
                int off = (wr*64 + mi*16 + lr)*64 + s*32 + lk*8;
                ah[mi] = *(const f16x8*)&lds[off];
            }
            #pragma unroll
            for (int ni = 0; ni < 4; ++ni) {
                int off = (wc*64 + ni*16 + lr)*64 + s*32 + lk*8;
                bh[ni] = *(const f16x8*)&lds[8192 + off];
            }
            #pragma unroll
            for (int mi = 0; mi < 4; ++mi)
                #pragma unroll
                for (int ni = 0; ni < 4; ++ni)
                    acc[mi][ni] = __builtin_amdgcn_mfma_f32_16x16x32_f16(ah[mi], bh[ni], acc[mi][ni], 0, 0, 0);
        }
    }
    #pragma unroll
    for (int mi = 0; mi < 4; ++mi)
        #pragma unroll
        for (int ni = 0; ni < 4; ++ni) {
            int col = bn + wc*64 + ni*16 + lr;
            #pragma unroll
            for (int r = 0; r < 4; ++r) {
                int row = bm + wr*64 + mi*16 + lk*4 + r;
                C[(size_t)row*VOCAB + col] = acc[mi][ni][r];
            }
        }
}

__global__ __launch_bounds__(128) void k_softmax_mask(float* __restrict__ A,
        const int* __restrict__ mask) {
    int row = blockIdx.x;
    int s = threadIdx.x;
    __shared__ float red[128];
    float v = A[(size_t)row*NUM_SLOTS + s] * SM_SCALE;
    red[s] = v; __syncthreads();
    for (int o = 64; o > 0; o >>= 1) { if (s < o) red[s] = fmaxf(red[s], red[s+o]); __syncthreads(); }
    float mx = red[0]; __syncthreads();
    float e = expf(v - mx);
    red[s] = e; __syncthreads();
    for (int o = 64; o > 0; o >>= 1) { if (s < o) red[s] += red[s+o]; __syncthreads(); }
    float sum = red[0];
    float m = (float)mask[row];
    A[(size_t)row*NUM_SLOTS + s] = e / sum * m;
}

// partial column sums: block (b, chunk) sums 64 l's
__global__ __launch_bounds__(128) void k_colsum(const float* __restrict__ A,
        float* __restrict__ csp) {
    int b = blockIdx.x; int ch = blockIdx.y; int s = threadIdx.x;
    const float* Ab = A + ((size_t)b*SEQ + ch*64)*NUM_SLOTS + s;
    float a0 = 0.f, a1 = 0.f, a2 = 0.f, a3 = 0.f;
    #pragma unroll
    for (int l = 0; l < 64; l += 4) {
        a0 += Ab[(size_t)(l+0)*NUM_SLOTS];
        a1 += Ab[(size_t)(l+1)*NUM_SLOTS];
        a2 += Ab[(size_t)(l+2)*NUM_SLOTS];
        a3 += Ab[(size_t)(l+3)*NUM_SLOTS];
    }
    csp[(b*8 + ch)*NUM_SLOTS + s] = (a0+a1) + (a2+a3);
}

// H_state = H + IR; writes fp32 and fp16 copies; sums 8 colsum partials
__global__ __launch_bounds__(256) void k_ir(const float* __restrict__ A,
        const float* __restrict__ V, const float* __restrict__ H,
        const float* __restrict__ csp, float* __restrict__ Hs,
        unsigned short* __restrict__ Hs16) {
    int bs = blockIdx.x; int b = bs >> 7; int s = bs & 127;
    int d = threadIdx.x;
    float sum = 1e-8f;
    #pragma unroll
    for (int p = 0; p < 8; ++p) sum += csp[(b*8 + p)*NUM_SLOTS + s];
    float inv = 1.0f / sum;
    const float* Ab = A + (size_t)b*SEQ*NUM_SLOTS + s;
    const float* Vb = V + (size_t)b*SEQ*D_MODEL + d;
    float a0 = 0.f, a1 = 0.f, a2 = 0.f, a3 = 0.f;
    for (int l = 0; l < SEQ; l += 4) {
        a0 += Ab[(size_t)(l+0)*NUM_SLOTS] * Vb[(size_t)(l+0)*D_MODEL];
        a1 += Ab[(size_t)(l+1)*NUM_SLOTS] * Vb[(size_t)(l+1)*D_MODEL];
        a2 += Ab[(size_t)(l+2)*NUM_SLOTS] * Vb[(size_t)(l+2)*D_MODEL];
        a3 += Ab[(size_t)(l+3)*NUM_SLOTS] * Vb[(size_t)(l+3)*D_MODEL];
    }
    float acc = (a0+a1) + (a2+a3);
    float v = H[s*D_MODEL + d] + acc * inv;
    Hs[(size_t)bs*D_MODEL + d] = v;
    Hs16[(size_t)bs*D_MODEL + d] = f2h(v);
}

// ---- one-time fp32->fp16 weight conversion, barrier-free per-wave (frozen) ----
__global__ __launch_bounds__(256) void k_convert(const float* __restrict__ Ws,
        const float* __restrict__ Wt, unsigned short* __restrict__ WF) {
    int i = blockIdx.x, j = blockIdx.y, z = blockIdx.z;
    int t = threadIdx.x, w = t >> 6, l = t & 63;
    __shared__ float lds[4*1056];
    float* lw = &lds[w*1056];
    size_t sBase = ((size_t)i*128 + j)*8192;
    size_t pOut = ((size_t)j*128 + i)*16384;
    int g = l >> 4, c = l & 15;
    if (z < 2) {
        int ks = z*4 + w;
        const float4* s4 = (const float4*)(Ws + sBase) + ks*256;
        #pragma unroll
        for (int q = 0; q < 4; ++q) {
            int idx = q*64 + l;
            float4 v = s4[idx];
            *(float4*)&lw[(idx>>3)*33 + 4*(idx&7)] = v;
        }
        asm volatile("s_waitcnt lgkmcnt(0)" ::: "memory");
        bool diag = (i == j);
        #pragma unroll
        for (int mt = 0; mt < 2; ++mt) {
            union { f16x8 v; } o;
            #pragma unroll
            for (int e = 0; e < 8; ++e) {
                float f = diag ? 0.f : lw[(g*8 + e)*33 + mt*16 + c];
                o.v[e] = (_Float16)f;
            }
            *(f16x8*)(WF + pOut + (size_t)((ks*2 + mt)*64 + l)*8) = o.v;
        }
    } else {
        int p0 = (z - 2)*8 + w*2;
        const float4* s4 = (const float4*)(Wt + sBase);
        #pragma unroll
        for (int q = 0; q < 4; ++q) {
            int idx = q*64 + l;
            int r = idx >> 3, c8 = idx & 7;
            float4 v = s4[r*64 + p0*4 + c8];
            *(float4*)&lw[r*33 + 4*c8] = v;
        }
        asm volatile("s_waitcnt lgkmcnt(0)" ::: "memory");
        #pragma unroll
        for (int dn = 0; dn < 2; ++dn) {
            int nt = p0 + dn;
            union { f16x8 v; } o;
            #pragma unroll
            for (int e = 0; e < 8; ++e)
                o.v[e] = (_Float16)lw[(g*8 + e)*33 + dn*16 + c];
            *(f16x8*)(WF + pOut + 8192 + (size_t)(nt*64 + l)*8) = o.v;
        }
    }
}

// ---- MFMA slot-pair kernel (frozen structure) ----
__global__ __launch_bounds__(256, 4) void k_pairs_mfma(const unsigned short* __restrict__ h16,
        const unsigned short* __restrict__ WF, float* __restrict__ part) {
    __shared__ unsigned short lds[2*10240];
    int j = blockIdx.x, g = blockIdx.y;
    int t = threadIdx.x, w = t >> 6, l = t & 63;
    int lg = l >> 4, c = l & 15;
    const unsigned short* pbase = WF + ((size_t)j*128 + g*16)*16384;

    {
        const unsigned short* src = pbase;
        #pragma unroll
        for (int q = 0; q < 4; ++q)
            GLD_LDS16(src + (size_t)(q*256 + t)*8, &lds[(q*256 + t)*8]);
        const unsigned short* hsrc = h16 + ((size_t)(t&7)*NUM_SLOTS + g*16)*D_MODEL + (t>>3)*8;
        GLD_LDS16(hsrc, &lds[8192 + t*8]);
    }
    __builtin_amdgcn_sched_barrier(0);
    f16x8 bqn[4];
    #pragma unroll
    for (int nt = 0; nt < 4; ++nt)
        bqn[nt] = *(const f16x8*)(pbase + 8192 + (size_t)((w*4+nt)*64 + l)*8);
    __builtin_amdgcn_sched_barrier(0);

    f32x4 acc[4];
    #pragma unroll
    for (int nt = 0; nt < 4; ++nt) acc[nt] = (f32x4){0.f,0.f,0.f,0.f};
    f16x8 hzero;
    #pragma unroll
    for (int e = 0; e < 8; ++e) hzero[e] = (_Float16)0.f;

    #pragma unroll 2
    for (int ii = 0; ii < 16; ++ii) {
        int cur = ii & 1;
        asm volatile("s_waitcnt vmcnt(4) lgkmcnt(0)" ::: "memory");
        __builtin_amdgcn_s_barrier();
        __builtin_amdgcn_sched_barrier(0);
        if (ii < 15) {
            const unsigned short* src = pbase + (size_t)(ii+1)*16384;
            unsigned short* dst = &lds[(cur^1)*10240];
            #pragma unroll
            for (int q = 0; q < 4; ++q)
                GLD_LDS16(src + (size_t)(q*256 + t)*8, dst + (size_t)(q*256 + t)*8);
            const unsigned short* hsrc = h16 + ((size_t)(t&7)*NUM_SLOTS + (g*16+ii+1))*D_MODEL + (t>>3)*8;
            GLD_LDS16(hsrc, dst + 8192 + (size_t)t*8);
        }
        __builtin_amdgcn_sched_barrier(0);
        f16x8 bq[4];
        #pragma unroll
        for (int nt = 0; nt < 4; ++nt) bq[nt] = bqn[nt];
        if (ii < 15) {
            const unsigned short* bp = pbase + (size_t)(ii+1)*16384 + 8192;
            #pragma unroll
            for (int nt = 0; nt < 4; ++nt)
                bqn[nt] = *(const f16x8*)(bp + (size_t)((w*4+nt)*64 + l)*8);
        }
        const unsigned short* buf = &lds[cur*10240];
        f32x4 d1[2];
        d1[0] = (f32x4){0.f,0.f,0.f,0.f};
        d1[1] = (f32x4){0.f,0.f,0.f,0.f};
        #pragma unroll
        for (int ks = 0; ks < 8; ++ks) {
            f16x8 a0 = *(const f16x8*)(buf + (size_t)((ks*2+0)*64 + l)*8);
            f16x8 a1 = *(const f16x8*)(buf + (size_t)((ks*2+1)*64 + l)*8);
            f16x8 hv = *(const f16x8*)(buf + 8192 + (size_t)(((ks*4+lg)*8 + (c&7)))*8);
            f16x8 hb = (c < 8) ? hv : hzero;
            d1[0] = __builtin_amdgcn_mfma_f32_16x16x32_f16(a0, hb, d1[0], 0, 0, 0);
            d1[1] = __builtin_amdgcn_mfma_f32_16x16x32_f16(a1, hb, d1[1], 0, 0, 0);
        }
        unsigned q0 = pk2(d1[0][0], d1[0][1]);
        unsigned q1 = pk2(d1[0][2], d1[0][3]);
        unsigned s0 = pk2(d1[1][0], d1[1][1]);
        unsigned s1 = pk2(d1[1][2], d1[1][3]);
        int srcLo = 32*(lg & 1) + c;
        int srcHi = srcLo + 16;
        unsigned a0s = (unsigned)__shfl((int)q0, srcLo, 64);
        unsigned a1s = (unsigned)__shfl((int)q1, srcLo, 64);
        unsigned a2s = (unsigned)__shfl((int)q0, srcHi, 64);
        unsigned a3s = (unsigned)__shfl((int)q1, srcHi, 64);
        unsigned b0s = (unsigned)__shfl((int)s0, srcLo, 64);
        unsigned b1s = (unsigned)__shfl((int)s1, srcLo, 64);
        unsigned b2s = (unsigned)__shfl((int)s0, srcHi, 64);
        unsigned b3s = (unsigned)__shfl((int)s1, srcHi, 64);
        bool himt = ((lg >> 1) & 1);
        union { unsigned u[4]; f16x8 v; } A2u;
        A2u.u[0] = himt ? b0s : a0s;
        A2u.u[1] = himt ? b1s : a1s;
        A2u.u[2] = himt ? b2s : a2s;
        A2u.u[3] = himt ? b3s : a3s;
        #pragma unroll
        for (int nt = 0; nt < 4; ++nt)
            acc[nt] = __builtin_amdgcn_mfma_f32_16x16x32_f16(A2u.v, bq[nt], acc[nt], 0, 0, 0);
    }
    if (lg < 2) {
        #pragma unroll
        for (int nt = 0; nt < 4; ++nt) {
            int d = (w*4 + nt)*16 + c;
            #pragma unroll
            for (int r = 0; r < 4; ++r) {
                int b = lg*4 + r;
                part[(((size_t)g*BATCH + b)*NUM_SLOTS + j)*D_MODEL + d] = acc[nt][r];
            }
        }
    }
}

// fallback fp32 pairs kernel (used when ws too small for WF)
__global__ __launch_bounds__(256) void k_pairs(const float* __restrict__ h,
        const float* __restrict__ Ws, const float* __restrict__ Wt,
        float* __restrict__ part) {
    int j = blockIdx.x;
    int g = blockIdx.y;
    int t = threadIdx.x;
    __shared__ float sh_h[BATCH][D_MODEL];
    __shared__ float sh_inter[BATCH][RANK];
    float acc[BATCH];
    #pragma unroll
    for (int b = 0; b < BATCH; ++b) acc[b] = 0.f;
    int tb = t >> 5, tr = t & 31;
    for (int ii = 0; ii < IPG; ++ii) {
        int i = g*IPG + ii;
        if (i == j) continue;
        #pragma unroll
        for (int b = 0; b < BATCH; ++b)
            sh_h[b][t] = h[((size_t)b*NUM_SLOTS + i)*D_MODEL + t];
        __syncthreads();
        const float* ws = Ws + ((size_t)i*NUM_SLOTS + j)*(D_MODEL*RANK);
        float accA = 0.f;
        #pragma unroll 8
        for (int d = 0; d < D_MODEL; ++d)
            accA += sh_h[tb][d] * ws[(size_t)d*RANK + tr];
        sh_inter[tb][tr] = accA;
        __syncthreads();
        const float* wt = Wt + ((size_t)i*NUM_SLOTS + j)*(RANK*D_MODEL);
        #pragma unroll 8
        for (int r = 0; r < RANK; ++r) {
            float w = wt[(size_t)r*D_MODEL + t];
            #pragma unroll
            for (int b = 0; b < BATCH; ++b) acc[b] += sh_inter[b][r] * w;
        }
        __syncthreads();
    }
    #pragma unroll
    for (int b = 0; b < BATCH; ++b)
        part[(((size_t)g*BATCH + b)*NUM_SLOTS + j)*D_MODEL + t] = acc[b];
}

// h = LN(h + relu(sum_g part)); writes fp32 and fp16 copies
__global__ __launch_bounds__(256) void k_ln(float* __restrict__ h,
        unsigned short* __restrict__ h16, const float* __restrict__ part,
        const float* __restrict__ gma, const float* __restrict__ bta) {
    int bj = blockIdx.x;
    int t = threadIdx.x;
    int b = bj >> 7, j = bj & 127;
    __shared__ float red[256];
    float v = 0.f;
    #pragma unroll
    for (int g = 0; g < IGROUPS; ++g)
        v += part[(((size_t)g*BATCH + b)*NUM_SLOTS + j)*D_MODEL + t];
    float x = h[(size_t)bj*D_MODEL + t] + fmaxf(v, 0.f);
    red[t] = x; __syncthreads();
    for (int o = 128; o > 0; o >>= 1) { if (t < o) red[t] += red[t+o]; __syncthreads(); }
    float mu = red[0] * (1.0f/D_MODEL); __syncthreads();
    float dx = x - mu;
    red[t] = dx*dx; __syncthreads();
    for (int o = 128; o > 0; o >>= 1) { if (t < o) red[t] += red[t+o]; __syncthreads(); }
    float var = red[0] * (1.0f/D_MODEL);
    float outv = dx * rsqrtf(var + LN_EPS) * gma[t] + bta[t];
    h[(size_t)bj*D_MODEL + t] = outv;
    h16[(size_t)bj*D_MODEL + t] = f2h(outv);
}

// fused expand attention: scores -> softmax -> Y, written as fp16
__global__ __launch_bounds__(256) void k_attn2y(const float* __restrict__ Q,
        const float* __restrict__ Kf, const float* __restrict__ Vf,
        unsigned short* __restrict__ Yh) {
    int bl = blockIdx.x; int b = bl / SEQ;
    int t = threadIdx.x;
    __shared__ float q[D_MODEL];
    __shared__ float prt[2][128];
    __shared__ float a[128];
    __shared__ float red[128];
    q[t] = Q[(size_t)bl*D_MODEL + t];
    __syncthreads();
    int s = t & 127, hf = t >> 7;
    const float* kf = Kf + ((size_t)b*NUM_SLOTS + s)*D_MODEL + hf*128;
    float accp = 0.f;
    #pragma unroll 8
    for (int d = 0; d < 128; ++d) accp += q[hf*128 + d]*kf[d];
    prt[hf][s] = accp;
    __syncthreads();
    float v = 0.f;
    if (t < 128) { v = (prt[0][t] + prt[1][t]) * SM_SCALE; red[t] = v; }
    __syncthreads();
    for (int o = 64; o > 0; o >>= 1) { if (t < o) red[t] = fmaxf(red[t], red[t+o]); __syncthreads(); }
    float mx = red[0]; __syncthreads();
    if (t < 128) { float e = expf(v - mx); a[t] = e; red[t] = e; }
    __syncthreads();
    for (int o = 64; o > 0; o >>= 1) { if (t < o) red[t] += red[t+o]; __syncthreads(); }
    float inv = 1.0f / red[0];
    __syncthreads();
    const float* vf = Vf + (size_t)b*NUM_SLOTS*D_MODEL + t;
    float y0 = 0.f, y1 = 0.f, y2 = 0.f, y3 = 0.f;
    #pragma unroll
    for (int s2 = 0; s2 < NUM_SLOTS; s2 += 4) {
        y0 += a[s2+0]*vf[(size_t)(s2+0)*D_MODEL];
        y1 += a[s2+1]*vf[(size_t)(s2+1)*D_MODEL];
        y2 += a[s2+2]*vf[(size_t)(s2+2)*D_MODEL];
        y3 += a[s2+3]*vf[(size_t)(s2+3)*D_MODEL];
    }
    float y = ((y0+y1) + (y2+y3)) * inv;
    Yh[(size_t)bl*D_MODEL + t] = f2h(y);
}

extern "C" void kernel_launch(void* const* d_in, const int* in_sizes, int n_in,
                              void* d_out, int out_size, void* d_ws, size_t ws_size,
                              hipStream_t stream) {
    const int*   ids    = (const int*)d_in[0];
    const int*   amask  = (const int*)d_in[1];
    const float* tok    = (const float*)d_in[2];
    const float* pos    = (const float*)d_in[3];
    const float* Hin    = (const float*)d_in[4];
    const float* Ws     = (const float*)d_in[5];
    const float* Wt     = (const float*)d_in[6];
    const float* Wq_in  = (const float*)d_in[7];
    const float* Wk_sl  = (const float*)d_in[8];
    const float* Wv_in  = (const float*)d_in[9];
    const float* Wq_out = (const float*)d_in[10];
    const float* Wk_fin = (const float*)d_in[11];
    const float* Wv_fin = (const float*)d_in[12];
    const float* Wop    = (const float*)d_in[13];
    const float* lnsc   = (const float*)d_in[14];
    const float* lnbs   = (const float*)d_in[15];
    float* out = (float*)d_out;

    const size_t WF_USH = (size_t)16384 * 16384;     // 512 MiB of ushorts
    const size_t F32_FLOATS = 18600000ULL;           // fp32+fp16 scratch region
    const bool useF16 = ws_size >= WF_USH*2 + F32_FLOATS*4 + 256;

    unsigned short* WF = (unsigned short*)d_ws;
    float* ws = useF16 ? (float*)(WF + WF_USH) : (float*)d_ws;

    float* X    = ws;
    float* Qin  = X    + (size_t)NTOK*D_MODEL;
    float* Vin  = Qin  + (size_t)NTOK*D_MODEL;
    float* Ksl  = Vin  + (size_t)NTOK*D_MODEL;
    float* Asc  = Ksl  + (size_t)NUM_SLOTS*D_MODEL;
    float* csp  = Asc  + (size_t)NTOK*NUM_SLOTS;
    float* Hst  = csp  + (size_t)BATCH*8*NUM_SLOTS;
    float* part = Hst  + (size_t)BATCH*NUM_SLOTS*D_MODEL;
    float* Qout = part + (size_t)IGROUPS*BATCH*NUM_SLOTS*D_MODEL;
    float* Kf   = Qout + (size_t)NTOK*D_MODEL;
    float* Vf   = Kf   + (size_t)BATCH*NUM_SLOTS*D_MODEL;
    float* A2   = Vf   + (size_t)BATCH*NUM_SLOTS*D_MODEL;
    float* Yb   = A2   + (size_t)NTOK*NUM_SLOTS;
    unsigned short* Yh = (unsigned short*)(Yb + (size_t)NTOK*D_MODEL);
    unsigned short* Yl = Yh + (size_t)NTOK*D_MODEL;   // unused now
    unsigned short* Wf16 = Yl + (size_t)NTOK*D_MODEL;
    unsigned short* Hst16 = Wf16 + (size_t)VOCAB*D_MODEL;

    // one-time weight conversions (independent of the rest)
    if (useF16)
        k_convert<<<dim3(128, 128, 4), 256, 0, stream>>>(Ws, Wt, WF);
    k_split16<<<(VOCAB*D_MODEL/4 + 255)/256, 256, 0, stream>>>(Wop, Wf16, VOCAB*D_MODEL/4);

    // embeddings
    k_embed<<<NTOK, 256, 0, stream>>>(ids, tok, pos, X);
    // X projections (Qin, Vin, Qout) fused into one dispatch
    k_gemm3<<<dim3(NTOK/64, 4, 3), 256, 0, stream>>>(X, Wq_in, Wv_in, Wq_out, Qin, Vin, Qout);
    k_gemm_nt<<<dim3(2, 4), 256, 0, stream>>>(Hin, Wk_sl, Ksl, NUM_SLOTS, D_MODEL, D_MODEL);
    // scores + softmax + mask
    k_gemm_nt<<<dim3(NTOK/64, 2), 256, 0, stream>>>(Qin, Ksl, Asc, NTOK, NUM_SLOTS, D_MODEL);
    k_softmax_mask<<<NTOK, 128, 0, stream>>>(Asc, amask);
    // column-normalize + aggregate into slots
    k_colsum<<<dim3(BATCH, 8), 128, 0, stream>>>(Asc, csp);
    k_ir<<<BATCH*NUM_SLOTS, 256, 0, stream>>>(Asc, Vin, Hin, csp, Hst, Hst16);
    // bilinear slot-interaction steps
    for (int st = 0; st < N_STEPS; ++st) {
        if (useF16)
            k_pairs_mfma<<<dim3(NUM_SLOTS, IGROUPS), 256, 0, stream>>>(Hst16, WF, part);
        else
            k_pairs<<<dim3(NUM_SLOTS, IGROUPS), 256, 0, stream>>>(Hst, Ws, Wt, part);
        k_ln<<<BATCH*NUM_SLOTS, 256, 0, stream>>>(Hst, Hst16, part, lnsc + st*D_MODEL, lnbs + st*D_MODEL);
    }
    // expand projections (Kf, Vf fused)
    k_kfvf<<<dim3(BATCH*NUM_SLOTS/64, 4, 2), 256, 0, stream>>>(Hst, Wk_fin, Wv_fin, Kf, Vf);
    // fused expand attention + Y (fp16)
    k_attn2y<<<NTOK, 256, 0, stream>>>(Qout, Kf, Vf, Yh);
    // logits: 1-pass fp16 MFMA with global_load_lds staging
    k_logits<<<dim3(NTOK/128, VOCAB/128), 256, 0, stream>>>(Yh, Wf16, out);
}

// Round 13
// 1422.699 us; speedup vs baseline: 1.4268x; 1.0023x over previous
//
#include <hip/hip_runtime.h>
#include <hip/hip_bf16.h>
#include <math.h>

#define D_MODEL 256
#define NUM_SLOTS 128
#define RANK 32
#define N_STEPS 6
#define VOCAB 32000
#define SEQ 512
#define BATCH 8
#define NTOK (BATCH*SEQ)
#define LN_EPS 1e-5f
#define SM_SCALE 0.0625f
#define IGROUPS 8
#define IPG (NUM_SLOTS/IGROUPS)

typedef __attribute__((ext_vector_type(8))) short bf16x8;
typedef __attribute__((ext_vector_type(8))) _Float16 f16x8;
typedef __attribute__((ext_vector_type(4))) float f32x4;

#define GLD_LDS16(g, l) __builtin_amdgcn_global_load_lds( \
    (const __attribute__((address_space(1))) unsigned int*)(g), \
    (__attribute__((address_space(3))) unsigned int*)(l), 16, 0, 0)

__device__ inline unsigned pk2(float a, float b) {
    auto v = __builtin_amdgcn_cvt_pkrtz(a, b);
    union { decltype(v) x; unsigned u; } c;
    c.x = v;
    return c.u;
}
__device__ inline unsigned short f2h(float x) {
    union { _Float16 h; unsigned short u; } c;
    c.h = (_Float16)x;
    return c.u;
}

// C[m,n] = sum_k A[m,k]*B[n,k]   (both row-major, K contiguous)  64x64 tile
__global__ __launch_bounds__(256) void k_gemm_nt(const float* __restrict__ A,
        const float* __restrict__ B, float* __restrict__ C, int M, int N, int K) {
    __shared__ float As[32][64];
    __shared__ float Bs[32][64];
    int bm = blockIdx.x * 64, bn = blockIdx.y * 64;
    int t = threadIdx.x;
    int tm = (t & 15) * 4, tn = (t >> 4) * 4;
    float acc[4][4] = {};
    for (int k0 = 0; k0 < K; k0 += 32) {
        #pragma unroll
        for (int r = 0; r < 8; ++r) {
            int idx = r*256 + t;
            int m = idx >> 5, k = idx & 31;
            As[k][m] = A[(size_t)(bm+m)*K + k0 + k];
        }
        #pragma unroll
        for (int r = 0; r < 8; ++r) {
            int idx = r*256 + t;
            int n = idx >> 5, k = idx & 31;
            Bs[k][n] = B[(size_t)(bn+n)*K + k0 + k];
        }
        __syncthreads();
        #pragma unroll
        for (int k = 0; k < 32; ++k) {
            float4 a4 = *(const float4*)&As[k][tm];
            float4 b4 = *(const float4*)&Bs[k][tn];
            float a[4] = {a4.x,a4.y,a4.z,a4.w};
            float b[4] = {b4.x,b4.y,b4.z,b4.w};
            #pragma unroll
            for (int i = 0; i < 4; ++i)
                #pragma unroll
                for (int jj = 0; jj < 4; ++jj)
                    acc[i][jj] += a[i]*b[jj];
        }
        __syncthreads();
    }
    #pragma unroll
    for (int i = 0; i < 4; ++i) {
        float4 v = make_float4(acc[i][0],acc[i][1],acc[i][2],acc[i][3]);
        *(float4*)&C[(size_t)(bm+tm+i)*N + bn+tn] = v;
    }
}

// 3 projections (Qin, Vin, Qout) with the embed (tok[ids]+pos) fused into
// A-staging — X is never materialized. blockIdx.z selects the projection.
__global__ __launch_bounds__(256) void k_gemm3e(const int* __restrict__ ids,
        const float* __restrict__ tok, const float* __restrict__ pos,
        const float* __restrict__ B0, const float* __restrict__ B1,
        const float* __restrict__ B2, float* __restrict__ C0,
        float* __restrict__ C1, float* __restrict__ C2) {
    const int K = D_MODEL, N = D_MODEL;
    const float* B = blockIdx.z == 0 ? B0 : (blockIdx.z == 1 ? B1 : B2);
    float* C = blockIdx.z == 0 ? C0 : (blockIdx.z == 1 ? C1 : C2);
    __shared__ float As[32][64];
    __shared__ float Bs[32][64];
    __shared__ int sid[64];
    int bm = blockIdx.x * 64, bn = blockIdx.y * 64;
    int t = threadIdx.x;
    if (t < 64) sid[t] = ids[bm + t];
    __syncthreads();
    int tm = (t & 15) * 4, tn = (t >> 4) * 4;
    float acc[4][4] = {};
    for (int k0 = 0; k0 < K; k0 += 32) {
        #pragma unroll
        for (int r = 0; r < 8; ++r) {
            int idx = r*256 + t;
            int m = idx >> 5, k = idx & 31;
            int gm = bm + m;
            As[k][m] = tok[(size_t)sid[m]*K + k0 + k] + pos[(gm & (SEQ-1))*K + k0 + k];
        }
        #pragma unroll
        for (int r = 0; r < 8; ++r) {
            int idx = r*256 + t;
            int n = idx >> 5, k = idx & 31;
            Bs[k][n] = B[(size_t)(bn+n)*K + k0 + k];
        }
        __syncthreads();
        #pragma unroll
        for (int k = 0; k < 32; ++k) {
            float4 a4 = *(const float4*)&As[k][tm];
            float4 b4 = *(const float4*)&Bs[k][tn];
            float a[4] = {a4.x,a4.y,a4.z,a4.w};
            float b[4] = {b4.x,b4.y,b4.z,b4.w};
            #pragma unroll
            for (int i = 0; i < 4; ++i)
                #pragma unroll
                for (int jj = 0; jj < 4; ++jj)
                    acc[i][jj] += a[i]*b[jj];
        }
        __syncthreads();
    }
    #pragma unroll
    for (int i = 0; i < 4; ++i) {
        float4 v = make_float4(acc[i][0],acc[i][1],acc[i][2],acc[i][3]);
        *(float4*)&C[(size_t)(bm+tm+i)*N + bn+tn] = v;
    }
}

// fused compress attention: scores (Qin . Ksl) -> softmax -> mask -> Asc row
__global__ __launch_bounds__(128) void k_attn1(const float* __restrict__ Qin,
        const float* __restrict__ Ksl, const int* __restrict__ mask,
        float* __restrict__ A) {
    int bl = blockIdx.x;
    int s = threadIdx.x;
    __shared__ float q[D_MODEL];
    __shared__ float red[128];
    q[s]       = Qin[(size_t)bl*D_MODEL + s];
    q[s + 128] = Qin[(size_t)bl*D_MODEL + s + 128];
    __syncthreads();
    const float* kr = Ksl + (size_t)s*D_MODEL;
    float acc = 0.f;
    #pragma unroll 8
    for (int d = 0; d < D_MODEL; ++d) acc += q[d]*kr[d];
    acc *= SM_SCALE;
    red[s] = acc; __syncthreads();
    for (int o = 64; o > 0; o >>= 1) { if (s < o) red[s] = fmaxf(red[s], red[s+o]); __syncthreads(); }
    float mx = red[0]; __syncthreads();
    float e = expf(acc - mx);
    red[s] = e; __syncthreads();
    for (int o = 64; o > 0; o >>= 1) { if (s < o) red[s] += red[s+o]; __syncthreads(); }
    float sum = red[0];
    float m = (float)mask[bl];
    A[(size_t)bl*NUM_SLOTS + s] = e / sum * m;
}

// fp32 -> fp16 (for W_out_proj)
__global__ __launch_bounds__(256) void k_split16(const float* __restrict__ in,
        unsigned short* __restrict__ o, int n4) {
    int i = blockIdx.x*256 + threadIdx.x;
    if (i >= n4) return;
    float4 v = ((const float4*)in)[i];
    ushort4 h;
    h.x = f2h(v.x); h.y = f2h(v.y); h.z = f2h(v.z); h.w = f2h(v.w);
    ((ushort4*)o)[i] = h;
}

// logits GEMM: 1-pass fp16 MFMA, global_load_lds staging. C = Y16 * W16^T.
__global__ __launch_bounds__(256) void k_logits(
        const unsigned short* __restrict__ Ahg,
        const unsigned short* __restrict__ Bhg, float* __restrict__ C) {
    __shared__ unsigned short lds[2*8192];   // Ah | Bh, each [128][64] linear
    int bm = blockIdx.x * 128, bn = blockIdx.y * 128;
    int t = threadIdx.x;
    int w = t >> 6, l = t & 63;
    int wr = w >> 1, wc = w & 1;
    int lr = l & 15, lk = l >> 4;
    f32x4 acc[4][4];
    #pragma unroll
    for (int mi = 0; mi < 4; ++mi)
        #pragma unroll
        for (int ni = 0; ni < 4; ++ni)
            acc[mi][ni] = (f32x4){0.f,0.f,0.f,0.f};

    for (int kc = 0; kc < 4; ++kc) {
        if (kc) __syncthreads();
        #pragma unroll
        for (int i = 0; i < 4; ++i) {
            int c = t + i*256;
            int row = c >> 3, c8 = c & 7;
            size_t ga = (size_t)(bm+row)*256 + kc*64 + c8*8;
            size_t gb = (size_t)(bn+row)*256 + kc*64 + c8*8;
            GLD_LDS16(Ahg + ga, &lds[c*8]);
            GLD_LDS16(Bhg + gb, &lds[8192 + c*8]);
        }
        __syncthreads();
        #pragma unroll
        for (int s = 0; s < 2; ++s) {
            f16x8 ah[4], bh[4];
            #pragma unroll
            for (int mi = 0; mi < 4; ++mi) {
                int off = (wr*64 + mi*16 + lr)*64 + s*32 + lk*8;
                ah[mi] = *(const f16x8*)&lds[off];
            }
            #pragma unroll
            for (int ni = 0; ni < 4; ++ni) {
                int off = (wc*64 + ni*16 + lr)*64 + s*32 + lk*8;
                bh[ni] = *(const f16x8*)&lds[8192 + off];
            }
            #pragma unroll
            for (int mi = 0; mi < 4; ++mi)
                #pragma unroll
                for (int ni = 0; ni < 4; ++ni)
                    acc[mi][ni] = __builtin_amdgcn_mfma_f32_16x16x32_f16(ah[mi], bh[ni], acc[mi][ni], 0, 0, 0);
        }
    }
    #pragma unroll
    for (int mi = 0; mi < 4; ++mi)
        #pragma unroll
        for (int ni = 0; ni < 4; ++ni) {
            int col = bn + wc*64 + ni*16 + lr;
            #pragma unroll
            for (int r = 0; r < 4; ++r) {
                int row = bm + wr*64 + mi*16 + lk*4 + r;
                C[(size_t)row*VOCAB + col] = acc[mi][ni][r];
            }
        }
}

// H_state = H + IR with colsum computed in-kernel; writes fp32 + fp16 copies
__global__ __launch_bounds__(256) void k_ir(const float* __restrict__ A,
        const float* __restrict__ V, const float* __restrict__ H,
        float* __restrict__ Hs, unsigned short* __restrict__ Hs16) {
    int bs = blockIdx.x; int b = bs >> 7; int s = bs & 127;
    int d = threadIdx.x;
    const float* Ab = A + (size_t)b*SEQ*NUM_SLOTS + s;
    const float* Vb = V + (size_t)b*SEQ*D_MODEL + d;
    float a0 = 0.f, a1 = 0.f, a2 = 0.f, a3 = 0.f;
    float s0 = 0.f, s1 = 0.f, s2 = 0.f, s3 = 0.f;
    for (int l = 0; l < SEQ; l += 4) {
        float w0 = Ab[(size_t)(l+0)*NUM_SLOTS];
        float w1 = Ab[(size_t)(l+1)*NUM_SLOTS];
        float w2 = Ab[(size_t)(l+2)*NUM_SLOTS];
        float w3 = Ab[(size_t)(l+3)*NUM_SLOTS];
        a0 += w0 * Vb[(size_t)(l+0)*D_MODEL];
        a1 += w1 * Vb[(size_t)(l+1)*D_MODEL];
        a2 += w2 * Vb[(size_t)(l+2)*D_MODEL];
        a3 += w3 * Vb[(size_t)(l+3)*D_MODEL];
        s0 += w0; s1 += w1; s2 += w2; s3 += w3;
    }
    float asum = (s0+s1) + (s2+s3) + 1e-8f;
    float acc = (a0+a1) + (a2+a3);
    float v = H[s*D_MODEL + d] + acc / asum;
    Hs[(size_t)bs*D_MODEL + d] = v;
    Hs16[(size_t)bs*D_MODEL + d] = f2h(v);
}

// ---- one-time fp32->fp16 weight conversion, barrier-free per-wave (frozen) ----
__global__ __launch_bounds__(256) void k_convert(const float* __restrict__ Ws,
        const float* __restrict__ Wt, unsigned short* __restrict__ WF) {
    int i = blockIdx.x, j = blockIdx.y, z = blockIdx.z;
    int t = threadIdx.x, w = t >> 6, l = t & 63;
    __shared__ float lds[4*1056];
    float* lw = &lds[w*1056];
    size_t sBase = ((size_t)i*128 + j)*8192;
    size_t pOut = ((size_t)j*128 + i)*16384;
    int g = l >> 4, c = l & 15;
    if (z < 2) {
        int ks = z*4 + w;
        const float4* s4 = (const float4*)(Ws + sBase) + ks*256;
        #pragma unroll
        for (int q = 0; q < 4; ++q) {
            int idx = q*64 + l;
            float4 v = s4[idx];
            *(float4*)&lw[(idx>>3)*33 + 4*(idx&7)] = v;
        }
        asm volatile("s_waitcnt lgkmcnt(0)" ::: "memory");
        bool diag = (i == j);
        #pragma unroll
        for (int mt = 0; mt < 2; ++mt) {
            union { f16x8 v; } o;
            #pragma unroll
            for (int e = 0; e < 8; ++e) {
                float f = diag ? 0.f : lw[(g*8 + e)*33 + mt*16 + c];
                o.v[e] = (_Float16)f;
            }
            *(f16x8*)(WF + pOut + (size_t)((ks*2 + mt)*64 + l)*8) = o.v;
        }
    } else {
        int p0 = (z - 2)*8 + w*2;
        const float4* s4 = (const float4*)(Wt + sBase);
        #pragma unroll
        for (int q = 0; q < 4; ++q) {
            int idx = q*64 + l;
            int r = idx >> 3, c8 = idx & 7;
            float4 v = s4[r*64 + p0*4 + c8];
            *(float4*)&lw[r*33 + 4*c8] = v;
        }
        asm volatile("s_waitcnt lgkmcnt(0)" ::: "memory");
        #pragma unroll
        for (int dn = 0; dn < 2; ++dn) {
            int nt = p0 + dn;
            union { f16x8 v; } o;
            #pragma unroll
            for (int e = 0; e < 8; ++e)
                o.v[e] = (_Float16)lw[(g*8 + e)*33 + dn*16 + c];
            *(f16x8*)(WF + pOut + 8192 + (size_t)(nt*64 + l)*8) = o.v;
        }
    }
}

// ---- MFMA slot-pair kernel (frozen structure) ----
__global__ __launch_bounds__(256, 4) void k_pairs_mfma(const unsigned short* __restrict__ h16,
        const unsigned short* __restrict__ WF, float* __restrict__ part) {
    __shared__ unsigned short lds[2*10240];
    int j = blockIdx.x, g = blockIdx.y;
    int t = threadIdx.x, w = t >> 6, l = t & 63;
    int lg = l >> 4, c = l & 15;
    const unsigned short* pbase = WF + ((size_t)j*128 + g*16)*16384;

    {
        const unsigned short* src = pbase;
        #pragma unroll
        for (int q = 0; q < 4; ++q)
            GLD_LDS16(src + (size_t)(q*256 + t)*8, &lds[(q*256 + t)*8]);
        const unsigned short* hsrc = h16 + ((size_t)(t&7)*NUM_SLOTS + g*16)*D_MODEL + (t>>3)*8;
        GLD_LDS16(hsrc, &lds[8192 + t*8]);
    }
    __builtin_amdgcn_sched_barrier(0);
    f16x8 bqn[4];
    #pragma unroll
    for (int nt = 0; nt < 4; ++nt)
        bqn[nt] = *(const f16x8*)(pbase + 8192 + (size_t)((w*4+nt)*64 + l)*8);
    __builtin_amdgcn_sched_barrier(0);

    f32x4 acc[4];
    #pragma unroll
    for (int nt = 0; nt < 4; ++nt) acc[nt] = (f32x4){0.f,0.f,0.f,0.f};
    f16x8 hzero;
    #pragma unroll
    for (int e = 0; e < 8; ++e) hzero[e] = (_Float16)0.f;

    #pragma unroll 2
    for (int ii = 0; ii < 16; ++ii) {
        int cur = ii & 1;
        asm volatile("s_waitcnt vmcnt(4) lgkmcnt(0)" ::: "memory");
        __builtin_amdgcn_s_barrier();
        __builtin_amdgcn_sched_barrier(0);
        if (ii < 15) {
            const unsigned short* src = pbase + (size_t)(ii+1)*16384;
            unsigned short* dst = &lds[(cur^1)*10240];
            #pragma unroll
            for (int q = 0; q < 4; ++q)
                GLD_LDS16(src + (size_t)(q*256 + t)*8, dst + (size_t)(q*256 + t)*8);
            const unsigned short* hsrc = h16 + ((size_t)(t&7)*NUM_SLOTS + (g*16+ii+1))*D_MODEL + (t>>3)*8;
            GLD_LDS16(hsrc, dst + 8192 + (size_t)t*8);
        }
        __builtin_amdgcn_sched_barrier(0);
        f16x8 bq[4];
        #pragma unroll
        for (int nt = 0; nt < 4; ++nt) bq[nt] = bqn[nt];
        if (ii < 15) {
            const unsigned short* bp = pbase + (size_t)(ii+1)*16384 + 8192;
            #pragma unroll
            for (int nt = 0; nt < 4; ++nt)
                bqn[nt] = *(const f16x8*)(bp + (size_t)((w*4+nt)*64 + l)*8);
        }
        const unsigned short* buf = &lds[cur*10240];
        f32x4 d1[2];
        d1[0] = (f32x4){0.f,0.f,0.f,0.f};
        d1[1] = (f32x4){0.f,0.f,0.f,0.f};
        #pragma unroll
        for (int ks = 0; ks < 8; ++ks) {
            f16x8 a0 = *(const f16x8*)(buf + (size_t)((ks*2+0)*64 + l)*8);
            f16x8 a1 = *(const f16x8*)(buf + (size_t)((ks*2+1)*64 + l)*8);
            f16x8 hv = *(const f16x8*)(buf + 8192 + (size_t)(((ks*4+lg)*8 + (c&7)))*8);
            f16x8 hb = (c < 8) ? hv : hzero;
            d1[0] = __builtin_amdgcn_mfma_f32_16x16x32_f16(a0, hb, d1[0], 0, 0, 0);
            d1[1] = __builtin_amdgcn_mfma_f32_16x16x32_f16(a1, hb, d1[1], 0, 0, 0);
        }
        unsigned q0 = pk2(d1[0][0], d1[0][1]);
        unsigned q1 = pk2(d1[0][2], d1[0][3]);
        unsigned s0 = pk2(d1[1][0], d1[1][1]);
        unsigned s1 = pk2(d1[1][2], d1[1][3]);
        int srcLo = 32*(lg & 1) + c;
        int srcHi = srcLo + 16;
        unsigned a0s = (unsigned)__shfl((int)q0, srcLo, 64);
        unsigned a1s = (unsigned)__shfl((int)q1, srcLo, 64);
        unsigned a2s = (unsigned)__shfl((int)q0, srcHi, 64);
        unsigned a3s = (unsigned)__shfl((int)q1, srcHi, 64);
        unsigned b0s = (unsigned)__shfl((int)s0, srcLo, 64);
        unsigned b1s = (unsigned)__shfl((int)s1, srcLo, 64);
        unsigned b2s = (unsigned)__shfl((int)s0, srcHi, 64);
        unsigned b3s = (unsigned)__shfl((int)s1, srcHi, 64);
        bool himt = ((lg >> 1) & 1);
        union { unsigned u[4]; f16x8 v; } A2u;
        A2u.u[0] = himt ? b0s : a0s;
        A2u.u[1] = himt ? b1s : a1s;
        A2u.u[2] = himt ? b2s : a2s;
        A2u.u[3] = himt ? b3s : a3s;
        #pragma unroll
        for (int nt = 0; nt < 4; ++nt)
            acc[nt] = __builtin_amdgcn_mfma_f32_16x16x32_f16(A2u.v, bq[nt], acc[nt], 0, 0, 0);
    }
    if (lg < 2) {
        #pragma unroll
        for (int nt = 0; nt < 4; ++nt) {
            int d = (w*4 + nt)*16 + c;
            #pragma unroll
            for (int r = 0; r < 4; ++r) {
                int b = lg*4 + r;
                part[(((size_t)g*BATCH + b)*NUM_SLOTS + j)*D_MODEL + d] = acc[nt][r];
            }
        }
    }
}

// h = LN(h + relu(sum_g part)); writes fp32 and fp16 copies
__global__ __launch_bounds__(256) void k_ln(float* __restrict__ h,
        unsigned short* __restrict__ h16, const float* __restrict__ part,
        const float* __restrict__ gma, const float* __restrict__ bta) {
    int bj = blockIdx.x;
    int t = threadIdx.x;
    int b = bj >> 7, j = bj & 127;
    __shared__ float red[256];
    float v = 0.f;
    #pragma unroll
    for (int g = 0; g < IGROUPS; ++g)
        v += part[(((size_t)g*BATCH + b)*NUM_SLOTS + j)*D_MODEL + t];
    float x = h[(size_t)bj*D_MODEL + t] + fmaxf(v, 0.f);
    red[t] = x; __syncthreads();
    for (int o = 128; o > 0; o >>= 1) { if (t < o) red[t] += red[t+o]; __syncthreads(); }
    float mu = red[0] * (1.0f/D_MODEL); __syncthreads();
    float dx = x - mu;
    red[t] = dx*dx; __syncthreads();
    for (int o = 128; o > 0; o >>= 1) { if (t < o) red[t] += red[t+o]; __syncthreads(); }
    float var = red[0] * (1.0f/D_MODEL);
    float outv = dx * rsqrtf(var + LN_EPS) * gma[t] + bta[t];
    h[(size_t)bj*D_MODEL + t] = outv;
    h16[(size_t)bj*D_MODEL + t] = f2h(outv);
}

// Kf/Vf projections from Hst, selected by blockIdx.z
__global__ __launch_bounds__(256) void k_kfvf(const float* __restrict__ A,
        const float* __restrict__ B0, const float* __restrict__ B1,
        float* __restrict__ C0, float* __restrict__ C1) {
    const int K = D_MODEL, N = D_MODEL;
    const float* B = blockIdx.z == 0 ? B0 : B1;
    float* C = blockIdx.z == 0 ? C0 : C1;
    __shared__ float As[32][64];
    __shared__ float Bs[32][64];
    int bm = blockIdx.x * 64, bn = blockIdx.y * 64;
    int t = threadIdx.x;
    int tm = (t & 15) * 4, tn = (t >> 4) * 4;
    float acc[4][4] = {};
    for (int k0 = 0; k0 < K; k0 += 32) {
        #pragma unroll
        for (int r = 0; r < 8; ++r) {
            int idx = r*256 + t;
            int m = idx >> 5, k = idx & 31;
            As[k][m] = A[(size_t)(bm+m)*K + k0 + k];
        }
        #pragma unroll
        for (int r = 0; r < 8; ++r) {
            int idx = r*256 + t;
            int n = idx >> 5, k = idx & 31;
            Bs[k][n] = B[(size_t)(bn+n)*K + k0 + k];
        }
        __syncthreads();
        #pragma unroll
        for (int k = 0; k < 32; ++k) {
            float4 a4 = *(const float4*)&As[k][tm];
            float4 b4 = *(const float4*)&Bs[k][tn];
            float a[4] = {a4.x,a4.y,a4.z,a4.w};
            float b[4] = {b4.x,b4.y,b4.z,b4.w};
            #pragma unroll
            for (int i = 0; i < 4; ++i)
                #pragma unroll
                for (int jj = 0; jj < 4; ++jj)
                    acc[i][jj] += a[i]*b[jj];
        }
        __syncthreads();
    }
    #pragma unroll
    for (int i = 0; i < 4; ++i) {
        float4 v = make_float4(acc[i][0],acc[i][1],acc[i][2],acc[i][3]);
        *(float4*)&C[(size_t)(bm+tm+i)*N + bn+tn] = v;
    }
}

// fused expand attention: scores -> softmax -> Y, written as fp16
__global__ __launch_bounds__(256) void k_attn2y(const float* __restrict__ Q,
        const float* __restrict__ Kf, const float* __restrict__ Vf,
        unsigned short* __restrict__ Yh) {
    int bl = blockIdx.x; int b = bl / SEQ;
    int t = threadIdx.x;
    __shared__ float q[D_MODEL];
    __shared__ float prt[2][128];
    __shared__ float a[128];
    __shared__ float red[128];
    q[t] = Q[(size_t)bl*D_MODEL + t];
    __syncthreads();
    int s = t & 127, hf = t >> 7;
    const float* kf = Kf + ((size_t)b*NUM_SLOTS + s)*D_MODEL + hf*128;
    float accp = 0.f;
    #pragma unroll 8
    for (int d = 0; d < 128; ++d) accp += q[hf*128 + d]*kf[d];
    prt[hf][s] = accp;
    __syncthreads();
    float v = 0.f;
    if (t < 128) { v = (prt[0][t] + prt[1][t]) * SM_SCALE; red[t] = v; }
    __syncthreads();
    for (int o = 64; o > 0; o >>= 1) { if (t < o) red[t] = fmaxf(red[t], red[t+o]); __syncthreads(); }
    float mx = red[0]; __syncthreads();
    if (t < 128) { float e = expf(v - mx); a[t] = e; red[t] = e; }
    __syncthreads();
    for (int o = 64; o > 0; o >>= 1) { if (t < o) red[t] += red[t+o]; __syncthreads(); }
    float inv = 1.0f / red[0];
    __syncthreads();
    const float* vf = Vf + (size_t)b*NUM_SLOTS*D_MODEL + t;
    float y0 = 0.f, y1 = 0.f, y2 = 0.f, y3 = 0.f;
    #pragma unroll
    for (int s2 = 0; s2 < NUM_SLOTS; s2 += 4) {
        y0 += a[s2+0]*vf[(size_t)(s2+0)*D_MODEL];
        y1 += a[s2+1]*vf[(size_t)(s2+1)*D_MODEL];
        y2 += a[s2+2]*vf[(size_t)(s2+2)*D_MODEL];
        y3 += a[s2+3]*vf[(size_t)(s2+3)*D_MODEL];
    }
    float y = ((y0+y1) + (y2+y3)) * inv;
    Yh[(size_t)bl*D_MODEL + t] = f2h(y);
}

extern "C" void kernel_launch(void* const* d_in, const int* in_sizes, int n_in,
                              void* d_out, int out_size, void* d_ws, size_t ws_size,
                              hipStream_t stream) {
    const int*   ids    = (const int*)d_in[0];
    const int*   amask  = (const int*)d_in[1];
    const float* tok    = (const float*)d_in[2];
    const float* pos    = (const float*)d_in[3];
    const float* Hin    = (const float*)d_in[4];
    const float* Ws     = (const float*)d_in[5];
    const float* Wt     = (const float*)d_in[6];
    const float* Wq_in  = (const float*)d_in[7];
    const float* Wk_sl  = (const float*)d_in[8];
    const float* Wv_in  = (const float*)d_in[9];
    const float* Wq_out = (const float*)d_in[10];
    const float* Wk_fin = (const float*)d_in[11];
    const float* Wv_fin = (const float*)d_in[12];
    const float* Wop    = (const float*)d_in[13];
    const float* lnsc   = (const float*)d_in[14];
    const float* lnbs   = (const float*)d_in[15];
    float* out = (float*)d_out;

    const size_t WF_USH = (size_t)16384 * 16384;     // 512 MiB of ushorts
    unsigned short* WF = (unsigned short*)d_ws;
    float* ws = (float*)(WF + WF_USH);

    float* X    = ws;                                  // unused (layout keep)
    float* Qin  = X    + (size_t)NTOK*D_MODEL;
    float* Vin  = Qin  + (size_t)NTOK*D_MODEL;
    float* Ksl  = Vin  + (size_t)NTOK*D_MODEL;
    float* Asc  = Ksl  + (size_t)NUM_SLOTS*D_MODEL;
    float* csp  = Asc  + (size_t)NTOK*NUM_SLOTS;       // unused (layout keep)
    float* Hst  = csp  + (size_t)BATCH*8*NUM_SLOTS;
    float* part = Hst  + (size_t)BATCH*NUM_SLOTS*D_MODEL;
    float* Qout = part + (size_t)IGROUPS*BATCH*NUM_SLOTS*D_MODEL;
    float* Kf   = Qout + (size_t)NTOK*D_MODEL;
    float* Vf   = Kf   + (size_t)BATCH*NUM_SLOTS*D_MODEL;
    float* A2   = Vf   + (size_t)BATCH*NUM_SLOTS*D_MODEL;
    float* Yb   = A2   + (size_t)NTOK*NUM_SLOTS;
    unsigned short* Yh = (unsigned short*)(Yb + (size_t)NTOK*D_MODEL);
    unsigned short* Yl = Yh + (size_t)NTOK*D_MODEL;    // unused
    unsigned short* Wf16 = Yl + (size_t)NTOK*D_MODEL;
    unsigned short* Hst16 = Wf16 + (size_t)VOCAB*D_MODEL;

    // one-time weight conversions (independent of the rest)
    k_convert<<<dim3(128, 128, 4), 256, 0, stream>>>(Ws, Wt, WF);
    k_split16<<<(VOCAB*D_MODEL/4 + 255)/256, 256, 0, stream>>>(Wop, Wf16, VOCAB*D_MODEL/4);

    // X projections (Qin, Vin, Qout) with embed fused into A-staging
    k_gemm3e<<<dim3(NTOK/64, 4, 3), 256, 0, stream>>>(ids, tok, pos,
            Wq_in, Wv_in, Wq_out, Qin, Vin, Qout);
    k_gemm_nt<<<dim3(2, 4), 256, 0, stream>>>(Hin, Wk_sl, Ksl, NUM_SLOTS, D_MODEL, D_MODEL);
    // fused scores + softmax + mask
    k_attn1<<<NTOK, 128, 0, stream>>>(Qin, Ksl, amask, Asc);
    // aggregate into slots (colsum fused)
    k_ir<<<BATCH*NUM_SLOTS, 256, 0, stream>>>(Asc, Vin, Hin, Hst, Hst16);
    // bilinear slot-interaction steps
    for (int st = 0; st < N_STEPS; ++st) {
        k_pairs_mfma<<<dim3(NUM_SLOTS, IGROUPS), 256, 0, stream>>>(Hst16, WF, part);
        k_ln<<<BATCH*NUM_SLOTS, 256, 0, stream>>>(Hst, Hst16, part, lnsc + st*D_MODEL, lnbs + st*D_MODEL);
    }
    // expand projections (Kf, Vf fused)
    k_kfvf<<<dim3(BATCH*NUM_SLOTS/64, 4, 2), 256, 0, stream>>>(Hst, Wk_fin, Wv_fin, Kf, Vf);
    // fused expand attention + Y (fp16)
    k_attn2y<<<NTOK, 256, 0, stream>>>(Qout, Kf, Vf, Yh);
    // logits: 1-pass fp16 MFMA with global_load_lds staging
    k_logits<<<dim3(NTOK/128, VOCAB/128), 256, 0, stream>>>(Yh, Wf16, out);
}

// Round 14
// 1352.118 us; speedup vs baseline: 1.5012x; 1.0522x over previous
//
#include <hip/hip_runtime.h>
#include <hip/hip_bf16.h>
#include <math.h>

#define D_MODEL 256
#define NUM_SLOTS 128
#define RANK 32
#define N_STEPS 6
#define VOCAB 32000
#define SEQ 512
#define BATCH 8
#define NTOK (BATCH*SEQ)
#define LN_EPS 1e-5f
#define SM_SCALE 0.0625f
#define IGROUPS 8

// convert block distribution across the four front dispatches
#define CB_A 0
#define NC_A 15360
#define CB_B (CB_A + NC_A)
#define NC_B 11776
#define CB_C (CB_B + NC_B)
#define NC_C 19200
#define CB_D (CB_C + NC_C)
#define NC_D 19200

typedef __attribute__((ext_vector_type(8))) short bf16x8;
typedef __attribute__((ext_vector_type(8))) _Float16 f16x8;
typedef __attribute__((ext_vector_type(4))) float f32x4;

#define GLD_LDS16(g, l) __builtin_amdgcn_global_load_lds( \
    (const __attribute__((address_space(1))) unsigned int*)(g), \
    (__attribute__((address_space(3))) unsigned int*)(l), 16, 0, 0)

__device__ inline unsigned pk2(float a, float b) {
    auto v = __builtin_amdgcn_cvt_pkrtz(a, b);
    union { decltype(v) x; unsigned u; } c;
    c.x = v;
    return c.u;
}
__device__ inline unsigned short f2h(float x) {
    union { _Float16 h; unsigned short u; } c;
    c.h = (_Float16)x;
    return c.u;
}

// ---- convert device body (frozen logic from k_convert) ----
__device__ __forceinline__ void dev_convert(int cb, int t, float* ldsAll,
        const float* __restrict__ Ws, const float* __restrict__ Wt,
        unsigned short* __restrict__ WF) {
    int z = cb >> 14, i = (cb >> 7) & 127, j = cb & 127;
    int w = t >> 6, l = t & 63;
    float* lw = &ldsAll[w*1056];
    size_t sBase = ((size_t)i*128 + j)*8192;
    size_t pOut = ((size_t)j*128 + i)*16384;
    int g = l >> 4, c = l & 15;
    if (z < 2) {
        int ks = z*4 + w;
        const float4* s4 = (const float4*)(Ws + sBase) + ks*256;
        #pragma unroll
        for (int q = 0; q < 4; ++q) {
            int idx = q*64 + l;
            float4 v = s4[idx];
            *(float4*)&lw[(idx>>3)*33 + 4*(idx&7)] = v;
        }
        asm volatile("s_waitcnt lgkmcnt(0)" ::: "memory");
        bool diag = (i == j);
        #pragma unroll
        for (int mt = 0; mt < 2; ++mt) {
            union { f16x8 v; } o;
            #pragma unroll
            for (int e = 0; e < 8; ++e) {
                float f = diag ? 0.f : lw[(g*8 + e)*33 + mt*16 + c];
                o.v[e] = (_Float16)f;
            }
            *(f16x8*)(WF + pOut + (size_t)((ks*2 + mt)*64 + l)*8) = o.v;
        }
    } else {
        int p0 = (z - 2)*8 + w*2;
        const float4* s4 = (const float4*)(Wt + sBase);
        #pragma unroll
        for (int q = 0; q < 4; ++q) {
            int idx = q*64 + l;
            int r = idx >> 3, c8 = idx & 7;
            float4 v = s4[r*64 + p0*4 + c8];
            *(float4*)&lw[r*33 + 4*c8] = v;
        }
        asm volatile("s_waitcnt lgkmcnt(0)" ::: "memory");
        #pragma unroll
        for (int dn = 0; dn < 2; ++dn) {
            int nt = p0 + dn;
            union { f16x8 v; } o;
            #pragma unroll
            for (int e = 0; e < 8; ++e)
                o.v[e] = (_Float16)lw[(g*8 + e)*33 + dn*16 + c];
            *(f16x8*)(WF + pOut + 8192 + (size_t)(nt*64 + l)*8) = o.v;
        }
    }
}

// ---- front A: gemm3e (embed-fused Qin/Vin/Qout projections) + convert ----
__global__ __launch_bounds__(256) void k_front_a(const int* __restrict__ ids,
        const float* __restrict__ tok, const float* __restrict__ pos,
        const float* __restrict__ B0, const float* __restrict__ B1,
        const float* __restrict__ B2, float* __restrict__ C0,
        float* __restrict__ C1, float* __restrict__ C2,
        const float* __restrict__ Ws, const float* __restrict__ Wt,
        unsigned short* __restrict__ WF) {
    __shared__ float smem[4352];
    int bid = blockIdx.x;
    int t = threadIdx.x;
    if (bid >= 768) { dev_convert(CB_A + bid - 768, t, smem, Ws, Wt, WF); return; }
    const int K = D_MODEL, N = D_MODEL;
    int bx = bid & 63, byz = bid >> 6;
    int by = byz & 3, bz = byz >> 2;
    const float* B = bz == 0 ? B0 : (bz == 1 ? B1 : B2);
    float* C = bz == 0 ? C0 : (bz == 1 ? C1 : C2);
    float* As = smem;
    float* Bs = smem + 2048;
    int* sid = (int*)(smem + 4096);
    int bm = bx * 64, bn = by * 64;
    if (t < 64) sid[t] = ids[bm + t];
    __syncthreads();
    int tm = (t & 15) * 4, tn = (t >> 4) * 4;
    float acc[4][4] = {};
    for (int k0 = 0; k0 < K; k0 += 32) {
        #pragma unroll
        for (int r = 0; r < 8; ++r) {
            int idx = r*256 + t;
            int m = idx >> 5, k = idx & 31;
            int gm = bm + m;
            As[k*64 + m] = tok[(size_t)sid[m]*K + k0 + k] + pos[(gm & (SEQ-1))*K + k0 + k];
        }
        #pragma unroll
        for (int r = 0; r < 8; ++r) {
            int idx = r*256 + t;
            int n = idx >> 5, k = idx & 31;
            Bs[k*64 + n] = B[(size_t)(bn+n)*K + k0 + k];
        }
        __syncthreads();
        #pragma unroll
        for (int k = 0; k < 32; ++k) {
            float4 a4 = *(const float4*)&As[k*64 + tm];
            float4 b4 = *(const float4*)&Bs[k*64 + tn];
            float a[4] = {a4.x,a4.y,a4.z,a4.w};
            float b[4] = {b4.x,b4.y,b4.z,b4.w};
            #pragma unroll
            for (int i = 0; i < 4; ++i)
                #pragma unroll
                for (int jj = 0; jj < 4; ++jj)
                    acc[i][jj] += a[i]*b[jj];
        }
        __syncthreads();
    }
    #pragma unroll
    for (int i = 0; i < 4; ++i) {
        float4 v = make_float4(acc[i][0],acc[i][1],acc[i][2],acc[i][3]);
        *(float4*)&C[(size_t)(bm+tm+i)*N + bn+tn] = v;
    }
}

// ---- front B: Ksl projection + W_out fp16 split + convert ----
__global__ __launch_bounds__(256) void k_front_b(const float* __restrict__ Hin,
        const float* __restrict__ Wk_sl, float* __restrict__ Ksl,
        const float* __restrict__ Wop, unsigned short* __restrict__ Wf16,
        const float* __restrict__ Ws, const float* __restrict__ Wt,
        unsigned short* __restrict__ WF) {
    __shared__ float smem[4352];
    int bid = blockIdx.x;
    int t = threadIdx.x;
    if (bid >= 8008) { dev_convert(CB_B + bid - 8008, t, smem, Ws, Wt, WF); return; }
    if (bid >= 8) {
        int i = (bid - 8)*256 + t;
        float4 v = ((const float4*)Wop)[i];
        ushort4 h;
        h.x = f2h(v.x); h.y = f2h(v.y); h.z = f2h(v.z); h.w = f2h(v.w);
        ((ushort4*)Wf16)[i] = h;
        return;
    }
    const int K = D_MODEL, N = D_MODEL;
    int bx = bid & 1, by = bid >> 1;
    float* As = smem;
    float* Bs = smem + 2048;
    int bm = bx * 64, bn = by * 64;
    int tm = (t & 15) * 4, tn = (t >> 4) * 4;
    float acc[4][4] = {};
    for (int k0 = 0; k0 < K; k0 += 32) {
        #pragma unroll
        for (int r = 0; r < 8; ++r) {
            int idx = r*256 + t;
            int m = idx >> 5, k = idx & 31;
            As[k*64 + m] = Hin[(size_t)(bm+m)*K + k0 + k];
        }
        #pragma unroll
        for (int r = 0; r < 8; ++r) {
            int idx = r*256 + t;
            int n = idx >> 5, k = idx & 31;
            Bs[k*64 + n] = Wk_sl[(size_t)(bn+n)*K + k0 + k];
        }
        __syncthreads();
        #pragma unroll
        for (int k = 0; k < 32; ++k) {
            float4 a4 = *(const float4*)&As[k*64 + tm];
            float4 b4 = *(const float4*)&Bs[k*64 + tn];
            float a[4] = {a4.x,a4.y,a4.z,a4.w};
            float b[4] = {b4.x,b4.y,b4.z,b4.w};
            #pragma unroll
            for (int i = 0; i < 4; ++i)
                #pragma unroll
                for (int jj = 0; jj < 4; ++jj)
                    acc[i][jj] += a[i]*b[jj];
        }
        __syncthreads();
    }
    #pragma unroll
    for (int i = 0; i < 4; ++i) {
        float4 v = make_float4(acc[i][0],acc[i][1],acc[i][2],acc[i][3]);
        *(float4*)&Ksl[(size_t)(bm+tm+i)*N + bn+tn] = v;
    }
}

// ---- front C: compress attention (scores+softmax+mask) + convert ----
__global__ __launch_bounds__(256) void k_front_c(const float* __restrict__ Qin,
        const float* __restrict__ Ksl, const int* __restrict__ mask,
        float* __restrict__ A,
        const float* __restrict__ Ws, const float* __restrict__ Wt,
        unsigned short* __restrict__ WF) {
    __shared__ float smem[4352];
    int bid = blockIdx.x;
    int t = threadIdx.x;
    if (bid >= NTOK) { dev_convert(CB_C + bid - NTOK, t, smem, Ws, Wt, WF); return; }
    int bl = bid;
    float* q   = smem;          // 256
    float* prt = smem + 256;    // 256
    float* red = smem + 512;    // 128
    q[t] = Qin[(size_t)bl*D_MODEL + t];
    __syncthreads();
    int s = t & 127, hf = t >> 7;
    const float* kr = Ksl + (size_t)s*D_MODEL + hf*128;
    float accp = 0.f;
    #pragma unroll 8
    for (int d = 0; d < 128; ++d) accp += q[hf*128 + d]*kr[d];
    prt[hf*128 + s] = accp;
    __syncthreads();
    float v = 0.f;
    if (t < 128) { v = (prt[t] + prt[128 + t]) * SM_SCALE; red[t] = v; }
    __syncthreads();
    for (int o = 64; o > 0; o >>= 1) { if (t < o) red[t] = fmaxf(red[t], red[t+o]); __syncthreads(); }
    float mx = red[0]; __syncthreads();
    float e = 0.f;
    if (t < 128) { e = expf(v - mx); red[t] = e; }
    __syncthreads();
    for (int o = 64; o > 0; o >>= 1) { if (t < o) red[t] += red[t+o]; __syncthreads(); }
    float sum = red[0];
    if (t < 128) {
        float m = (float)mask[bl];
        A[(size_t)bl*NUM_SLOTS + t] = e / sum * m;
    }
}

// ---- front D: slot aggregation (IR, colsum fused) + convert ----
__global__ __launch_bounds__(256) void k_front_d(const float* __restrict__ A,
        const float* __restrict__ V, const float* __restrict__ H,
        float* __restrict__ Hs, unsigned short* __restrict__ Hs16,
        const float* __restrict__ Ws, const float* __restrict__ Wt,
        unsigned short* __restrict__ WF) {
    __shared__ float smem[4352];
    int bid = blockIdx.x;
    int t = threadIdx.x;
    if (bid >= BATCH*NUM_SLOTS) { dev_convert(CB_D + bid - BATCH*NUM_SLOTS, t, smem, Ws, Wt, WF); return; }
    int bs = bid; int b = bs >> 7; int s = bs & 127;
    int d = t;
    const float* Ab = A + (size_t)b*SEQ*NUM_SLOTS + s;
    const float* Vb = V + (size_t)b*SEQ*D_MODEL + d;
    float a0 = 0.f, a1 = 0.f, a2 = 0.f, a3 = 0.f;
    float s0 = 0.f, s1 = 0.f, s2 = 0.f, s3 = 0.f;
    for (int l = 0; l < SEQ; l += 4) {
        float w0 = Ab[(size_t)(l+0)*NUM_SLOTS];
        float w1 = Ab[(size_t)(l+1)*NUM_SLOTS];
        float w2 = Ab[(size_t)(l+2)*NUM_SLOTS];
        float w3 = Ab[(size_t)(l+3)*NUM_SLOTS];
        a0 += w0 * Vb[(size_t)(l+0)*D_MODEL];
        a1 += w1 * Vb[(size_t)(l+1)*D_MODEL];
        a2 += w2 * Vb[(size_t)(l+2)*D_MODEL];
        a3 += w3 * Vb[(size_t)(l+3)*D_MODEL];
        s0 += w0; s1 += w1; s2 += w2; s3 += w3;
    }
    float asum = (s0+s1) + (s2+s3) + 1e-8f;
    float acc = (a0+a1) + (a2+a3);
    float v = H[s*D_MODEL + d] + acc / asum;
    Hs[(size_t)bs*D_MODEL + d] = v;
    Hs16[(size_t)bs*D_MODEL + d] = f2h(v);
}

// logits GEMM: 1-pass fp16 MFMA, global_load_lds staging (frozen)
__global__ __launch_bounds__(256) void k_logits(
        const unsigned short* __restrict__ Ahg,
        const unsigned short* __restrict__ Bhg, float* __restrict__ C) {
    __shared__ unsigned short lds[2*8192];
    int bm = blockIdx.x * 128, bn = blockIdx.y * 128;
    int t = threadIdx.x;
    int w = t >> 6, l = t & 63;
    int wr = w >> 1, wc = w & 1;
    int lr = l & 15, lk = l >> 4;
    f32x4 acc[4][4];
    #pragma unroll
    for (int mi = 0; mi < 4; ++mi)
        #pragma unroll
        for (int ni = 0; ni < 4; ++ni)
            acc[mi][ni] = (f32x4){0.f,0.f,0.f,0.f};

    for (int kc = 0; kc < 4; ++kc) {
        if (kc) __syncthreads();
        #pragma unroll
        for (int i = 0; i < 4; ++i) {
            int c = t + i*256;
            int row = c >> 3, c8 = c & 7;
            size_t ga = (size_t)(bm+row)*256 + kc*64 + c8*8;
            size_t gb = (size_t)(bn+row)*256 + kc*64 + c8*8;
            GLD_LDS16(Ahg + ga, &lds[c*8]);
            GLD_LDS16(Bhg + gb, &lds[8192 + c*8]);
        }
        __syncthreads();
        #pragma unroll
        for (int s = 0; s < 2; ++s) {
            f16x8 ah[4], bh[4];
            #pragma unroll
            for (int mi = 0; mi < 4; ++mi) {
                int off = (wr*64 + mi*16 + lr)*64 + s*32 + lk*8;
                ah[mi] = *(const f16x8*)&lds[off];
            }
            #pragma unroll
            for (int ni = 0; ni < 4; ++ni) {
                int off = (wc*64 + ni*16 + lr)*64 + s*32 + lk*8;
                bh[ni] = *(const f16x8*)&lds[8192 + off];
            }
            #pragma unroll
            for (int mi = 0; mi < 4; ++mi)
                #pragma unroll
                for (int ni = 0; ni < 4; ++ni)
                    acc[mi][ni] = __builtin_amdgcn_mfma_f32_16x16x32_f16(ah[mi], bh[ni], acc[mi][ni], 0, 0, 0);
        }
    }
    #pragma unroll
    for (int mi = 0; mi < 4; ++mi)
        #pragma unroll
        for (int ni = 0; ni < 4; ++ni) {
            int col = bn + wc*64 + ni*16 + lr;
            #pragma unroll
            for (int r = 0; r < 4; ++r) {
                int row = bm + wr*64 + mi*16 + lk*4 + r;
                C[(size_t)row*VOCAB + col] = acc[mi][ni][r];
            }
        }
}

// ---- MFMA slot-pair kernel (frozen structure) ----
__global__ __launch_bounds__(256, 4) void k_pairs_mfma(const unsigned short* __restrict__ h16,
        const unsigned short* __restrict__ WF, float* __restrict__ part) {
    __shared__ unsigned short lds[2*10240];
    int j = blockIdx.x, g = blockIdx.y;
    int t = threadIdx.x, w = t >> 6, l = t & 63;
    int lg = l >> 4, c = l & 15;
    const unsigned short* pbase = WF + ((size_t)j*128 + g*16)*16384;

    {
        const unsigned short* src = pbase;
        #pragma unroll
        for (int q = 0; q < 4; ++q)
            GLD_LDS16(src + (size_t)(q*256 + t)*8, &lds[(q*256 + t)*8]);
        const unsigned short* hsrc = h16 + ((size_t)(t&7)*NUM_SLOTS + g*16)*D_MODEL + (t>>3)*8;
        GLD_LDS16(hsrc, &lds[8192 + t*8]);
    }
    __builtin_amdgcn_sched_barrier(0);
    f16x8 bqn[4];
    #pragma unroll
    for (int nt = 0; nt < 4; ++nt)
        bqn[nt] = *(const f16x8*)(pbase + 8192 + (size_t)((w*4+nt)*64 + l)*8);
    __builtin_amdgcn_sched_barrier(0);

    f32x4 acc[4];
    #pragma unroll
    for (int nt = 0; nt < 4; ++nt) acc[nt] = (f32x4){0.f,0.f,0.f,0.f};
    f16x8 hzero;
    #pragma unroll
    for (int e = 0; e < 8; ++e) hzero[e] = (_Float16)0.f;

    #pragma unroll 2
    for (int ii = 0; ii < 16; ++ii) {
        int cur = ii & 1;
        asm volatile("s_waitcnt vmcnt(4) lgkmcnt(0)" ::: "memory");
        __builtin_amdgcn_s_barrier();
        __builtin_amdgcn_sched_barrier(0);
        if (ii < 15) {
            const unsigned short* src = pbase + (size_t)(ii+1)*16384;
            unsigned short* dst = &lds[(cur^1)*10240];
            #pragma unroll
            for (int q = 0; q < 4; ++q)
                GLD_LDS16(src + (size_t)(q*256 + t)*8, dst + (size_t)(q*256 + t)*8);
            const unsigned short* hsrc = h16 + ((size_t)(t&7)*NUM_SLOTS + (g*16+ii+1))*D_MODEL + (t>>3)*8;
            GLD_LDS16(hsrc, dst + 8192 + (size_t)t*8);
        }
        __builtin_amdgcn_sched_barrier(0);
        f16x8 bq[4];
        #pragma unroll
        for (int nt = 0; nt < 4; ++nt) bq[nt] = bqn[nt];
        if (ii < 15) {
            const unsigned short* bp = pbase + (size_t)(ii+1)*16384 + 8192;
            #pragma unroll
            for (int nt = 0; nt < 4; ++nt)
                bqn[nt] = *(const f16x8*)(bp + (size_t)((w*4+nt)*64 + l)*8);
        }
        const unsigned short* buf = &lds[cur*10240];
        f32x4 d1[2];
        d1[0] = (f32x4){0.f,0.f,0.f,0.f};
        d1[1] = (f32x4){0.f,0.f,0.f,0.f};
        #pragma unroll
        for (int ks = 0; ks < 8; ++ks) {
            f16x8 a0 = *(const f16x8*)(buf + (size_t)((ks*2+0)*64 + l)*8);
            f16x8 a1 = *(const f16x8*)(buf + (size_t)((ks*2+1)*64 + l)*8);
            f16x8 hv = *(const f16x8*)(buf + 8192 + (size_t)(((ks*4+lg)*8 + (c&7)))*8);
            f16x8 hb = (c < 8) ? hv : hzero;
            d1[0] = __builtin_amdgcn_mfma_f32_16x16x32_f16(a0, hb, d1[0], 0, 0, 0);
            d1[1] = __builtin_amdgcn_mfma_f32_16x16x32_f16(a1, hb, d1[1], 0, 0, 0);
        }
        unsigned q0 = pk2(d1[0][0], d1[0][1]);
        unsigned q1 = pk2(d1[0][2], d1[0][3]);
        unsigned s0 = pk2(d1[1][0], d1[1][1]);
        unsigned s1 = pk2(d1[1][2], d1[1][3]);
        int srcLo = 32*(lg & 1) + c;
        int srcHi = srcLo + 16;
        unsigned a0s = (unsigned)__shfl((int)q0, srcLo, 64);
        unsigned a1s = (unsigned)__shfl((int)q1, srcLo, 64);
        unsigned a2s = (unsigned)__shfl((int)q0, srcHi, 64);
        unsigned a3s = (unsigned)__shfl((int)q1, srcHi, 64);
        unsigned b0s = (unsigned)__shfl((int)s0, srcLo, 64);
        unsigned b1s = (unsigned)__shfl((int)s1, srcLo, 64);
        unsigned b2s = (unsigned)__shfl((int)s0, srcHi, 64);
        unsigned b3s = (unsigned)__shfl((int)s1, srcHi, 64);
        bool himt = ((lg >> 1) & 1);
        union { unsigned u[4]; f16x8 v; } A2u;
        A2u.u[0] = himt ? b0s : a0s;
        A2u.u[1] = himt ? b1s : a1s;
        A2u.u[2] = himt ? b2s : a2s;
        A2u.u[3] = himt ? b3s : a3s;
        #pragma unroll
        for (int nt = 0; nt < 4; ++nt)
            acc[nt] = __builtin_amdgcn_mfma_f32_16x16x32_f16(A2u.v, bq[nt], acc[nt], 0, 0, 0);
    }
    if (lg < 2) {
        #pragma unroll
        for (int nt = 0; nt < 4; ++nt) {
            int d = (w*4 + nt)*16 + c;
            #pragma unroll
            for (int r = 0; r < 4; ++r) {
                int b = lg*4 + r;
                part[(((size_t)g*BATCH + b)*NUM_SLOTS + j)*D_MODEL + d] = acc[nt][r];
            }
        }
    }
}

// h = LN(h + relu(sum_g part)); writes fp32 and fp16 copies (frozen)
__global__ __launch_bounds__(256) void k_ln(float* __restrict__ h,
        unsigned short* __restrict__ h16, const float* __restrict__ part,
        const float* __restrict__ gma, const float* __restrict__ bta) {
    int bj = blockIdx.x;
    int t = threadIdx.x;
    int b = bj >> 7, j = bj & 127;
    __shared__ float red[256];
    float v = 0.f;
    #pragma unroll
    for (int g = 0; g < IGROUPS; ++g)
        v += part[(((size_t)g*BATCH + b)*NUM_SLOTS + j)*D_MODEL + t];
    float x = h[(size_t)bj*D_MODEL + t] + fmaxf(v, 0.f);
    red[t] = x; __syncthreads();
    for (int o = 128; o > 0; o >>= 1) { if (t < o) red[t] += red[t+o]; __syncthreads(); }
    float mu = red[0] * (1.0f/D_MODEL); __syncthreads();
    float dx = x - mu;
    red[t] = dx*dx; __syncthreads();
    for (int o = 128; o > 0; o >>= 1) { if (t < o) red[t] += red[t+o]; __syncthreads(); }
    float var = red[0] * (1.0f/D_MODEL);
    float outv = dx * rsqrtf(var + LN_EPS) * gma[t] + bta[t];
    h[(size_t)bj*D_MODEL + t] = outv;
    h16[(size_t)bj*D_MODEL + t] = f2h(outv);
}

// Kf/Vf projections from Hst, selected by blockIdx.z (frozen)
__global__ __launch_bounds__(256) void k_kfvf(const float* __restrict__ A,
        const float* __restrict__ B0, const float* __restrict__ B1,
        float* __restrict__ C0, float* __restrict__ C1) {
    const int K = D_MODEL, N = D_MODEL;
    const float* B = blockIdx.z == 0 ? B0 : B1;
    float* C = blockIdx.z == 0 ? C0 : C1;
    __shared__ float As[32][64];
    __shared__ float Bs[32][64];
    int bm = blockIdx.x * 64, bn = blockIdx.y * 64;
    int t = threadIdx.x;
    int tm = (t & 15) * 4, tn = (t >> 4) * 4;
    float acc[4][4] = {};
    for (int k0 = 0; k0 < K; k0 += 32) {
        #pragma unroll
        for (int r = 0; r < 8; ++r) {
            int idx = r*256 + t;
            int m = idx >> 5, k = idx & 31;
            As[k][m] = A[(size_t)(bm+m)*K + k0 + k];
        }
        #pragma unroll
        for (int r = 0; r < 8; ++r) {
            int idx = r*256 + t;
            int n = idx >> 5, k = idx & 31;
            Bs[k][n] = B[(size_t)(bn+n)*K + k0 + k];
        }
        __syncthreads();
        #pragma unroll
        for (int k = 0; k < 32; ++k) {
            float4 a4 = *(const float4*)&As[k][tm];
            float4 b4 = *(const float4*)&Bs[k][tn];
            float a[4] = {a4.x,a4.y,a4.z,a4.w};
            float b[4] = {b4.x,b4.y,b4.z,b4.w};
            #pragma unroll
            for (int i = 0; i < 4; ++i)
                #pragma unroll
                for (int jj = 0; jj < 4; ++jj)
                    acc[i][jj] += a[i]*b[jj];
        }
        __syncthreads();
    }
    #pragma unroll
    for (int i = 0; i < 4; ++i) {
        float4 v = make_float4(acc[i][0],acc[i][1],acc[i][2],acc[i][3]);
        *(float4*)&C[(size_t)(bm+tm+i)*N + bn+tn] = v;
    }
}

// fused expand attention: scores -> softmax -> Y, written as fp16 (frozen)
__global__ __launch_bounds__(256) void k_attn2y(const float* __restrict__ Q,
        const float* __restrict__ Kf, const float* __restrict__ Vf,
        unsigned short* __restrict__ Yh) {
    int bl = blockIdx.x; int b = bl / SEQ;
    int t = threadIdx.x;
    __shared__ float q[D_MODEL];
    __shared__ float prt[2][128];
    __shared__ float a[128];
    __shared__ float red[128];
    q[t] = Q[(size_t)bl*D_MODEL + t];
    __syncthreads();
    int s = t & 127, hf = t >> 7;
    const float* kf = Kf + ((size_t)b*NUM_SLOTS + s)*D_MODEL + hf*128;
    float accp = 0.f;
    #pragma unroll 8
    for (int d = 0; d < 128; ++d) accp += q[hf*128 + d]*kf[d];
    prt[hf][s] = accp;
    __syncthreads();
    float v = 0.f;
    if (t < 128) { v = (prt[0][t] + prt[1][t]) * SM_SCALE; red[t] = v; }
    __syncthreads();
    for (int o = 64; o > 0; o >>= 1) { if (t < o) red[t] = fmaxf(red[t], red[t+o]); __syncthreads(); }
    float mx = red[0]; __syncthreads();
    if (t < 128) { float e = expf(v - mx); a[t] = e; red[t] = e; }
    __syncthreads();
    for (int o = 64; o > 0; o >>= 1) { if (t < o) red[t] += red[t+o]; __syncthreads(); }
    float inv = 1.0f / red[0];
    __syncthreads();
    const float* vf = Vf + (size_t)b*NUM_SLOTS*D_MODEL + t;
    float y0 = 0.f, y1 = 0.f, y2 = 0.f, y3 = 0.f;
    #pragma unroll
    for (int s2 = 0; s2 < NUM_SLOTS; s2 += 4) {
        y0 += a[s2+0]*vf[(size_t)(s2+0)*D_MODEL];
        y1 += a[s2+1]*vf[(size_t)(s2+1)*D_MODEL];
        y2 += a[s2+2]*vf[(size_t)(s2+2)*D_MODEL];
        y3 += a[s2+3]*vf[(size_t)(s2+3)*D_MODEL];
    }
    float y = ((y0+y1) + (y2+y3)) * inv;
    Yh[(size_t)bl*D_MODEL + t] = f2h(y);
}

extern "C" void kernel_launch(void* const* d_in, const int* in_sizes, int n_in,
                              void* d_out, int out_size, void* d_ws, size_t ws_size,
                              hipStream_t stream) {
    const int*   ids    = (const int*)d_in[0];
    const int*   amask  = (const int*)d_in[1];
    const float* tok    = (const float*)d_in[2];
    const float* pos    = (const float*)d_in[3];
    const float* Hin    = (const float*)d_in[4];
    const float* Ws     = (const float*)d_in[5];
    const float* Wt     = (const float*)d_in[6];
    const float* Wq_in  = (const float*)d_in[7];
    const float* Wk_sl  = (const float*)d_in[8];
    const float* Wv_in  = (const float*)d_in[9];
    const float* Wq_out = (const float*)d_in[10];
    const float* Wk_fin = (const float*)d_in[11];
    const float* Wv_fin = (const float*)d_in[12];
    const float* Wop    = (const float*)d_in[13];
    const float* lnsc   = (const float*)d_in[14];
    const float* lnbs   = (const float*)d_in[15];
    float* out = (float*)d_out;

    const size_t WF_USH = (size_t)16384 * 16384;     // 512 MiB of ushorts
    unsigned short* WF = (unsigned short*)d_ws;
    float* ws = (float*)(WF + WF_USH);

    float* X    = ws;
    float* Qin  = X    + (size_t)NTOK*D_MODEL;
    float* Vin  = Qin  + (size_t)NTOK*D_MODEL;
    float* Ksl  = Vin  + (size_t)NTOK*D_MODEL;
    float* Asc  = Ksl  + (size_t)NUM_SLOTS*D_MODEL;
    float* csp  = Asc  + (size_t)NTOK*NUM_SLOTS;
    float* Hst  = csp  + (size_t)BATCH*8*NUM_SLOTS;
    float* part = Hst  + (size_t)BATCH*NUM_SLOTS*D_MODEL;
    float* Qout = part + (size_t)IGROUPS*BATCH*NUM_SLOTS*D_MODEL;
    float* Kf   = Qout + (size_t)NTOK*D_MODEL;
    float* Vf   = Kf   + (size_t)BATCH*NUM_SLOTS*D_MODEL;
    float* A2   = Vf   + (size_t)BATCH*NUM_SLOTS*D_MODEL;
    float* Yb   = A2   + (size_t)NTOK*NUM_SLOTS;
    unsigned short* Yh = (unsigned short*)(Yb + (size_t)NTOK*D_MODEL);
    unsigned short* Yl = Yh + (size_t)NTOK*D_MODEL;
    unsigned short* Wf16 = Yl + (size_t)NTOK*D_MODEL;
    unsigned short* Hst16 = Wf16 + (size_t)VOCAB*D_MODEL;

    // front phase: serial small-kernel chain, each overlapped with a slice
    // of the independent weight-conversion blocks
    k_front_a<<<768 + NC_A, 256, 0, stream>>>(ids, tok, pos,
            Wq_in, Wv_in, Wq_out, Qin, Vin, Qout, Ws, Wt, WF);
    k_front_b<<<8008 + NC_B, 256, 0, stream>>>(Hin, Wk_sl, Ksl, Wop, Wf16, Ws, Wt, WF);
    k_front_c<<<NTOK + NC_C, 256, 0, stream>>>(Qin, Ksl, amask, Asc, Ws, Wt, WF);
    k_front_d<<<BATCH*NUM_SLOTS + NC_D, 256, 0, stream>>>(Asc, Vin, Hin, Hst, Hst16, Ws, Wt, WF);

    // bilinear slot-interaction steps
    for (int st = 0; st < N_STEPS; ++st) {
        k_pairs_mfma<<<dim3(NUM_SLOTS, IGROUPS), 256, 0, stream>>>(Hst16, WF, part);
        k_ln<<<BATCH*NUM_SLOTS, 256, 0, stream>>>(Hst, Hst16, part, lnsc + st*D_MODEL, lnbs + st*D_MODEL);
    }
    // expand projections (Kf, Vf fused)
    k_kfvf<<<dim3(BATCH*NUM_SLOTS/64, 4, 2), 256, 0, stream>>>(Hst, Wk_fin, Wv_fin, Kf, Vf);
    // fused expand attention + Y (fp16)
    k_attn2y<<<NTOK, 256, 0, stream>>>(Qout, Kf, Vf, Yh);
    // logits: 1-pass fp16 MFMA with global_load_lds staging
    k_logits<<<dim3(NTOK/128, VOCAB/128), 256, 0, stream>>>(Yh, Wf16, out);
}